// Round 1
// 1371.296 us; speedup vs baseline: 1.0346x; 1.0346x over previous
//
#include <hip/hip_runtime.h>
#include <hip/hip_bf16.h>
#include <type_traits>

typedef __hip_bfloat16 bf16;
typedef __attribute__((ext_vector_type(8))) short short8;
typedef __attribute__((ext_vector_type(4))) float floatx4;

static constexpr int kNumItem = 50000;

__device__ __forceinline__ float bf2f(const bf16 x) { return __bfloat162float(x); }

union alignas(16) Pack8 {
  bf16 b[8];
  short8 s;
};
union alignas(8) Pack4 {
  bf16 b[4];
  short4 s;
};

__device__ __forceinline__ void async_cp16(const void* g, void* l) {
  __builtin_amdgcn_global_load_lds((const __attribute__((address_space(1))) void*)g,
                                   (__attribute__((address_space(3))) void*)l, 16, 0, 0);
}

// ---------------- per-row 1/max(||x||,1e-12), fp32 input (slim path) ------------
__global__ __launch_bounds__(256) void row_invnorm(const float* __restrict__ X,
                                                   float* __restrict__ out,
                                                   int M, int K) {
  const int lane = threadIdx.x & 63;
  const int wave = threadIdx.x >> 6;
  const int row = blockIdx.x * 4 + wave;
  if (row >= M) return;
  const float* xr = X + (size_t)row * K;
  float s = 0.f;
  for (int c = lane * 8; c < K; c += 64 * 8) {
    float4 a = *(const float4*)(xr + c);
    float4 b = *(const float4*)(xr + c + 4);
    s += a.x * a.x + a.y * a.y + a.z * a.z + a.w * a.w;
    s += b.x * b.x + b.y * b.y + b.z * b.z + b.w * b.w;
  }
#pragma unroll
  for (int off = 32; off > 0; off >>= 1) s += __shfl_xor(s, off, 64);
  if (lane == 0) out[row] = 1.0f / fmaxf(sqrtf(s), 1e-12f);
}

// ------------- fused: fp32 row -> bf16 row copy + 1/||row|| (fat path) ----------
__global__ __launch_bounds__(256) void cvt_rows_norm(const float* __restrict__ X,
                                                     bf16* __restrict__ Xb,
                                                     float* __restrict__ out,
                                                     int M, int K) {
  const int lane = threadIdx.x & 63;
  const int wave = threadIdx.x >> 6;
  const int row = blockIdx.x * 4 + wave;
  if (row >= M) return;
  const float* xr = X + (size_t)row * K;
  bf16* dr = Xb + (size_t)row * K;
  float s = 0.f;
  for (int c = lane * 8; c < K; c += 64 * 8) {
    float4 a = *(const float4*)(xr + c);
    float4 b = *(const float4*)(xr + c + 4);
    s += a.x * a.x + a.y * a.y + a.z * a.z + a.w * a.w;
    s += b.x * b.x + b.y * b.y + b.z * b.z + b.w * b.w;
    Pack8 p;
    p.b[0] = __float2bfloat16(a.x); p.b[1] = __float2bfloat16(a.y);
    p.b[2] = __float2bfloat16(a.z); p.b[3] = __float2bfloat16(a.w);
    p.b[4] = __float2bfloat16(b.x); p.b[5] = __float2bfloat16(b.y);
    p.b[6] = __float2bfloat16(b.z); p.b[7] = __float2bfloat16(b.w);
    *(short8*)(void*)(dr + c) = p.s;
  }
#pragma unroll
  for (int off = 32; off > 0; off >>= 1) s += __shfl_xor(s, off, 64);
  if (lane == 0) out[row] = 1.0f / fmaxf(sqrtf(s), 1e-12f);
}

// ---------------- pack 7 fp32 weight matrices -> one contiguous bf16 region -----
struct WPack {
  const float* src[7];
  int start4[7];  // chunk (float4) start offset of each segment in the concat
  int total4;
};
__global__ __launch_bounds__(256) void cvt_many(WPack p, bf16* __restrict__ dst) {
  int c = blockIdx.x * 256 + threadIdx.x;
  const int stride = gridDim.x * 256;
  for (; c < p.total4; c += stride) {
    int s = 0;
#pragma unroll
    for (int k = 1; k < 7; k++)
      if (c >= p.start4[k]) s = k;
    const float4 v = ((const float4*)p.src[s])[c - p.start4[s]];
    Pack4 q;
    q.b[0] = __float2bfloat16(v.x); q.b[1] = __float2bfloat16(v.y);
    q.b[2] = __float2bfloat16(v.z); q.b[3] = __float2bfloat16(v.w);
    *(short4*)(void*)(dst + (size_t)c * 4) = q.s;
  }
}

// ---------------- NT GEMM: C[M,N] = act(scale_m * (A[M,K] @ B[N,K]^T) + bias[N]) ----
// m97-style 128-tile; bf16 MFMA; bf16 sources staged via global_load_lds(16B);
// fp32 sources converted during LDS staging. C/D layout col=lane&15, row=quad*4+r.
template <int BM, int BN, typename AT, typename BT, typename CT>
__global__ __launch_bounds__(256) void gemm_bt(const AT* __restrict__ A,
                                               const BT* __restrict__ B,
                                               CT* __restrict__ C,
                                               int M, int N, int K,
                                               const float* __restrict__ rowScale,
                                               const float* __restrict__ bias,
                                               int doRelu) {
  constexpr int BK = 32;
  __shared__ __align__(16) bf16 sA[BM * BK];
  __shared__ __align__(16) bf16 sB[BN * BK];
  const int t = threadIdx.x;
  const int lane = t & 63;
  const int wave = t >> 6;
  constexpr int WN = BN / 64;  // waves along N
  const int wm = wave / WN;
  const int wn = wave % WN;
  const int m0 = blockIdx.y * BM;
  const int n0 = blockIdx.x * BN;
  const int lane16 = lane & 15;
  const int quad = lane >> 4;

  floatx4 acc[4][4];
#pragma unroll
  for (int i = 0; i < 4; i++)
#pragma unroll
    for (int j = 0; j < 4; j++) acc[i][j] = (floatx4)0.0f;

  for (int k0 = 0; k0 < K; k0 += BK) {
    // stage A tile: BM rows x 32 bf16 (4 chunks of 8 elems per row)
#pragma unroll
    for (int it = 0; it < BM / 64; ++it) {
      int c = t + 256 * it;
      int row = c >> 2;
      int col = (c & 3) * 8;
      int gr = m0 + row;
      if (gr > M - 1) gr = M - 1;  // clamp: safe re-read, stores are guarded
      if constexpr (std::is_same_v<AT, bf16>) {
        async_cp16(A + (size_t)gr * K + k0 + col, &sA[c * 8]);
      } else {
        const float* src = A + (size_t)gr * K + k0 + col;
        float4 fa = *(const float4*)src;
        float4 fb = *(const float4*)(src + 4);
        Pack8 p;
        p.b[0] = __float2bfloat16(fa.x); p.b[1] = __float2bfloat16(fa.y);
        p.b[2] = __float2bfloat16(fa.z); p.b[3] = __float2bfloat16(fa.w);
        p.b[4] = __float2bfloat16(fb.x); p.b[5] = __float2bfloat16(fb.y);
        p.b[6] = __float2bfloat16(fb.z); p.b[7] = __float2bfloat16(fb.w);
        *(short8*)(void*)&sA[c * 8] = p.s;
      }
    }
    // stage B tile (weights, N rows x K)
#pragma unroll
    for (int it = 0; it < BN / 64; ++it) {
      int c = t + 256 * it;
      int row = c >> 2;
      int col = (c & 3) * 8;
      int gr = n0 + row;
      if (gr > N - 1) gr = N - 1;
      if constexpr (std::is_same_v<BT, bf16>) {
        async_cp16(B + (size_t)gr * K + k0 + col, &sB[c * 8]);
      } else {
        const float* src = B + (size_t)gr * K + k0 + col;
        float4 fa = *(const float4*)src;
        float4 fb = *(const float4*)(src + 4);
        Pack8 p;
        p.b[0] = __float2bfloat16(fa.x); p.b[1] = __float2bfloat16(fa.y);
        p.b[2] = __float2bfloat16(fa.z); p.b[3] = __float2bfloat16(fa.w);
        p.b[4] = __float2bfloat16(fb.x); p.b[5] = __float2bfloat16(fb.y);
        p.b[6] = __float2bfloat16(fb.z); p.b[7] = __float2bfloat16(fb.w);
        *(short8*)(void*)&sB[c * 8] = p.s;
      }
    }
    __syncthreads();

    short8 afr[4], bfr[4];
#pragma unroll
    for (int i = 0; i < 4; i++)
      afr[i] = *(const short8*)(const void*)&sA[(wm * 64 + i * 16 + lane16) * BK + quad * 8];
#pragma unroll
    for (int j = 0; j < 4; j++)
      bfr[j] = *(const short8*)(const void*)&sB[(wn * 64 + j * 16 + lane16) * BK + quad * 8];
#pragma unroll
    for (int i = 0; i < 4; i++)
#pragma unroll
      for (int j = 0; j < 4; j++)
        acc[i][j] = __builtin_amdgcn_mfma_f32_16x16x32_bf16(afr[i], bfr[j], acc[i][j], 0, 0, 0);
    __syncthreads();
  }

  // epilogue
#pragma unroll
  for (int i = 0; i < 4; i++) {
#pragma unroll
    for (int j = 0; j < 4; j++) {
      const int col = n0 + wn * 64 + j * 16 + lane16;
      const float bv = bias[col];
#pragma unroll
      for (int r = 0; r < 4; r++) {
        const int row = m0 + wm * 64 + i * 16 + quad * 4 + r;
        if (row < M) {
          float v = acc[i][j][r];
          if (rowScale) v *= rowScale[row];
          v += bv;
          if (doRelu) v = v > 0.f ? v : 0.f;
          if constexpr (std::is_same_v<CT, bf16>)
            C[(size_t)row * N + col] = __float2bfloat16(v);
          else
            C[(size_t)row * N + col] = v;
        }
      }
    }
  }
}

// ---- per-token/per-item fusion: grid-stride, weights loaded once per block ----
// LDS 52 KB (3 blocks/CU). swc chunk-major: [mat][d4][lane] float4 -> contiguous
// lane addresses, conflict-free. sxn is wave-private (no barrier in token loop).
// seq == nullptr => DENSE mode: idx = token (sequential coalesced reads, no
// random gather latency). __launch_bounds__(256,4) caps VGPRs at 128 so the 3
// LDS-limited blocks/CU (12 waves) actually become resident (was 256 VGPR -> 8).
__global__ __launch_bounds__(256, 4) void fuse_attn2(const int* __restrict__ seq,
                                                     const bf16* __restrict__ c_emb,
                                                     const bf16* __restrict__ t_emb,
                                                     const bf16* __restrict__ cf_emb,
                                                     const float* __restrict__ id_emb,
                                                     const float* __restrict__ wq,
                                                     const float* __restrict__ wk,
                                                     const float* __restrict__ wv,
                                                     float* __restrict__ out, int n_tok) {
  __shared__ __align__(16) float4 swc[3072];  // 48 KB: [mat][d4][j]
  __shared__ float sxn[4][4][64];             // 4 KB: [wave][m][d]
  const int t = threadIdx.x;
  const int lane = t & 63;
  const int wave = t >> 6;

  for (int c = t; c < 3072; c += 256) {
    const int mat = c >> 10, rem = c & 1023, d4 = rem >> 6, j = rem & 63;
    const float* W = (mat == 0) ? wq : (mat == 1 ? wk : wv);
    swc[c] = *(const float4*)(W + j * 64 + d4 * 4);
  }
  __syncthreads();

  const int gw = blockIdx.x * 4 + wave;
  const int gstride = gridDim.x * 4;
  for (int token = gw; token < n_tok; token += gstride) {
    int idx = seq ? seq[token] : token;
    if (idx >= kNumItem || idx < 0) idx = 0;  // ref: padding index NUM_ITEM -> 0

    float x[4];
    x[0] = bf2f(c_emb[(size_t)idx * 64 + lane]);
    x[1] = bf2f(t_emb[(size_t)idx * 64 + lane]);
    x[2] = bf2f(cf_emb[(size_t)idx * 64 + lane]);
    x[3] = id_emb[(size_t)idx * 64 + lane];

#pragma unroll
    for (int m = 0; m < 4; m++) {
      // single 2-value butterfly: sum and sum-of-squares
      float sm = x[m], ss = x[m] * x[m];
#pragma unroll
      for (int off = 32; off > 0; off >>= 1) {
        sm += __shfl_xor(sm, off, 64);
        ss += __shfl_xor(ss, off, 64);
      }
      const float inv = 1.0f / fmaxf(sqrtf(ss), 1e-12f);
      const float xh = x[m] * inv;
      const float mu = sm * inv * (1.0f / 64.0f);
      const float ex2 = ss * inv * inv * (1.0f / 64.0f);
      const float var = ex2 - mu * mu;  // E[x^2] - mu^2
      const float xn = (xh - mu) * rsqrtf(var + 1e-5f);
      x[m] = xn;
      sxn[wave][m][lane] = xn;
    }
    // wave-private LDS round-trip: program order within the wave suffices.

    float q[4] = {0, 0, 0, 0}, kk[4] = {0, 0, 0, 0}, v[4] = {0, 0, 0, 0};
#pragma unroll
    for (int d4 = 0; d4 < 16; d4++) {
      const float4 a = swc[d4 * 64 + lane];
      const float4 b = swc[1024 + d4 * 64 + lane];
      const float4 g = swc[2048 + d4 * 64 + lane];
#pragma unroll
      for (int m = 0; m < 4; m++) {
        const float4 xn4 = *(const float4*)&sxn[wave][m][d4 * 4];
        q[m] += xn4.x * a.x + xn4.y * a.y + xn4.z * a.z + xn4.w * a.w;
        kk[m] += xn4.x * b.x + xn4.y * b.y + xn4.z * b.z + xn4.w * b.w;
        v[m] += xn4.x * g.x + xn4.y * g.y + xn4.z * g.z + xn4.w * g.w;
      }
    }

    // scores s[m][n] = (1/8) sum_j q[m][j] k[n][j]: butterfly-reduce 16 values
    float p[16];
#pragma unroll
    for (int m = 0; m < 4; m++)
#pragma unroll
      for (int n = 0; n < 4; n++) p[m * 4 + n] = q[m] * kk[n];
#pragma unroll
    for (int off = 1; off < 64; off <<= 1)
#pragma unroll
      for (int i = 0; i < 16; i++) p[i] += __shfl_xor(p[i], off, 64);

    float abar[4] = {0, 0, 0, 0};
#pragma unroll
    for (int m = 0; m < 4; m++) {
      float s0 = p[m * 4 + 0] * 0.125f, s1 = p[m * 4 + 1] * 0.125f;
      float s2 = p[m * 4 + 2] * 0.125f, s3 = p[m * 4 + 3] * 0.125f;
      float mx = fmaxf(fmaxf(s0, s1), fmaxf(s2, s3));
      float e0 = expf(s0 - mx), e1 = expf(s1 - mx), e2 = expf(s2 - mx), e3 = expf(s3 - mx);
      float inv = 1.0f / (e0 + e1 + e2 + e3);
      abar[0] += e0 * inv;
      abar[1] += e1 * inv;
      abar[2] += e2 * inv;
      abar[3] += e3 * inv;
    }
    const float o =
        0.25f * (abar[0] * v[0] + abar[1] * v[1] + abar[2] * v[2] + abar[3] * v[3]);
    out[(size_t)token * 64 + lane] = o;
  }
}

// ---- row gather: out[token] = fused[clamp(seq[token])]; 16 lanes x float4/row ----
__global__ __launch_bounds__(256) void gather_out(const int* __restrict__ seq,
                                                  const float* __restrict__ fused,
                                                  float* __restrict__ out, int n_tok) {
  const int gid = blockIdx.x * 256 + threadIdx.x;
  if (gid >= n_tok * 16) return;
  const int token = gid >> 4;
  const int c4 = gid & 15;
  int idx = seq[token];
  if (idx >= kNumItem || idx < 0) idx = 0;
  ((float4*)out)[(size_t)token * 16 + c4] = ((const float4*)fused)[(size_t)idx * 16 + c4];
}

extern "C" void kernel_launch(void* const* d_in, const int* in_sizes, int n_in,
                              void* d_out, int out_size, void* d_ws, size_t ws_size,
                              hipStream_t stream) {
  const int* seq = (const int*)d_in[0];
  const float* content = (const float*)d_in[1];
  const float* text = (const float*)d_in[2];
  const float* cf_feat = (const float*)d_in[3];
  const float* item_emb = (const float*)d_in[4];
  const float* c_w1 = (const float*)d_in[5];
  const float* c_b1 = (const float*)d_in[6];
  const float* c_w2 = (const float*)d_in[7];
  const float* c_b2 = (const float*)d_in[8];
  const float* c_w3 = (const float*)d_in[9];
  const float* c_b3 = (const float*)d_in[10];
  const float* t_w1 = (const float*)d_in[11];
  const float* t_b1 = (const float*)d_in[12];
  const float* t_w2 = (const float*)d_in[13];
  const float* t_b2 = (const float*)d_in[14];
  const float* t_w3 = (const float*)d_in[15];
  const float* t_b3 = (const float*)d_in[16];
  const float* cf_w = (const float*)d_in[17];
  const float* cf_b = (const float*)d_in[18];
  const float* wq = (const float*)d_in[19];
  const float* wk = (const float*)d_in[20];
  const float* wv = (const float*)d_in[21];
  float* out = (float*)d_out;

  const int M = kNumItem;         // 50000
  const int n_tok = in_sizes[0];  // 51200

  // ---- workspace carve-up (ws_size-tiered) ----
  char* w = (char*)d_ws;
  size_t off = 0;
  auto alloc = [&](size_t bytes) -> void* {
    void* p = w + off;
    off += (bytes + 255) & ~(size_t)255;
    return p;
  };
  float* invn_c = (float*)alloc((size_t)M * 4);
  float* invn_t = (float*)alloc((size_t)M * 4);
  bf16* c_emb = (bf16*)alloc((size_t)M * 64 * 2);
  bf16* t_emb = (bf16*)alloc((size_t)M * 64 * 2);
  bf16* cf_emb = (bf16*)alloc((size_t)M * 64 * 2);
  bf16* H1 = (bf16*)alloc((size_t)M * 1024 * 2);  // reused by text chain
  bf16* H2 = (bf16*)alloc((size_t)M * 256 * 2);

  // bf16 weight pack: c_w1,c_w2,c_w3,t_w1,t_w2,t_w3,cf_w concatenated
  const int nw[7] = {1024 * 1024, 256 * 1024, 64 * 256, 768 * 768, 256 * 768, 64 * 256, 64 * 64};
  int wofs[8];
  wofs[0] = 0;
  for (int i = 0; i < 7; i++) wofs[i + 1] = wofs[i] + nw[i];
  bf16* Wb = (bf16*)alloc((size_t)wofs[7] * 2);
  const bool useWb = (off <= ws_size);
  bf16* Ab = (bf16*)alloc((size_t)M * 1024 * 2);  // bf16 copy of content/text (reused)
  const bool useAb = useWb && (off <= ws_size);
  // dense fused-embedding table: out[token] = fusedTab[seq[token]]
  float* fusedTab = (float*)alloc((size_t)M * 64 * 4);
  const bool useFused = (off <= ws_size);

  if (useWb) {
    WPack p;
    for (int i = 0; i < 7; i++) {
      const float* srcs[7] = {c_w1, c_w2, c_w3, t_w1, t_w2, t_w3, cf_w};
      p.src[i] = srcs[i];
      p.start4[i] = wofs[i] / 4;
    }
    p.total4 = wofs[7] / 4;
    cvt_many<<<dim3(2048), dim3(256), 0, stream>>>(p, Wb);
  }

  if (useAb) {
    // ---- fat path: bf16 A + bf16 B everywhere big ----
    cvt_rows_norm<<<dim3((M + 3) / 4), dim3(256), 0, stream>>>(content, Ab, invn_c, M, 1024);
    gemm_bt<128, 128, bf16, bf16, bf16>
        <<<dim3(1024 / 128, (M + 127) / 128), dim3(256), 0, stream>>>(
            Ab, Wb + wofs[0], H1, M, 1024, 1024, invn_c, c_b1, 1);
    gemm_bt<128, 128, bf16, bf16, bf16>
        <<<dim3(256 / 128, (M + 127) / 128), dim3(256), 0, stream>>>(
            H1, Wb + wofs[1], H2, M, 256, 1024, nullptr, c_b2, 1);
    gemm_bt<256, 64, bf16, bf16, bf16>
        <<<dim3(1, (M + 255) / 256), dim3(256), 0, stream>>>(
            H2, Wb + wofs[2], c_emb, M, 64, 256, nullptr, c_b3, 0);

    cvt_rows_norm<<<dim3((M + 3) / 4), dim3(256), 0, stream>>>(text, Ab, invn_t, M, 768);
    gemm_bt<128, 128, bf16, bf16, bf16>
        <<<dim3(768 / 128, (M + 127) / 128), dim3(256), 0, stream>>>(
            Ab, Wb + wofs[3], H1, M, 768, 768, invn_t, t_b1, 1);
    gemm_bt<128, 128, bf16, bf16, bf16>
        <<<dim3(256 / 128, (M + 127) / 128), dim3(256), 0, stream>>>(
            H1, Wb + wofs[4], H2, M, 256, 768, nullptr, t_b2, 1);
    gemm_bt<256, 64, bf16, bf16, bf16>
        <<<dim3(1, (M + 255) / 256), dim3(256), 0, stream>>>(
            H2, Wb + wofs[5], t_emb, M, 64, 256, nullptr, t_b3, 0);

    gemm_bt<256, 64, float, bf16, bf16>
        <<<dim3(1, (M + 255) / 256), dim3(256), 0, stream>>>(
            cf_feat, Wb + wofs[6], cf_emb, M, 64, 64, nullptr, cf_b, 0);
  } else if (useWb) {
    // ---- slim path: fp32 A (packed in-kernel) + bf16 B ----
    row_invnorm<<<dim3((M + 3) / 4), dim3(256), 0, stream>>>(content, invn_c, M, 1024);
    row_invnorm<<<dim3((M + 3) / 4), dim3(256), 0, stream>>>(text, invn_t, M, 768);
    gemm_bt<128, 128, float, bf16, bf16>
        <<<dim3(1024 / 128, (M + 127) / 128), dim3(256), 0, stream>>>(
            content, Wb + wofs[0], H1, M, 1024, 1024, invn_c, c_b1, 1);
    gemm_bt<128, 128, bf16, bf16, bf16>
        <<<dim3(256 / 128, (M + 127) / 128), dim3(256), 0, stream>>>(
            H1, Wb + wofs[1], H2, M, 256, 1024, nullptr, c_b2, 1);
    gemm_bt<256, 64, bf16, bf16, bf16>
        <<<dim3(1, (M + 255) / 256), dim3(256), 0, stream>>>(
            H2, Wb + wofs[2], c_emb, M, 64, 256, nullptr, c_b3, 0);
    gemm_bt<128, 128, float, bf16, bf16>
        <<<dim3(768 / 128, (M + 127) / 128), dim3(256), 0, stream>>>(
            text, Wb + wofs[3], H1, M, 768, 768, invn_t, t_b1, 1);
    gemm_bt<128, 128, bf16, bf16, bf16>
        <<<dim3(256 / 128, (M + 127) / 128), dim3(256), 0, stream>>>(
            H1, Wb + wofs[4], H2, M, 256, 768, nullptr, t_b2, 1);
    gemm_bt<256, 64, bf16, bf16, bf16>
        <<<dim3(1, (M + 255) / 256), dim3(256), 0, stream>>>(
            H2, Wb + wofs[5], t_emb, M, 64, 256, nullptr, t_b3, 0);
    gemm_bt<256, 64, float, bf16, bf16>
        <<<dim3(1, (M + 255) / 256), dim3(256), 0, stream>>>(
            cf_feat, Wb + wofs[6], cf_emb, M, 64, 64, nullptr, cf_b, 0);
  } else {
    // ---- minimal path (round-2 behavior): fp32 A and B ----
    row_invnorm<<<dim3((M + 3) / 4), dim3(256), 0, stream>>>(content, invn_c, M, 1024);
    row_invnorm<<<dim3((M + 3) / 4), dim3(256), 0, stream>>>(text, invn_t, M, 768);
    gemm_bt<128, 128, float, float, bf16>
        <<<dim3(1024 / 128, (M + 127) / 128), dim3(256), 0, stream>>>(
            content, c_w1, H1, M, 1024, 1024, invn_c, c_b1, 1);
    gemm_bt<128, 128, bf16, float, bf16>
        <<<dim3(256 / 128, (M + 127) / 128), dim3(256), 0, stream>>>(
            H1, c_w2, H2, M, 256, 1024, nullptr, c_b2, 1);
    gemm_bt<256, 64, bf16, float, bf16>
        <<<dim3(1, (M + 255) / 256), dim3(256), 0, stream>>>(
            H2, c_w3, c_emb, M, 64, 256, nullptr, c_b3, 0);
    gemm_bt<128, 128, float, float, bf16>
        <<<dim3(768 / 128, (M + 127) / 128), dim3(256), 0, stream>>>(
            text, t_w1, H1, M, 768, 768, invn_t, t_b1, 1);
    gemm_bt<128, 128, bf16, float, bf16>
        <<<dim3(256 / 128, (M + 127) / 128), dim3(256), 0, stream>>>(
            H1, t_w2, H2, M, 256, 768, nullptr, t_b2, 1);
    gemm_bt<256, 64, bf16, float, bf16>
        <<<dim3(1, (M + 255) / 256), dim3(256), 0, stream>>>(
            H2, t_w3, t_emb, M, 64, 256, nullptr, t_b3, 0);
    gemm_bt<256, 64, float, float, bf16>
        <<<dim3(1, (M + 255) / 256), dim3(256), 0, stream>>>(
            cf_feat, cf_w, cf_emb, M, 64, 64, nullptr, cf_b, 0);
  }

  if (useFused) {
    // ---- dense fuse over all 50000 items (sequential, coalesced; no gather
    // latency chain), then trivial row gather into token order ----
    fuse_attn2<<<dim3(768), dim3(256), 0, stream>>>(
        nullptr, c_emb, t_emb, cf_emb, item_emb, wq, wk, wv, fusedTab, M);
    gather_out<<<dim3((n_tok * 16 + 255) / 256), dim3(256), 0, stream>>>(
        seq, fusedTab, out, n_tok);
  } else {
    // fallback: token-wise fuse with random gathers (previous behavior)
    fuse_attn2<<<dim3(768), dim3(256), 0, stream>>>(
        seq, c_emb, t_emb, cf_emb, item_emb, wq, wk, wv, out, n_tok);
  }
}

// Round 2
// 1124.164 us; speedup vs baseline: 1.2620x; 1.2198x over previous
//
#include <hip/hip_runtime.h>
#include <hip/hip_bf16.h>
#include <type_traits>

typedef __hip_bfloat16 bf16;
typedef __attribute__((ext_vector_type(8))) short short8;
typedef __attribute__((ext_vector_type(4))) float floatx4;

static constexpr int kNumItem = 50000;

__device__ __forceinline__ float bf2f(const bf16 x) { return __bfloat162float(x); }

union alignas(16) Pack8 {
  bf16 b[8];
  short8 s;
};
union alignas(8) Pack4 {
  bf16 b[4];
  short4 s;
};

__device__ __forceinline__ void async_cp16(const void* g, void* l) {
  __builtin_amdgcn_global_load_lds((const __attribute__((address_space(1))) void*)g,
                                   (__attribute__((address_space(3))) void*)l, 16, 0, 0);
}

// ---------------- per-row 1/max(||x||,1e-12), fp32 input (slim path) ------------
__global__ __launch_bounds__(256) void row_invnorm(const float* __restrict__ X,
                                                   float* __restrict__ out,
                                                   int M, int K) {
  const int lane = threadIdx.x & 63;
  const int wave = threadIdx.x >> 6;
  const int row = blockIdx.x * 4 + wave;
  if (row >= M) return;
  const float* xr = X + (size_t)row * K;
  float s = 0.f;
  for (int c = lane * 8; c < K; c += 64 * 8) {
    float4 a = *(const float4*)(xr + c);
    float4 b = *(const float4*)(xr + c + 4);
    s += a.x * a.x + a.y * a.y + a.z * a.z + a.w * a.w;
    s += b.x * b.x + b.y * b.y + b.z * b.z + b.w * b.w;
  }
#pragma unroll
  for (int off = 32; off > 0; off >>= 1) s += __shfl_xor(s, off, 64);
  if (lane == 0) out[row] = 1.0f / fmaxf(sqrtf(s), 1e-12f);
}

// ------------- fused: fp32 row -> bf16 row copy + 1/||row|| (fat path) ----------
__global__ __launch_bounds__(256) void cvt_rows_norm(const float* __restrict__ X,
                                                     bf16* __restrict__ Xb,
                                                     float* __restrict__ out,
                                                     int M, int K) {
  const int lane = threadIdx.x & 63;
  const int wave = threadIdx.x >> 6;
  const int row = blockIdx.x * 4 + wave;
  if (row >= M) return;
  const float* xr = X + (size_t)row * K;
  bf16* dr = Xb + (size_t)row * K;
  float s = 0.f;
  for (int c = lane * 8; c < K; c += 64 * 8) {
    float4 a = *(const float4*)(xr + c);
    float4 b = *(const float4*)(xr + c + 4);
    s += a.x * a.x + a.y * a.y + a.z * a.z + a.w * a.w;
    s += b.x * b.x + b.y * b.y + b.z * b.z + b.w * b.w;
    Pack8 p;
    p.b[0] = __float2bfloat16(a.x); p.b[1] = __float2bfloat16(a.y);
    p.b[2] = __float2bfloat16(a.z); p.b[3] = __float2bfloat16(a.w);
    p.b[4] = __float2bfloat16(b.x); p.b[5] = __float2bfloat16(b.y);
    p.b[6] = __float2bfloat16(b.z); p.b[7] = __float2bfloat16(b.w);
    *(short8*)(void*)(dr + c) = p.s;
  }
#pragma unroll
  for (int off = 32; off > 0; off >>= 1) s += __shfl_xor(s, off, 64);
  if (lane == 0) out[row] = 1.0f / fmaxf(sqrtf(s), 1e-12f);
}

// ---------------- pack 10 fp32 weight matrices -> one contiguous bf16 region ----
static constexpr int kNWSeg = 10;
struct WPack {
  const float* src[kNWSeg];
  int start4[kNWSeg];  // chunk (float4) start offset of each segment in the concat
  int total4;
};
__global__ __launch_bounds__(256) void cvt_many(WPack p, bf16* __restrict__ dst) {
  int c = blockIdx.x * 256 + threadIdx.x;
  const int stride = gridDim.x * 256;
  for (; c < p.total4; c += stride) {
    int s = 0;
#pragma unroll
    for (int k = 1; k < kNWSeg; k++)
      if (c >= p.start4[k]) s = k;
    const float4 v = ((const float4*)p.src[s])[c - p.start4[s]];
    Pack4 q;
    q.b[0] = __float2bfloat16(v.x); q.b[1] = __float2bfloat16(v.y);
    q.b[2] = __float2bfloat16(v.z); q.b[3] = __float2bfloat16(v.w);
    *(short4*)(void*)(dst + (size_t)c * 4) = q.s;
  }
}

// ---------------- NT GEMM: C[M,N] = act(scale_m * (A[M,K] @ B[N,K]^T) + bias[N]) ----
// m97-style 128-tile; bf16 MFMA; bf16 sources staged via global_load_lds(16B);
// fp32 sources converted during LDS staging. C/D layout col=lane&15, row=quad*4+r.
template <int BM, int BN, typename AT, typename BT, typename CT>
__global__ __launch_bounds__(256) void gemm_bt(const AT* __restrict__ A,
                                               const BT* __restrict__ B,
                                               CT* __restrict__ C,
                                               int M, int N, int K,
                                               const float* __restrict__ rowScale,
                                               const float* __restrict__ bias,
                                               int doRelu) {
  constexpr int BK = 32;
  __shared__ __align__(16) bf16 sA[BM * BK];
  __shared__ __align__(16) bf16 sB[BN * BK];
  const int t = threadIdx.x;
  const int lane = t & 63;
  const int wave = t >> 6;
  constexpr int WN = BN / 64;  // waves along N
  const int wm = wave / WN;
  const int wn = wave % WN;
  const int m0 = blockIdx.y * BM;
  const int n0 = blockIdx.x * BN;
  const int lane16 = lane & 15;
  const int quad = lane >> 4;

  floatx4 acc[4][4];
#pragma unroll
  for (int i = 0; i < 4; i++)
#pragma unroll
    for (int j = 0; j < 4; j++) acc[i][j] = (floatx4)0.0f;

  for (int k0 = 0; k0 < K; k0 += BK) {
    // stage A tile: BM rows x 32 bf16 (4 chunks of 8 elems per row)
#pragma unroll
    for (int it = 0; it < BM / 64; ++it) {
      int c = t + 256 * it;
      int row = c >> 2;
      int col = (c & 3) * 8;
      int gr = m0 + row;
      if (gr > M - 1) gr = M - 1;  // clamp: safe re-read, stores are guarded
      if constexpr (std::is_same_v<AT, bf16>) {
        async_cp16(A + (size_t)gr * K + k0 + col, &sA[c * 8]);
      } else {
        const float* src = A + (size_t)gr * K + k0 + col;
        float4 fa = *(const float4*)src;
        float4 fb = *(const float4*)(src + 4);
        Pack8 p;
        p.b[0] = __float2bfloat16(fa.x); p.b[1] = __float2bfloat16(fa.y);
        p.b[2] = __float2bfloat16(fa.z); p.b[3] = __float2bfloat16(fa.w);
        p.b[4] = __float2bfloat16(fb.x); p.b[5] = __float2bfloat16(fb.y);
        p.b[6] = __float2bfloat16(fb.z); p.b[7] = __float2bfloat16(fb.w);
        *(short8*)(void*)&sA[c * 8] = p.s;
      }
    }
    // stage B tile (weights, N rows x K)
#pragma unroll
    for (int it = 0; it < BN / 64; ++it) {
      int c = t + 256 * it;
      int row = c >> 2;
      int col = (c & 3) * 8;
      int gr = n0 + row;
      if (gr > N - 1) gr = N - 1;
      if constexpr (std::is_same_v<BT, bf16>) {
        async_cp16(B + (size_t)gr * K + k0 + col, &sB[c * 8]);
      } else {
        const float* src = B + (size_t)gr * K + k0 + col;
        float4 fa = *(const float4*)src;
        float4 fb = *(const float4*)(src + 4);
        Pack8 p;
        p.b[0] = __float2bfloat16(fa.x); p.b[1] = __float2bfloat16(fa.y);
        p.b[2] = __float2bfloat16(fa.z); p.b[3] = __float2bfloat16(fa.w);
        p.b[4] = __float2bfloat16(fb.x); p.b[5] = __float2bfloat16(fb.y);
        p.b[6] = __float2bfloat16(fb.z); p.b[7] = __float2bfloat16(fb.w);
        *(short8*)(void*)&sB[c * 8] = p.s;
      }
    }
    __syncthreads();

    short8 afr[4], bfr[4];
#pragma unroll
    for (int i = 0; i < 4; i++)
      afr[i] = *(const short8*)(const void*)&sA[(wm * 64 + i * 16 + lane16) * BK + quad * 8];
#pragma unroll
    for (int j = 0; j < 4; j++)
      bfr[j] = *(const short8*)(const void*)&sB[(wn * 64 + j * 16 + lane16) * BK + quad * 8];
#pragma unroll
    for (int i = 0; i < 4; i++)
#pragma unroll
      for (int j = 0; j < 4; j++)
        acc[i][j] = __builtin_amdgcn_mfma_f32_16x16x32_bf16(afr[i], bfr[j], acc[i][j], 0, 0, 0);
    __syncthreads();
  }

  // epilogue
#pragma unroll
  for (int i = 0; i < 4; i++) {
#pragma unroll
    for (int j = 0; j < 4; j++) {
      const int col = n0 + wn * 64 + j * 16 + lane16;
      const float bv = bias ? bias[col] : 0.f;
#pragma unroll
      for (int r = 0; r < 4; r++) {
        const int row = m0 + wm * 64 + i * 16 + quad * 4 + r;
        if (row < M) {
          float v = acc[i][j][r];
          if (rowScale) v *= rowScale[row];
          v += bv;
          if (doRelu) v = v > 0.f ? v : 0.f;
          if constexpr (std::is_same_v<CT, bf16>)
            C[(size_t)row * N + col] = __float2bfloat16(v);
          else
            C[(size_t)row * N + col] = v;
        }
      }
    }
  }
}

// ---- l2norm + LayerNorm per (item,modal) row: 16 lanes/row, 4-stage butterfly ----
// Xn[row=item*4+m][64] bf16. Rows read from the 4 modality tables.
__global__ __launch_bounds__(256) void norm_ln(const bf16* __restrict__ c_emb,
                                               const bf16* __restrict__ t_emb,
                                               const bf16* __restrict__ cf_emb,
                                               const float* __restrict__ id_emb,
                                               bf16* __restrict__ Xn, int nItem) {
  const int gid = blockIdx.x * 256 + threadIdx.x;
  const int row = gid >> 4;
  const int d4 = gid & 15;
  if (row >= nItem * 4) return;
  const int item = row >> 2;
  const int m = row & 3;

  float x[4];
  if (m == 3) {
    const float4 f = *(const float4*)(id_emb + (size_t)item * 64 + d4 * 4);
    x[0] = f.x; x[1] = f.y; x[2] = f.z; x[3] = f.w;
  } else {
    const bf16* src = (m == 0) ? c_emb : (m == 1 ? t_emb : cf_emb);
    Pack4 p;
    p.s = *(const short4*)(const void*)(src + (size_t)item * 64 + d4 * 4);
    x[0] = bf2f(p.b[0]); x[1] = bf2f(p.b[1]); x[2] = bf2f(p.b[2]); x[3] = bf2f(p.b[3]);
  }

  float sm = x[0] + x[1] + x[2] + x[3];
  float ss = x[0] * x[0] + x[1] * x[1] + x[2] * x[2] + x[3] * x[3];
#pragma unroll
  for (int off = 1; off < 16; off <<= 1) {
    sm += __shfl_xor(sm, off, 64);
    ss += __shfl_xor(ss, off, 64);
  }
  const float inv = 1.0f / fmaxf(sqrtf(ss), 1e-12f);
  const float mu = sm * inv * (1.0f / 64.0f);
  const float ex2 = ss * inv * inv * (1.0f / 64.0f);
  const float var = ex2 - mu * mu;
  const float rs = rsqrtf(var + 1e-5f);

  Pack4 o;
#pragma unroll
  for (int c = 0; c < 4; c++) o.b[c] = __float2bfloat16((x[c] * inv - mu) * rs);
  *(short4*)(void*)(Xn + (size_t)row * 64 + d4 * 4) = o.s;
}

// ---- tiny attention: 4 items/wave, 16 lanes/item (lane = sub*16 + d4) ----------
// Q,K,V fp32 [nItem*4, 64]; out fp32 [nItem, 64]. Scores via 4-stage butterfly.
__global__ __launch_bounds__(256) void attn4(const float* __restrict__ Q,
                                             const float* __restrict__ K,
                                             const float* __restrict__ V,
                                             float* __restrict__ out, int nGroup) {
  const int t = threadIdx.x;
  const int wave = t >> 6;
  const int lane = t & 63;
  const int sub = lane >> 4;
  const int d4 = lane & 15;
  const int group = blockIdx.x * 4 + wave;
  if (group >= nGroup) return;
  const int item = group * 4 + sub;
  const size_t rb = (size_t)item * 4;

  float4 q4[4], k4[4], v4[4];
#pragma unroll
  for (int m = 0; m < 4; m++) {
    q4[m] = *(const float4*)(Q + (rb + m) * 64 + d4 * 4);
    k4[m] = *(const float4*)(K + (rb + m) * 64 + d4 * 4);
    v4[m] = *(const float4*)(V + (rb + m) * 64 + d4 * 4);
  }

  // per-lane partial dot over its 4 d's, then 4-stage butterfly within 16 lanes
  float p[16];
#pragma unroll
  for (int m = 0; m < 4; m++)
#pragma unroll
    for (int n = 0; n < 4; n++)
      p[m * 4 + n] = q4[m].x * k4[n].x + q4[m].y * k4[n].y +
                     q4[m].z * k4[n].z + q4[m].w * k4[n].w;
#pragma unroll
  for (int off = 1; off < 16; off <<= 1)
#pragma unroll
    for (int i = 0; i < 16; i++) p[i] += __shfl_xor(p[i], off, 64);

  float abar[4] = {0, 0, 0, 0};
#pragma unroll
  for (int m = 0; m < 4; m++) {
    const float s0 = p[m * 4 + 0] * 0.125f, s1 = p[m * 4 + 1] * 0.125f;
    const float s2 = p[m * 4 + 2] * 0.125f, s3 = p[m * 4 + 3] * 0.125f;
    const float mx = fmaxf(fmaxf(s0, s1), fmaxf(s2, s3));
    const float e0 = expf(s0 - mx), e1 = expf(s1 - mx);
    const float e2 = expf(s2 - mx), e3 = expf(s3 - mx);
    const float inv = 1.0f / (e0 + e1 + e2 + e3);
    abar[0] += e0 * inv;
    abar[1] += e1 * inv;
    abar[2] += e2 * inv;
    abar[3] += e3 * inv;
  }

  float4 o;
  o.x = 0.25f * (abar[0] * v4[0].x + abar[1] * v4[1].x + abar[2] * v4[2].x + abar[3] * v4[3].x);
  o.y = 0.25f * (abar[0] * v4[0].y + abar[1] * v4[1].y + abar[2] * v4[2].y + abar[3] * v4[3].y);
  o.z = 0.25f * (abar[0] * v4[0].z + abar[1] * v4[1].z + abar[2] * v4[2].z + abar[3] * v4[3].z);
  o.w = 0.25f * (abar[0] * v4[0].w + abar[1] * v4[1].w + abar[2] * v4[2].w + abar[3] * v4[3].w);
  *(float4*)(out + (size_t)item * 64 + d4 * 4) = o;
}

// ---- per-token/per-item fusion (FALLBACK path only) ----------------------------
__global__ __launch_bounds__(256, 4) void fuse_attn2(const int* __restrict__ seq,
                                                     const bf16* __restrict__ c_emb,
                                                     const bf16* __restrict__ t_emb,
                                                     const bf16* __restrict__ cf_emb,
                                                     const float* __restrict__ id_emb,
                                                     const float* __restrict__ wq,
                                                     const float* __restrict__ wk,
                                                     const float* __restrict__ wv,
                                                     float* __restrict__ out, int n_tok) {
  __shared__ __align__(16) float4 swc[3072];  // 48 KB: [mat][d4][j]
  __shared__ float sxn[4][4][64];             // 4 KB: [wave][m][d]
  const int t = threadIdx.x;
  const int lane = t & 63;
  const int wave = t >> 6;

  for (int c = t; c < 3072; c += 256) {
    const int mat = c >> 10, rem = c & 1023, d4 = rem >> 6, j = rem & 63;
    const float* W = (mat == 0) ? wq : (mat == 1 ? wk : wv);
    swc[c] = *(const float4*)(W + j * 64 + d4 * 4);
  }
  __syncthreads();

  const int gw = blockIdx.x * 4 + wave;
  const int gstride = gridDim.x * 4;
  for (int token = gw; token < n_tok; token += gstride) {
    int idx = seq ? seq[token] : token;
    if (idx >= kNumItem || idx < 0) idx = 0;

    float x[4];
    x[0] = bf2f(c_emb[(size_t)idx * 64 + lane]);
    x[1] = bf2f(t_emb[(size_t)idx * 64 + lane]);
    x[2] = bf2f(cf_emb[(size_t)idx * 64 + lane]);
    x[3] = id_emb[(size_t)idx * 64 + lane];

#pragma unroll
    for (int m = 0; m < 4; m++) {
      float sm = x[m], ss = x[m] * x[m];
#pragma unroll
      for (int off = 32; off > 0; off >>= 1) {
        sm += __shfl_xor(sm, off, 64);
        ss += __shfl_xor(ss, off, 64);
      }
      const float inv = 1.0f / fmaxf(sqrtf(ss), 1e-12f);
      const float xh = x[m] * inv;
      const float mu = sm * inv * (1.0f / 64.0f);
      const float ex2 = ss * inv * inv * (1.0f / 64.0f);
      const float var = ex2 - mu * mu;
      const float xn = (xh - mu) * rsqrtf(var + 1e-5f);
      x[m] = xn;
      sxn[wave][m][lane] = xn;
    }

    float q[4] = {0, 0, 0, 0}, kk[4] = {0, 0, 0, 0}, v[4] = {0, 0, 0, 0};
#pragma unroll
    for (int d4 = 0; d4 < 16; d4++) {
      const float4 a = swc[d4 * 64 + lane];
      const float4 b = swc[1024 + d4 * 64 + lane];
      const float4 g = swc[2048 + d4 * 64 + lane];
#pragma unroll
      for (int m = 0; m < 4; m++) {
        const float4 xn4 = *(const float4*)&sxn[wave][m][d4 * 4];
        q[m] += xn4.x * a.x + xn4.y * a.y + xn4.z * a.z + xn4.w * a.w;
        kk[m] += xn4.x * b.x + xn4.y * b.y + xn4.z * b.z + xn4.w * b.w;
        v[m] += xn4.x * g.x + xn4.y * g.y + xn4.z * g.z + xn4.w * g.w;
      }
    }

    float p[16];
#pragma unroll
    for (int m = 0; m < 4; m++)
#pragma unroll
      for (int n = 0; n < 4; n++) p[m * 4 + n] = q[m] * kk[n];
#pragma unroll
    for (int off = 1; off < 64; off <<= 1)
#pragma unroll
      for (int i = 0; i < 16; i++) p[i] += __shfl_xor(p[i], off, 64);

    float abar[4] = {0, 0, 0, 0};
#pragma unroll
    for (int m = 0; m < 4; m++) {
      float s0 = p[m * 4 + 0] * 0.125f, s1 = p[m * 4 + 1] * 0.125f;
      float s2 = p[m * 4 + 2] * 0.125f, s3 = p[m * 4 + 3] * 0.125f;
      float mx = fmaxf(fmaxf(s0, s1), fmaxf(s2, s3));
      float e0 = expf(s0 - mx), e1 = expf(s1 - mx), e2 = expf(s2 - mx), e3 = expf(s3 - mx);
      float inv = 1.0f / (e0 + e1 + e2 + e3);
      abar[0] += e0 * inv;
      abar[1] += e1 * inv;
      abar[2] += e2 * inv;
      abar[3] += e3 * inv;
    }
    const float o =
        0.25f * (abar[0] * v[0] + abar[1] * v[1] + abar[2] * v[2] + abar[3] * v[3]);
    out[(size_t)token * 64 + lane] = o;
  }
}

// ---- row gather: out[token] = fused[clamp(seq[token])]; 16 lanes x float4/row ----
__global__ __launch_bounds__(256) void gather_out(const int* __restrict__ seq,
                                                  const float* __restrict__ fused,
                                                  float* __restrict__ out, int n_tok) {
  const int gid = blockIdx.x * 256 + threadIdx.x;
  if (gid >= n_tok * 16) return;
  const int token = gid >> 4;
  const int c4 = gid & 15;
  int idx = seq[token];
  if (idx >= kNumItem || idx < 0) idx = 0;
  ((float4*)out)[(size_t)token * 16 + c4] = ((const float4*)fused)[(size_t)idx * 16 + c4];
}

extern "C" void kernel_launch(void* const* d_in, const int* in_sizes, int n_in,
                              void* d_out, int out_size, void* d_ws, size_t ws_size,
                              hipStream_t stream) {
  const int* seq = (const int*)d_in[0];
  const float* content = (const float*)d_in[1];
  const float* text = (const float*)d_in[2];
  const float* cf_feat = (const float*)d_in[3];
  const float* item_emb = (const float*)d_in[4];
  const float* c_w1 = (const float*)d_in[5];
  const float* c_b1 = (const float*)d_in[6];
  const float* c_w2 = (const float*)d_in[7];
  const float* c_b2 = (const float*)d_in[8];
  const float* c_w3 = (const float*)d_in[9];
  const float* c_b3 = (const float*)d_in[10];
  const float* t_w1 = (const float*)d_in[11];
  const float* t_b1 = (const float*)d_in[12];
  const float* t_w2 = (const float*)d_in[13];
  const float* t_b2 = (const float*)d_in[14];
  const float* t_w3 = (const float*)d_in[15];
  const float* t_b3 = (const float*)d_in[16];
  const float* cf_w = (const float*)d_in[17];
  const float* cf_b = (const float*)d_in[18];
  const float* wq = (const float*)d_in[19];
  const float* wk = (const float*)d_in[20];
  const float* wv = (const float*)d_in[21];
  float* out = (float*)d_out;

  const int M = kNumItem;         // 50000
  const int n_tok = in_sizes[0];  // 51200

  // ---- workspace carve-up (ws_size-tiered) ----
  char* w = (char*)d_ws;
  size_t off = 0;
  auto alloc = [&](size_t bytes) -> void* {
    void* p = w + off;
    off += (bytes + 255) & ~(size_t)255;
    return p;
  };
  float* invn_c = (float*)alloc((size_t)M * 4);
  float* invn_t = (float*)alloc((size_t)M * 4);
  bf16* c_emb = (bf16*)alloc((size_t)M * 64 * 2);
  bf16* t_emb = (bf16*)alloc((size_t)M * 64 * 2);
  bf16* cf_emb = (bf16*)alloc((size_t)M * 64 * 2);
  bf16* H1 = (bf16*)alloc((size_t)M * 1024 * 2);  // reused by text chain, then Q|K
  bf16* H2 = (bf16*)alloc((size_t)M * 256 * 2);

  // bf16 weight pack: c_w1,c_w2,c_w3,t_w1,t_w2,t_w3,cf_w,wq,wk,wv concatenated
  const int nw[kNWSeg] = {1024 * 1024, 256 * 1024, 64 * 256, 768 * 768, 256 * 768,
                          64 * 256,    64 * 64,    64 * 64,  64 * 64,   64 * 64};
  int wofs[kNWSeg + 1];
  wofs[0] = 0;
  for (int i = 0; i < kNWSeg; i++) wofs[i + 1] = wofs[i] + nw[i];
  bf16* Wb = (bf16*)alloc((size_t)wofs[kNWSeg] * 2);
  const bool useWb = (off <= ws_size);
  bf16* Ab = (bf16*)alloc((size_t)M * 1024 * 2);  // bf16 copy of content/text; then Xn|V
  const bool useAb = useWb && (off <= ws_size);
  // dense fused-embedding table: out[token] = fusedTab[seq[token]]
  float* fusedTab = (float*)alloc((size_t)M * 64 * 4);
  const bool useFused = (off <= ws_size);

  // aliases for the attention pipeline (regions free by the time they're used):
  const int R = M * 4;                                 // 200000 (item,modal) rows
  bf16* Xn = (bf16*)Ab;                                // 25.6 MB
  float* Vbuf = (float*)((char*)Ab + (size_t)R * 64 * 2);   // 51.2 MB (in Ab)
  float* Qbuf = (float*)H1;                            // 51.2 MB
  float* Kbuf = (float*)((char*)H1 + (size_t)R * 64 * 4);   // 51.2 MB (H1 = 102.4 MB)

  if (useWb) {
    WPack p;
    const float* srcs[kNWSeg] = {c_w1, c_w2, c_w3, t_w1, t_w2, t_w3, cf_w, wq, wk, wv};
    for (int i = 0; i < kNWSeg; i++) {
      p.src[i] = srcs[i];
      p.start4[i] = wofs[i] / 4;
    }
    p.total4 = wofs[kNWSeg] / 4;
    cvt_many<<<dim3(2048), dim3(256), 0, stream>>>(p, Wb);
  }

  if (useAb) {
    // ---- fat path: bf16 A + bf16 B everywhere big ----
    cvt_rows_norm<<<dim3((M + 3) / 4), dim3(256), 0, stream>>>(content, Ab, invn_c, M, 1024);
    gemm_bt<128, 128, bf16, bf16, bf16>
        <<<dim3(1024 / 128, (M + 127) / 128), dim3(256), 0, stream>>>(
            Ab, Wb + wofs[0], H1, M, 1024, 1024, invn_c, c_b1, 1);
    gemm_bt<128, 128, bf16, bf16, bf16>
        <<<dim3(256 / 128, (M + 127) / 128), dim3(256), 0, stream>>>(
            H1, Wb + wofs[1], H2, M, 256, 1024, nullptr, c_b2, 1);
    gemm_bt<256, 64, bf16, bf16, bf16>
        <<<dim3(1, (M + 255) / 256), dim3(256), 0, stream>>>(
            H2, Wb + wofs[2], c_emb, M, 64, 256, nullptr, c_b3, 0);

    cvt_rows_norm<<<dim3((M + 3) / 4), dim3(256), 0, stream>>>(text, Ab, invn_t, M, 768);
    gemm_bt<128, 128, bf16, bf16, bf16>
        <<<dim3(768 / 128, (M + 127) / 128), dim3(256), 0, stream>>>(
            Ab, Wb + wofs[3], H1, M, 768, 768, invn_t, t_b1, 1);
    gemm_bt<128, 128, bf16, bf16, bf16>
        <<<dim3(256 / 128, (M + 127) / 128), dim3(256), 0, stream>>>(
            H1, Wb + wofs[4], H2, M, 256, 768, nullptr, t_b2, 1);
    gemm_bt<256, 64, bf16, bf16, bf16>
        <<<dim3(1, (M + 255) / 256), dim3(256), 0, stream>>>(
            H2, Wb + wofs[5], t_emb, M, 64, 256, nullptr, t_b3, 0);

    gemm_bt<256, 64, float, bf16, bf16>
        <<<dim3(1, (M + 255) / 256), dim3(256), 0, stream>>>(
            cf_feat, Wb + wofs[6], cf_emb, M, 64, 64, nullptr, cf_b, 0);

    // ---- attention pipeline: norm+LN -> QKV GEMMs (fp32 out) -> tiny attn ----
    // H1 (Q|K), Ab (Xn|V), H2 all free at this point.
    norm_ln<<<dim3((R * 16 + 255) / 256), dim3(256), 0, stream>>>(
        c_emb, t_emb, cf_emb, item_emb, Xn, M);
    gemm_bt<256, 64, bf16, bf16, float>
        <<<dim3(1, (R + 255) / 256), dim3(256), 0, stream>>>(
            Xn, Wb + wofs[7], Qbuf, R, 64, 64, nullptr, nullptr, 0);
    gemm_bt<256, 64, bf16, bf16, float>
        <<<dim3(1, (R + 255) / 256), dim3(256), 0, stream>>>(
            Xn, Wb + wofs[8], Kbuf, R, 64, 64, nullptr, nullptr, 0);
    gemm_bt<256, 64, bf16, bf16, float>
        <<<dim3(1, (R + 255) / 256), dim3(256), 0, stream>>>(
            Xn, Wb + wofs[9], Vbuf, R, 64, 64, nullptr, nullptr, 0);
    const int nGroup = (M + 3) / 4;  // 12500
    attn4<<<dim3((nGroup + 3) / 4), dim3(256), 0, stream>>>(
        Qbuf, Kbuf, Vbuf, fusedTab, nGroup);
    gather_out<<<dim3((n_tok * 16 + 255) / 256), dim3(256), 0, stream>>>(
        seq, fusedTab, out, n_tok);
  } else if (useWb) {
    // ---- slim path: fp32 A (packed in-kernel) + bf16 B ----
    row_invnorm<<<dim3((M + 3) / 4), dim3(256), 0, stream>>>(content, invn_c, M, 1024);
    row_invnorm<<<dim3((M + 3) / 4), dim3(256), 0, stream>>>(text, invn_t, M, 768);
    gemm_bt<128, 128, float, bf16, bf16>
        <<<dim3(1024 / 128, (M + 127) / 128), dim3(256), 0, stream>>>(
            content, Wb + wofs[0], H1, M, 1024, 1024, invn_c, c_b1, 1);
    gemm_bt<128, 128, bf16, bf16, bf16>
        <<<dim3(256 / 128, (M + 127) / 128), dim3(256), 0, stream>>>(
            H1, Wb + wofs[1], H2, M, 256, 1024, nullptr, c_b2, 1);
    gemm_bt<256, 64, bf16, bf16, bf16>
        <<<dim3(1, (M + 255) / 256), dim3(256), 0, stream>>>(
            H2, Wb + wofs[2], c_emb, M, 64, 256, nullptr, c_b3, 0);
    gemm_bt<128, 128, float, bf16, bf16>
        <<<dim3(768 / 128, (M + 127) / 128), dim3(256), 0, stream>>>(
            text, Wb + wofs[3], H1, M, 768, 768, invn_t, t_b1, 1);
    gemm_bt<128, 128, bf16, bf16, bf16>
        <<<dim3(256 / 128, (M + 127) / 128), dim3(256), 0, stream>>>(
            H1, Wb + wofs[4], H2, M, 256, 768, nullptr, t_b2, 1);
    gemm_bt<256, 64, bf16, bf16, bf16>
        <<<dim3(1, (M + 255) / 256), dim3(256), 0, stream>>>(
            H2, Wb + wofs[5], t_emb, M, 64, 256, nullptr, t_b3, 0);
    gemm_bt<256, 64, float, bf16, bf16>
        <<<dim3(1, (M + 255) / 256), dim3(256), 0, stream>>>(
            cf_feat, Wb + wofs[6], cf_emb, M, 64, 64, nullptr, cf_b, 0);
    if (useFused) {
      fuse_attn2<<<dim3(768), dim3(256), 0, stream>>>(
          nullptr, c_emb, t_emb, cf_emb, item_emb, wq, wk, wv, fusedTab, M);
      gather_out<<<dim3((n_tok * 16 + 255) / 256), dim3(256), 0, stream>>>(
          seq, fusedTab, out, n_tok);
    } else {
      fuse_attn2<<<dim3(768), dim3(256), 0, stream>>>(
          seq, c_emb, t_emb, cf_emb, item_emb, wq, wk, wv, out, n_tok);
    }
  } else {
    // ---- minimal path: fp32 A and B ----
    row_invnorm<<<dim3((M + 3) / 4), dim3(256), 0, stream>>>(content, invn_c, M, 1024);
    row_invnorm<<<dim3((M + 3) / 4), dim3(256), 0, stream>>>(text, invn_t, M, 768);
    gemm_bt<128, 128, float, float, bf16>
        <<<dim3(1024 / 128, (M + 127) / 128), dim3(256), 0, stream>>>(
            content, c_w1, H1, M, 1024, 1024, invn_c, c_b1, 1);
    gemm_bt<128, 128, bf16, float, bf16>
        <<<dim3(256 / 128, (M + 127) / 128), dim3(256), 0, stream>>>(
            H1, c_w2, H2, M, 256, 1024, nullptr, c_b2, 1);
    gemm_bt<256, 64, bf16, float, bf16>
        <<<dim3(1, (M + 255) / 256), dim3(256), 0, stream>>>(
            H2, c_w3, c_emb, M, 64, 256, nullptr, c_b3, 0);
    gemm_bt<128, 128, float, float, bf16>
        <<<dim3(768 / 128, (M + 127) / 128), dim3(256), 0, stream>>>(
            text, t_w1, H1, M, 768, 768, invn_t, t_b1, 1);
    gemm_bt<128, 128, bf16, float, bf16>
        <<<dim3(256 / 128, (M + 127) / 128), dim3(256), 0, stream>>>(
            H1, t_w2, H2, M, 256, 768, nullptr, t_b2, 1);
    gemm_bt<256, 64, bf16, float, bf16>
        <<<dim3(1, (M + 255) / 256), dim3(256), 0, stream>>>(
            H2, t_w3, t_emb, M, 64, 256, nullptr, t_b3, 0);
    gemm_bt<256, 64, float, float, bf16>
        <<<dim3(1, (M + 255) / 256), dim3(256), 0, stream>>>(
            cf_feat, cf_w, cf_emb, M, 64, 64, nullptr, cf_b, 0);
    fuse_attn2<<<dim3(768), dim3(256), 0, stream>>>(
        seq, c_emb, t_emb, cf_emb, item_emb, wq, wk, wv, out, n_tok);
  }
}

// Round 3
// 1034.363 us; speedup vs baseline: 1.3716x; 1.0868x over previous
//
#include <hip/hip_runtime.h>
#include <hip/hip_bf16.h>
#include <type_traits>

typedef __hip_bfloat16 bf16;
typedef __attribute__((ext_vector_type(8))) short short8;
typedef __attribute__((ext_vector_type(4))) float floatx4;

static constexpr int kNumItem = 50000;

__device__ __forceinline__ float bf2f(const bf16 x) { return __bfloat162float(x); }

union alignas(16) Pack8 {
  bf16 b[8];
  short8 s;
};
union alignas(8) Pack4 {
  bf16 b[4];
  short4 s;
};

__device__ __forceinline__ void async_cp16(const void* g, void* l) {
  __builtin_amdgcn_global_load_lds((const __attribute__((address_space(1))) void*)g,
                                   (__attribute__((address_space(3))) void*)l, 16, 0, 0);
}

// bijective XCD-chunk remap (m204): consecutive remapped ids stay on one XCD.
__device__ __forceinline__ int xcd_swz(int orig, int nwg) {
  const int nx = 8;
  const int q = nwg / nx, r = nwg % nx;
  const int xcd = orig % nx, loc = orig / nx;
  return (xcd < r ? xcd * (q + 1) : r * (q + 1) + (xcd - r) * q) + loc;
}

// ---------------- per-row 1/max(||x||,1e-12), fp32 input (slim path) ------------
__global__ __launch_bounds__(256) void row_invnorm(const float* __restrict__ X,
                                                   float* __restrict__ out,
                                                   int M, int K) {
  const int lane = threadIdx.x & 63;
  const int wave = threadIdx.x >> 6;
  const int row = blockIdx.x * 4 + wave;
  if (row >= M) return;
  const float* xr = X + (size_t)row * K;
  float s = 0.f;
  for (int c = lane * 8; c < K; c += 64 * 8) {
    float4 a = *(const float4*)(xr + c);
    float4 b = *(const float4*)(xr + c + 4);
    s += a.x * a.x + a.y * a.y + a.z * a.z + a.w * a.w;
    s += b.x * b.x + b.y * b.y + b.z * b.z + b.w * b.w;
  }
#pragma unroll
  for (int off = 32; off > 0; off >>= 1) s += __shfl_xor(s, off, 64);
  if (lane == 0) out[row] = 1.0f / fmaxf(sqrtf(s), 1e-12f);
}

// ------------- fused: fp32 row -> bf16 row copy + 1/||row|| (fat path) ----------
__global__ __launch_bounds__(256) void cvt_rows_norm(const float* __restrict__ X,
                                                     bf16* __restrict__ Xb,
                                                     float* __restrict__ out,
                                                     int M, int K) {
  const int lane = threadIdx.x & 63;
  const int wave = threadIdx.x >> 6;
  const int row = blockIdx.x * 4 + wave;
  if (row >= M) return;
  const float* xr = X + (size_t)row * K;
  bf16* dr = Xb + (size_t)row * K;
  float s = 0.f;
  for (int c = lane * 8; c < K; c += 64 * 8) {
    float4 a = *(const float4*)(xr + c);
    float4 b = *(const float4*)(xr + c + 4);
    s += a.x * a.x + a.y * a.y + a.z * a.z + a.w * a.w;
    s += b.x * b.x + b.y * b.y + b.z * b.z + b.w * b.w;
    Pack8 p;
    p.b[0] = __float2bfloat16(a.x); p.b[1] = __float2bfloat16(a.y);
    p.b[2] = __float2bfloat16(a.z); p.b[3] = __float2bfloat16(a.w);
    p.b[4] = __float2bfloat16(b.x); p.b[5] = __float2bfloat16(b.y);
    p.b[6] = __float2bfloat16(b.z); p.b[7] = __float2bfloat16(b.w);
    *(short8*)(void*)(dr + c) = p.s;
  }
#pragma unroll
  for (int off = 32; off > 0; off >>= 1) s += __shfl_xor(s, off, 64);
  if (lane == 0) out[row] = 1.0f / fmaxf(sqrtf(s), 1e-12f);
}

// ---------------- pack 10 fp32 weight matrices -> one contiguous bf16 region ----
static constexpr int kNWSeg = 10;
struct WPack {
  const float* src[kNWSeg];
  int start4[kNWSeg];  // chunk (float4) start offset of each segment in the concat
  int total4;
};
__global__ __launch_bounds__(256) void cvt_many(WPack p, bf16* __restrict__ dst) {
  int c = blockIdx.x * 256 + threadIdx.x;
  const int stride = gridDim.x * 256;
  for (; c < p.total4; c += stride) {
    int s = 0;
#pragma unroll
    for (int k = 1; k < kNWSeg; k++)
      if (c >= p.start4[k]) s = k;
    const float4 v = ((const float4*)p.src[s])[c - p.start4[s]];
    Pack4 q;
    q.b[0] = __float2bfloat16(v.x); q.b[1] = __float2bfloat16(v.y);
    q.b[2] = __float2bfloat16(v.z); q.b[3] = __float2bfloat16(v.w);
    *(short4*)(void*)(dst + (size_t)c * 4) = q.s;
  }
}

// ---------------- NT GEMM: C[M,N] = act(scale_m * (A[M,K] @ B[N,K]^T) + bias[N]) ----
// m97-style 128-tile; bf16 MFMA; bf16 sources staged via global_load_lds(16B);
// fp32 sources converted during LDS staging. C/D layout col=lane&15, row=quad*4+r.
// XCD-swizzled tile ids: consecutive tiles (sharing the A panel) on one XCD L2.
template <int BM, int BN, typename AT, typename BT, typename CT>
__global__ __launch_bounds__(256) void gemm_bt(const AT* __restrict__ A,
                                               const BT* __restrict__ B,
                                               CT* __restrict__ C,
                                               int M, int N, int K,
                                               const float* __restrict__ rowScale,
                                               const float* __restrict__ bias,
                                               int doRelu) {
  constexpr int BK = 32;
  __shared__ __align__(16) bf16 sA[BM * BK];
  __shared__ __align__(16) bf16 sB[BN * BK];
  const int t = threadIdx.x;
  const int lane = t & 63;
  const int wave = t >> 6;
  constexpr int WN = BN / 64;  // waves along N
  const int wm = wave / WN;
  const int wn = wave % WN;
  const int gx = gridDim.x;
  const int wgid = xcd_swz(blockIdx.y * gx + blockIdx.x, gx * gridDim.y);
  const int m0 = (wgid / gx) * BM;
  const int n0 = (wgid % gx) * BN;
  const int lane16 = lane & 15;
  const int quad = lane >> 4;

  floatx4 acc[4][4];
#pragma unroll
  for (int i = 0; i < 4; i++)
#pragma unroll
    for (int j = 0; j < 4; j++) acc[i][j] = (floatx4)0.0f;

  for (int k0 = 0; k0 < K; k0 += BK) {
    // stage A tile: BM rows x 32 bf16 (4 chunks of 8 elems per row)
#pragma unroll
    for (int it = 0; it < BM / 64; ++it) {
      int c = t + 256 * it;
      int row = c >> 2;
      int col = (c & 3) * 8;
      int gr = m0 + row;
      if (gr > M - 1) gr = M - 1;  // clamp: safe re-read, stores are guarded
      if constexpr (std::is_same_v<AT, bf16>) {
        async_cp16(A + (size_t)gr * K + k0 + col, &sA[c * 8]);
      } else {
        const float* src = A + (size_t)gr * K + k0 + col;
        float4 fa = *(const float4*)src;
        float4 fb = *(const float4*)(src + 4);
        Pack8 p;
        p.b[0] = __float2bfloat16(fa.x); p.b[1] = __float2bfloat16(fa.y);
        p.b[2] = __float2bfloat16(fa.z); p.b[3] = __float2bfloat16(fa.w);
        p.b[4] = __float2bfloat16(fb.x); p.b[5] = __float2bfloat16(fb.y);
        p.b[6] = __float2bfloat16(fb.z); p.b[7] = __float2bfloat16(fb.w);
        *(short8*)(void*)&sA[c * 8] = p.s;
      }
    }
    // stage B tile (weights, N rows x K)
#pragma unroll
    for (int it = 0; it < BN / 64; ++it) {
      int c = t + 256 * it;
      int row = c >> 2;
      int col = (c & 3) * 8;
      int gr = n0 + row;
      if (gr > N - 1) gr = N - 1;
      if constexpr (std::is_same_v<BT, bf16>) {
        async_cp16(B + (size_t)gr * K + k0 + col, &sB[c * 8]);
      } else {
        const float* src = B + (size_t)gr * K + k0 + col;
        float4 fa = *(const float4*)src;
        float4 fb = *(const float4*)(src + 4);
        Pack8 p;
        p.b[0] = __float2bfloat16(fa.x); p.b[1] = __float2bfloat16(fa.y);
        p.b[2] = __float2bfloat16(fa.z); p.b[3] = __float2bfloat16(fa.w);
        p.b[4] = __float2bfloat16(fb.x); p.b[5] = __float2bfloat16(fb.y);
        p.b[6] = __float2bfloat16(fb.z); p.b[7] = __float2bfloat16(fb.w);
        *(short8*)(void*)&sB[c * 8] = p.s;
      }
    }
    __syncthreads();

    short8 afr[4], bfr[4];
#pragma unroll
    for (int i = 0; i < 4; i++)
      afr[i] = *(const short8*)(const void*)&sA[(wm * 64 + i * 16 + lane16) * BK + quad * 8];
#pragma unroll
    for (int j = 0; j < 4; j++)
      bfr[j] = *(const short8*)(const void*)&sB[(wn * 64 + j * 16 + lane16) * BK + quad * 8];
#pragma unroll
    for (int i = 0; i < 4; i++)
#pragma unroll
      for (int j = 0; j < 4; j++)
        acc[i][j] = __builtin_amdgcn_mfma_f32_16x16x32_bf16(afr[i], bfr[j], acc[i][j], 0, 0, 0);
    __syncthreads();
  }

  // epilogue
#pragma unroll
  for (int i = 0; i < 4; i++) {
#pragma unroll
    for (int j = 0; j < 4; j++) {
      const int col = n0 + wn * 64 + j * 16 + lane16;
      const float bv = bias ? bias[col] : 0.f;
#pragma unroll
      for (int r = 0; r < 4; r++) {
        const int row = m0 + wm * 64 + i * 16 + quad * 4 + r;
        if (row < M) {
          float v = acc[i][j][r];
          if (rowScale) v *= rowScale[row];
          v += bv;
          if (doRelu) v = v > 0.f ? v : 0.f;
          if constexpr (std::is_same_v<CT, bf16>)
            C[(size_t)row * N + col] = __float2bfloat16(v);
          else
            C[(size_t)row * N + col] = v;
        }
      }
    }
  }
}

// ------- wide-tile NT GEMM: BM=128, BN=256, 512 threads (8 waves = 2Mx4N) -------
// bf16-only sources (global_load_lds staging). Cuts A-panel re-staging to N/256.
template <typename CT>
__global__ __launch_bounds__(512) void gemm_bt2(const bf16* __restrict__ A,
                                                const bf16* __restrict__ B,
                                                CT* __restrict__ C,
                                                int M, int N, int K,
                                                const float* __restrict__ rowScale,
                                                const float* __restrict__ bias,
                                                int doRelu) {
  constexpr int BM = 128, BN = 256, BK = 32;
  __shared__ __align__(16) bf16 sA[BM * BK];  // 8 KB
  __shared__ __align__(16) bf16 sB[BN * BK];  // 16 KB
  const int t = threadIdx.x;
  const int lane = t & 63;
  const int wave = t >> 6;   // 0..7
  const int wm = wave >> 2;  // 0..1 along M
  const int wn = wave & 3;   // 0..3 along N
  const int gx = gridDim.x;
  const int wgid = xcd_swz(blockIdx.y * gx + blockIdx.x, gx * gridDim.y);
  const int m0 = (wgid / gx) * BM;
  const int n0 = (wgid % gx) * BN;
  const int lane16 = lane & 15;
  const int quad = lane >> 4;

  floatx4 acc[4][4];
#pragma unroll
  for (int i = 0; i < 4; i++)
#pragma unroll
    for (int j = 0; j < 4; j++) acc[i][j] = (floatx4)0.0f;

  for (int k0 = 0; k0 < K; k0 += BK) {
    {  // A tile: 128 rows x 32 bf16 = 512 chunks, 1 per thread
      const int c = t;
      const int row = c >> 2;
      const int col = (c & 3) * 8;
      int gr = m0 + row;
      if (gr > M - 1) gr = M - 1;
      async_cp16(A + (size_t)gr * K + k0 + col, &sA[c * 8]);
    }
#pragma unroll
    for (int it = 0; it < 2; ++it) {  // B tile: 256 rows x 32 = 1024 chunks
      const int c = t + 512 * it;
      const int row = c >> 2;
      const int col = (c & 3) * 8;
      int gr = n0 + row;
      if (gr > N - 1) gr = N - 1;
      async_cp16(B + (size_t)gr * K + k0 + col, &sB[c * 8]);
    }
    __syncthreads();

    short8 afr[4], bfr[4];
#pragma unroll
    for (int i = 0; i < 4; i++)
      afr[i] = *(const short8*)(const void*)&sA[(wm * 64 + i * 16 + lane16) * BK + quad * 8];
#pragma unroll
    for (int j = 0; j < 4; j++)
      bfr[j] = *(const short8*)(const void*)&sB[(wn * 64 + j * 16 + lane16) * BK + quad * 8];
#pragma unroll
    for (int i = 0; i < 4; i++)
#pragma unroll
      for (int j = 0; j < 4; j++)
        acc[i][j] = __builtin_amdgcn_mfma_f32_16x16x32_bf16(afr[i], bfr[j], acc[i][j], 0, 0, 0);
    __syncthreads();
  }

#pragma unroll
  for (int i = 0; i < 4; i++) {
#pragma unroll
    for (int j = 0; j < 4; j++) {
      const int col = n0 + wn * 64 + j * 16 + lane16;
      const float bv = bias ? bias[col] : 0.f;
#pragma unroll
      for (int r = 0; r < 4; r++) {
        const int row = m0 + wm * 64 + i * 16 + quad * 4 + r;
        if (row < M) {
          float v = acc[i][j][r];
          if (rowScale) v *= rowScale[row];
          v += bv;
          if (doRelu) v = v > 0.f ? v : 0.f;
          if constexpr (std::is_same_v<CT, bf16>)
            C[(size_t)row * N + col] = __float2bfloat16(v);
          else
            C[(size_t)row * N + col] = v;
        }
      }
    }
  }
}

// ---- l2norm + LayerNorm per (item,modal) row: 16 lanes/row, 4-stage butterfly ----
// Xn[row=item*4+m][64] bf16. Rows read from the 4 modality tables.
__global__ __launch_bounds__(256) void norm_ln(const bf16* __restrict__ c_emb,
                                               const bf16* __restrict__ t_emb,
                                               const bf16* __restrict__ cf_emb,
                                               const float* __restrict__ id_emb,
                                               bf16* __restrict__ Xn, int nItem) {
  const int gid = blockIdx.x * 256 + threadIdx.x;
  const int row = gid >> 4;
  const int d4 = gid & 15;
  if (row >= nItem * 4) return;
  const int item = row >> 2;
  const int m = row & 3;

  float x[4];
  if (m == 3) {
    const float4 f = *(const float4*)(id_emb + (size_t)item * 64 + d4 * 4);
    x[0] = f.x; x[1] = f.y; x[2] = f.z; x[3] = f.w;
  } else {
    const bf16* src = (m == 0) ? c_emb : (m == 1 ? t_emb : cf_emb);
    Pack4 p;
    p.s = *(const short4*)(const void*)(src + (size_t)item * 64 + d4 * 4);
    x[0] = bf2f(p.b[0]); x[1] = bf2f(p.b[1]); x[2] = bf2f(p.b[2]); x[3] = bf2f(p.b[3]);
  }

  float sm = x[0] + x[1] + x[2] + x[3];
  float ss = x[0] * x[0] + x[1] * x[1] + x[2] * x[2] + x[3] * x[3];
#pragma unroll
  for (int off = 1; off < 16; off <<= 1) {
    sm += __shfl_xor(sm, off, 64);
    ss += __shfl_xor(ss, off, 64);
  }
  const float inv = 1.0f / fmaxf(sqrtf(ss), 1e-12f);
  const float mu = sm * inv * (1.0f / 64.0f);
  const float ex2 = ss * inv * inv * (1.0f / 64.0f);
  const float var = ex2 - mu * mu;
  const float rs = rsqrtf(var + 1e-5f);

  Pack4 o;
#pragma unroll
  for (int c = 0; c < 4; c++) o.b[c] = __float2bfloat16((x[c] * inv - mu) * rs);
  *(short4*)(void*)(Xn + (size_t)row * 64 + d4 * 4) = o.s;
}

// ---- tiny attention: 4 items/wave, 16 lanes/item (lane = sub*16 + d4) ----------
// Q,K,V fp32 [nItem*4, 64]; out fp32 [nItem, 64]. Scores via 4-stage butterfly.
__global__ __launch_bounds__(256) void attn4(const float* __restrict__ Q,
                                             const float* __restrict__ K,
                                             const float* __restrict__ V,
                                             float* __restrict__ out, int nGroup) {
  const int t = threadIdx.x;
  const int wave = t >> 6;
  const int lane = t & 63;
  const int sub = lane >> 4;
  const int d4 = lane & 15;
  const int group = blockIdx.x * 4 + wave;
  if (group >= nGroup) return;
  const int item = group * 4 + sub;
  const size_t rb = (size_t)item * 4;

  float4 q4[4], k4[4], v4[4];
#pragma unroll
  for (int m = 0; m < 4; m++) {
    q4[m] = *(const float4*)(Q + (rb + m) * 64 + d4 * 4);
    k4[m] = *(const float4*)(K + (rb + m) * 64 + d4 * 4);
    v4[m] = *(const float4*)(V + (rb + m) * 64 + d4 * 4);
  }

  // per-lane partial dot over its 4 d's, then 4-stage butterfly within 16 lanes
  float p[16];
#pragma unroll
  for (int m = 0; m < 4; m++)
#pragma unroll
    for (int n = 0; n < 4; n++)
      p[m * 4 + n] = q4[m].x * k4[n].x + q4[m].y * k4[n].y +
                     q4[m].z * k4[n].z + q4[m].w * k4[n].w;
#pragma unroll
  for (int off = 1; off < 16; off <<= 1)
#pragma unroll
    for (int i = 0; i < 16; i++) p[i] += __shfl_xor(p[i], off, 64);

  float abar[4] = {0, 0, 0, 0};
#pragma unroll
  for (int m = 0; m < 4; m++) {
    const float s0 = p[m * 4 + 0] * 0.125f, s1 = p[m * 4 + 1] * 0.125f;
    const float s2 = p[m * 4 + 2] * 0.125f, s3 = p[m * 4 + 3] * 0.125f;
    const float mx = fmaxf(fmaxf(s0, s1), fmaxf(s2, s3));
    const float e0 = expf(s0 - mx), e1 = expf(s1 - mx);
    const float e2 = expf(s2 - mx), e3 = expf(s3 - mx);
    const float inv = 1.0f / (e0 + e1 + e2 + e3);
    abar[0] += e0 * inv;
    abar[1] += e1 * inv;
    abar[2] += e2 * inv;
    abar[3] += e3 * inv;
  }

  float4 o;
  o.x = 0.25f * (abar[0] * v4[0].x + abar[1] * v4[1].x + abar[2] * v4[2].x + abar[3] * v4[3].x);
  o.y = 0.25f * (abar[0] * v4[0].y + abar[1] * v4[1].y + abar[2] * v4[2].y + abar[3] * v4[3].y);
  o.z = 0.25f * (abar[0] * v4[0].z + abar[1] * v4[1].z + abar[2] * v4[2].z + abar[3] * v4[3].z);
  o.w = 0.25f * (abar[0] * v4[0].w + abar[1] * v4[1].w + abar[2] * v4[2].w + abar[3] * v4[3].w);
  *(float4*)(out + (size_t)item * 64 + d4 * 4) = o;
}

// ---- per-token/per-item fusion (FALLBACK path only) ----------------------------
__global__ __launch_bounds__(256, 4) void fuse_attn2(const int* __restrict__ seq,
                                                     const bf16* __restrict__ c_emb,
                                                     const bf16* __restrict__ t_emb,
                                                     const bf16* __restrict__ cf_emb,
                                                     const float* __restrict__ id_emb,
                                                     const float* __restrict__ wq,
                                                     const float* __restrict__ wk,
                                                     const float* __restrict__ wv,
                                                     float* __restrict__ out, int n_tok) {
  __shared__ __align__(16) float4 swc[3072];  // 48 KB: [mat][d4][j]
  __shared__ float sxn[4][4][64];             // 4 KB: [wave][m][d]
  const int t = threadIdx.x;
  const int lane = t & 63;
  const int wave = t >> 6;

  for (int c = t; c < 3072; c += 256) {
    const int mat = c >> 10, rem = c & 1023, d4 = rem >> 6, j = rem & 63;
    const float* W = (mat == 0) ? wq : (mat == 1 ? wk : wv);
    swc[c] = *(const float4*)(W + j * 64 + d4 * 4);
  }
  __syncthreads();

  const int gw = blockIdx.x * 4 + wave;
  const int gstride = gridDim.x * 4;
  for (int token = gw; token < n_tok; token += gstride) {
    int idx = seq ? seq[token] : token;
    if (idx >= kNumItem || idx < 0) idx = 0;

    float x[4];
    x[0] = bf2f(c_emb[(size_t)idx * 64 + lane]);
    x[1] = bf2f(t_emb[(size_t)idx * 64 + lane]);
    x[2] = bf2f(cf_emb[(size_t)idx * 64 + lane]);
    x[3] = id_emb[(size_t)idx * 64 + lane];

#pragma unroll
    for (int m = 0; m < 4; m++) {
      float sm = x[m], ss = x[m] * x[m];
#pragma unroll
      for (int off = 32; off > 0; off >>= 1) {
        sm += __shfl_xor(sm, off, 64);
        ss += __shfl_xor(ss, off, 64);
      }
      const float inv = 1.0f / fmaxf(sqrtf(ss), 1e-12f);
      const float xh = x[m] * inv;
      const float mu = sm * inv * (1.0f / 64.0f);
      const float ex2 = ss * inv * inv * (1.0f / 64.0f);
      const float var = ex2 - mu * mu;
      const float xn = (xh - mu) * rsqrtf(var + 1e-5f);
      x[m] = xn;
      sxn[wave][m][lane] = xn;
    }

    float q[4] = {0, 0, 0, 0}, kk[4] = {0, 0, 0, 0}, v[4] = {0, 0, 0, 0};
#pragma unroll
    for (int d4 = 0; d4 < 16; d4++) {
      const float4 a = swc[d4 * 64 + lane];
      const float4 b = swc[1024 + d4 * 64 + lane];
      const float4 g = swc[2048 + d4 * 64 + lane];
#pragma unroll
      for (int m = 0; m < 4; m++) {
        const float4 xn4 = *(const float4*)&sxn[wave][m][d4 * 4];
        q[m] += xn4.x * a.x + xn4.y * a.y + xn4.z * a.z + xn4.w * a.w;
        kk[m] += xn4.x * b.x + xn4.y * b.y + xn4.z * b.z + xn4.w * b.w;
        v[m] += xn4.x * g.x + xn4.y * g.y + xn4.z * g.z + xn4.w * g.w;
      }
    }

    float p[16];
#pragma unroll
    for (int m = 0; m < 4; m++)
#pragma unroll
      for (int n = 0; n < 4; n++) p[m * 4 + n] = q[m] * kk[n];
#pragma unroll
    for (int off = 1; off < 64; off <<= 1)
#pragma unroll
      for (int i = 0; i < 16; i++) p[i] += __shfl_xor(p[i], off, 64);

    float abar[4] = {0, 0, 0, 0};
#pragma unroll
    for (int m = 0; m < 4; m++) {
      float s0 = p[m * 4 + 0] * 0.125f, s1 = p[m * 4 + 1] * 0.125f;
      float s2 = p[m * 4 + 2] * 0.125f, s3 = p[m * 4 + 3] * 0.125f;
      float mx = fmaxf(fmaxf(s0, s1), fmaxf(s2, s3));
      float e0 = expf(s0 - mx), e1 = expf(s1 - mx), e2 = expf(s2 - mx), e3 = expf(s3 - mx);
      float inv = 1.0f / (e0 + e1 + e2 + e3);
      abar[0] += e0 * inv;
      abar[1] += e1 * inv;
      abar[2] += e2 * inv;
      abar[3] += e3 * inv;
    }
    const float o =
        0.25f * (abar[0] * v[0] + abar[1] * v[1] + abar[2] * v[2] + abar[3] * v[3]);
    out[(size_t)token * 64 + lane] = o;
  }
}

// ---- row gather: out[token] = fused[clamp(seq[token])]; 16 lanes x float4/row ----
__global__ __launch_bounds__(256) void gather_out(const int* __restrict__ seq,
                                                  const float* __restrict__ fused,
                                                  float* __restrict__ out, int n_tok) {
  const int gid = blockIdx.x * 256 + threadIdx.x;
  if (gid >= n_tok * 16) return;
  const int token = gid >> 4;
  const int c4 = gid & 15;
  int idx = seq[token];
  if (idx >= kNumItem || idx < 0) idx = 0;
  ((float4*)out)[(size_t)token * 16 + c4] = ((const float4*)fused)[(size_t)idx * 16 + c4];
}

extern "C" void kernel_launch(void* const* d_in, const int* in_sizes, int n_in,
                              void* d_out, int out_size, void* d_ws, size_t ws_size,
                              hipStream_t stream) {
  const int* seq = (const int*)d_in[0];
  const float* content = (const float*)d_in[1];
  const float* text = (const float*)d_in[2];
  const float* cf_feat = (const float*)d_in[3];
  const float* item_emb = (const float*)d_in[4];
  const float* c_w1 = (const float*)d_in[5];
  const float* c_b1 = (const float*)d_in[6];
  const float* c_w2 = (const float*)d_in[7];
  const float* c_b2 = (const float*)d_in[8];
  const float* c_w3 = (const float*)d_in[9];
  const float* c_b3 = (const float*)d_in[10];
  const float* t_w1 = (const float*)d_in[11];
  const float* t_b1 = (const float*)d_in[12];
  const float* t_w2 = (const float*)d_in[13];
  const float* t_b2 = (const float*)d_in[14];
  const float* t_w3 = (const float*)d_in[15];
  const float* t_b3 = (const float*)d_in[16];
  const float* cf_w = (const float*)d_in[17];
  const float* cf_b = (const float*)d_in[18];
  const float* wq = (const float*)d_in[19];
  const float* wk = (const float*)d_in[20];
  const float* wv = (const float*)d_in[21];
  float* out = (float*)d_out;

  const int M = kNumItem;         // 50000
  const int n_tok = in_sizes[0];  // 51200

  // ---- workspace carve-up (ws_size-tiered) ----
  char* w = (char*)d_ws;
  size_t off = 0;
  auto alloc = [&](size_t bytes) -> void* {
    void* p = w + off;
    off += (bytes + 255) & ~(size_t)255;
    return p;
  };
  float* invn_c = (float*)alloc((size_t)M * 4);
  float* invn_t = (float*)alloc((size_t)M * 4);
  bf16* c_emb = (bf16*)alloc((size_t)M * 64 * 2);
  bf16* t_emb = (bf16*)alloc((size_t)M * 64 * 2);
  bf16* cf_emb = (bf16*)alloc((size_t)M * 64 * 2);
  bf16* H1 = (bf16*)alloc((size_t)M * 1024 * 2);  // reused by text chain, then Q|K
  bf16* H2 = (bf16*)alloc((size_t)M * 256 * 2);

  // bf16 weight pack: c_w1,c_w2,c_w3,t_w1,t_w2,t_w3,cf_w,wq,wk,wv concatenated
  const int nw[kNWSeg] = {1024 * 1024, 256 * 1024, 64 * 256, 768 * 768, 256 * 768,
                          64 * 256,    64 * 64,    64 * 64,  64 * 64,   64 * 64};
  int wofs[kNWSeg + 1];
  wofs[0] = 0;
  for (int i = 0; i < kNWSeg; i++) wofs[i + 1] = wofs[i] + nw[i];
  bf16* Wb = (bf16*)alloc((size_t)wofs[kNWSeg] * 2);
  const bool useWb = (off <= ws_size);
  bf16* Ab = (bf16*)alloc((size_t)M * 1024 * 2);  // bf16 copy of content/text; then Xn|V
  const bool useAb = useWb && (off <= ws_size);
  // dense fused-embedding table: out[token] = fusedTab[seq[token]]
  float* fusedTab = (float*)alloc((size_t)M * 64 * 4);
  const bool useFused = (off <= ws_size);

  // aliases for the attention pipeline (regions free by the time they're used):
  const int R = M * 4;                                 // 200000 (item,modal) rows
  bf16* Xn = (bf16*)Ab;                                // 25.6 MB
  float* Vbuf = (float*)((char*)Ab + (size_t)R * 64 * 2);   // 51.2 MB (in Ab)
  float* Qbuf = (float*)H1;                            // 51.2 MB
  float* Kbuf = (float*)((char*)H1 + (size_t)R * 64 * 4);   // 51.2 MB (H1 = 102.4 MB)

  if (useWb) {
    WPack p;
    const float* srcs[kNWSeg] = {c_w1, c_w2, c_w3, t_w1, t_w2, t_w3, cf_w, wq, wk, wv};
    for (int i = 0; i < kNWSeg; i++) {
      p.src[i] = srcs[i];
      p.start4[i] = wofs[i] / 4;
    }
    p.total4 = wofs[kNWSeg] / 4;
    cvt_many<<<dim3(2048), dim3(256), 0, stream>>>(p, Wb);
  }

  if (useAb) {
    // ---- fat path: bf16 A + bf16 B everywhere big; wide tiles on big GEMMs ----
    cvt_rows_norm<<<dim3((M + 3) / 4), dim3(256), 0, stream>>>(content, Ab, invn_c, M, 1024);
    gemm_bt2<bf16><<<dim3(1024 / 256, (M + 127) / 128), dim3(512), 0, stream>>>(
        Ab, Wb + wofs[0], H1, M, 1024, 1024, invn_c, c_b1, 1);
    gemm_bt2<bf16><<<dim3(1, (M + 127) / 128), dim3(512), 0, stream>>>(
        H1, Wb + wofs[1], H2, M, 256, 1024, nullptr, c_b2, 1);
    gemm_bt<256, 64, bf16, bf16, bf16>
        <<<dim3(1, (M + 255) / 256), dim3(256), 0, stream>>>(
            H2, Wb + wofs[2], c_emb, M, 64, 256, nullptr, c_b3, 0);

    cvt_rows_norm<<<dim3((M + 3) / 4), dim3(256), 0, stream>>>(text, Ab, invn_t, M, 768);
    gemm_bt2<bf16><<<dim3(768 / 256, (M + 127) / 128), dim3(512), 0, stream>>>(
        Ab, Wb + wofs[3], H1, M, 768, 768, invn_t, t_b1, 1);
    gemm_bt2<bf16><<<dim3(1, (M + 127) / 128), dim3(512), 0, stream>>>(
        H1, Wb + wofs[4], H2, M, 256, 768, nullptr, t_b2, 1);
    gemm_bt<256, 64, bf16, bf16, bf16>
        <<<dim3(1, (M + 255) / 256), dim3(256), 0, stream>>>(
            H2, Wb + wofs[5], t_emb, M, 64, 256, nullptr, t_b3, 0);

    gemm_bt<256, 64, float, bf16, bf16>
        <<<dim3(1, (M + 255) / 256), dim3(256), 0, stream>>>(
            cf_feat, Wb + wofs[6], cf_emb, M, 64, 64, nullptr, cf_b, 0);

    // ---- attention pipeline: norm+LN -> QKV GEMMs (fp32 out) -> tiny attn ----
    // H1 (Q|K), Ab (Xn|V), H2 all free at this point.
    norm_ln<<<dim3((R * 16 + 255) / 256), dim3(256), 0, stream>>>(
        c_emb, t_emb, cf_emb, item_emb, Xn, M);
    gemm_bt<256, 64, bf16, bf16, float>
        <<<dim3(1, (R + 255) / 256), dim3(256), 0, stream>>>(
            Xn, Wb + wofs[7], Qbuf, R, 64, 64, nullptr, nullptr, 0);
    gemm_bt<256, 64, bf16, bf16, float>
        <<<dim3(1, (R + 255) / 256), dim3(256), 0, stream>>>(
            Xn, Wb + wofs[8], Kbuf, R, 64, 64, nullptr, nullptr, 0);
    gemm_bt<256, 64, bf16, bf16, float>
        <<<dim3(1, (R + 255) / 256), dim3(256), 0, stream>>>(
            Xn, Wb + wofs[9], Vbuf, R, 64, 64, nullptr, nullptr, 0);
    const int nGroup = (M + 3) / 4;  // 12500
    attn4<<<dim3((nGroup + 3) / 4), dim3(256), 0, stream>>>(
        Qbuf, Kbuf, Vbuf, fusedTab, nGroup);
    gather_out<<<dim3((n_tok * 16 + 255) / 256), dim3(256), 0, stream>>>(
        seq, fusedTab, out, n_tok);
  } else if (useWb) {
    // ---- slim path: fp32 A (packed in-kernel) + bf16 B ----
    row_invnorm<<<dim3((M + 3) / 4), dim3(256), 0, stream>>>(content, invn_c, M, 1024);
    row_invnorm<<<dim3((M + 3) / 4), dim3(256), 0, stream>>>(text, invn_t, M, 768);
    gemm_bt<128, 128, float, bf16, bf16>
        <<<dim3(1024 / 128, (M + 127) / 128), dim3(256), 0, stream>>>(
            content, Wb + wofs[0], H1, M, 1024, 1024, invn_c, c_b1, 1);
    gemm_bt<128, 128, bf16, bf16, bf16>
        <<<dim3(256 / 128, (M + 127) / 128), dim3(256), 0, stream>>>(
            H1, Wb + wofs[1], H2, M, 256, 1024, nullptr, c_b2, 1);
    gemm_bt<256, 64, bf16, bf16, bf16>
        <<<dim3(1, (M + 255) / 256), dim3(256), 0, stream>>>(
            H2, Wb + wofs[2], c_emb, M, 64, 256, nullptr, c_b3, 0);
    gemm_bt<128, 128, float, bf16, bf16>
        <<<dim3(768 / 128, (M + 127) / 128), dim3(256), 0, stream>>>(
            text, Wb + wofs[3], H1, M, 768, 768, invn_t, t_b1, 1);
    gemm_bt<128, 128, bf16, bf16, bf16>
        <<<dim3(256 / 128, (M + 127) / 128), dim3(256), 0, stream>>>(
            H1, Wb + wofs[4], H2, M, 256, 768, nullptr, t_b2, 1);
    gemm_bt<256, 64, bf16, bf16, bf16>
        <<<dim3(1, (M + 255) / 256), dim3(256), 0, stream>>>(
            H2, Wb + wofs[5], t_emb, M, 64, 256, nullptr, t_b3, 0);
    gemm_bt<256, 64, float, bf16, bf16>
        <<<dim3(1, (M + 255) / 256), dim3(256), 0, stream>>>(
            cf_feat, Wb + wofs[6], cf_emb, M, 64, 64, nullptr, cf_b, 0);
    if (useFused) {
      fuse_attn2<<<dim3(768), dim3(256), 0, stream>>>(
          nullptr, c_emb, t_emb, cf_emb, item_emb, wq, wk, wv, fusedTab, M);
      gather_out<<<dim3((n_tok * 16 + 255) / 256), dim3(256), 0, stream>>>(
          seq, fusedTab, out, n_tok);
    } else {
      fuse_attn2<<<dim3(768), dim3(256), 0, stream>>>(
          seq, c_emb, t_emb, cf_emb, item_emb, wq, wk, wv, out, n_tok);
    }
  } else {
    // ---- minimal path: fp32 A and B ----
    row_invnorm<<<dim3((M + 3) / 4), dim3(256), 0, stream>>>(content, invn_c, M, 1024);
    row_invnorm<<<dim3((M + 3) / 4), dim3(256), 0, stream>>>(text, invn_t, M, 768);
    gemm_bt<128, 128, float, float, bf16>
        <<<dim3(1024 / 128, (M + 127) / 128), dim3(256), 0, stream>>>(
            content, c_w1, H1, M, 1024, 1024, invn_c, c_b1, 1);
    gemm_bt<128, 128, bf16, float, bf16>
        <<<dim3(256 / 128, (M + 127) / 128), dim3(256), 0, stream>>>(
            H1, c_w2, H2, M, 256, 1024, nullptr, c_b2, 1);
    gemm_bt<256, 64, bf16, float, bf16>
        <<<dim3(1, (M + 255) / 256), dim3(256), 0, stream>>>(
            H2, c_w3, c_emb, M, 64, 256, nullptr, c_b3, 0);
    gemm_bt<128, 128, float, float, bf16>
        <<<dim3(768 / 128, (M + 127) / 128), dim3(256), 0, stream>>>(
            text, t_w1, H1, M, 768, 768, invn_t, t_b1, 1);
    gemm_bt<128, 128, bf16, float, bf16>
        <<<dim3(256 / 128, (M + 127) / 128), dim3(256), 0, stream>>>(
            H1, t_w2, H2, M, 256, 768, nullptr, t_b2, 1);
    gemm_bt<256, 64, bf16, float, bf16>
        <<<dim3(1, (M + 255) / 256), dim3(256), 0, stream>>>(
            H2, t_w3, t_emb, M, 64, 256, nullptr, t_b3, 0);
    gemm_bt<256, 64, float, float, bf16>
        <<<dim3(1, (M + 255) / 256), dim3(256), 0, stream>>>(
            cf_feat, cf_w, cf_emb, M, 64, 64, nullptr, cf_b, 0);
    fuse_attn2<<<dim3(768), dim3(256), 0, stream>>>(
        seq, c_emb, t_emb, cf_emb, item_emb, wq, wk, wv, out, n_tok);
  }
}

// Round 4
// 998.950 us; speedup vs baseline: 1.4202x; 1.0355x over previous
//
#include <hip/hip_runtime.h>
#include <hip/hip_bf16.h>
#include <type_traits>

typedef __hip_bfloat16 bf16;
typedef __attribute__((ext_vector_type(8))) short short8;
typedef __attribute__((ext_vector_type(4))) float floatx4;

static constexpr int kNumItem = 50000;

__device__ __forceinline__ float bf2f(const bf16 x) { return __bfloat162float(x); }

union alignas(16) Pack8 {
  bf16 b[8];
  short8 s;
};
union alignas(8) Pack4 {
  bf16 b[4];
  short4 s;
};

__device__ __forceinline__ void async_cp16(const void* g, void* l) {
  __builtin_amdgcn_global_load_lds((const __attribute__((address_space(1))) void*)g,
                                   (__attribute__((address_space(3))) void*)l, 16, 0, 0);
}

// bijective XCD-chunk remap (m204): consecutive remapped ids stay on one XCD.
__device__ __forceinline__ int xcd_swz(int orig, int nwg) {
  const int nx = 8;
  const int q = nwg / nx, r = nwg % nx;
  const int xcd = orig % nx, loc = orig / nx;
  return (xcd < r ? xcd * (q + 1) : r * (q + 1) + (xcd - r) * q) + loc;
}

// ---------------- per-row 1/max(||x||,1e-12), fp32 input (slim path) ------------
__global__ __launch_bounds__(256) void row_invnorm(const float* __restrict__ X,
                                                   float* __restrict__ out,
                                                   int M, int K) {
  const int lane = threadIdx.x & 63;
  const int wave = threadIdx.x >> 6;
  const int row = blockIdx.x * 4 + wave;
  if (row >= M) return;
  const float* xr = X + (size_t)row * K;
  float s = 0.f;
  for (int c = lane * 8; c < K; c += 64 * 8) {
    float4 a = *(const float4*)(xr + c);
    float4 b = *(const float4*)(xr + c + 4);
    s += a.x * a.x + a.y * a.y + a.z * a.z + a.w * a.w;
    s += b.x * b.x + b.y * b.y + b.z * b.z + b.w * b.w;
  }
#pragma unroll
  for (int off = 32; off > 0; off >>= 1) s += __shfl_xor(s, off, 64);
  if (lane == 0) out[row] = 1.0f / fmaxf(sqrtf(s), 1e-12f);
}

// ------------- fused: fp32 row -> bf16 row copy + 1/||row|| (fat path) ----------
__global__ __launch_bounds__(256) void cvt_rows_norm(const float* __restrict__ X,
                                                     bf16* __restrict__ Xb,
                                                     float* __restrict__ out,
                                                     int M, int K) {
  const int lane = threadIdx.x & 63;
  const int wave = threadIdx.x >> 6;
  const int row = blockIdx.x * 4 + wave;
  if (row >= M) return;
  const float* xr = X + (size_t)row * K;
  bf16* dr = Xb + (size_t)row * K;
  float s = 0.f;
  for (int c = lane * 8; c < K; c += 64 * 8) {
    float4 a = *(const float4*)(xr + c);
    float4 b = *(const float4*)(xr + c + 4);
    s += a.x * a.x + a.y * a.y + a.z * a.z + a.w * a.w;
    s += b.x * b.x + b.y * b.y + b.z * b.z + b.w * b.w;
    Pack8 p;
    p.b[0] = __float2bfloat16(a.x); p.b[1] = __float2bfloat16(a.y);
    p.b[2] = __float2bfloat16(a.z); p.b[3] = __float2bfloat16(a.w);
    p.b[4] = __float2bfloat16(b.x); p.b[5] = __float2bfloat16(b.y);
    p.b[6] = __float2bfloat16(b.z); p.b[7] = __float2bfloat16(b.w);
    *(short8*)(void*)(dr + c) = p.s;
  }
#pragma unroll
  for (int off = 32; off > 0; off >>= 1) s += __shfl_xor(s, off, 64);
  if (lane == 0) out[row] = 1.0f / fmaxf(sqrtf(s), 1e-12f);
}

// ---------------- pack 10 fp32 weight matrices -> one contiguous bf16 region ----
static constexpr int kNWSeg = 10;
struct WPack {
  const float* src[kNWSeg];
  int start4[kNWSeg];  // chunk (float4) start offset of each segment in the concat
  int total4;
};
__global__ __launch_bounds__(256) void cvt_many(WPack p, bf16* __restrict__ dst) {
  int c = blockIdx.x * 256 + threadIdx.x;
  const int stride = gridDim.x * 256;
  for (; c < p.total4; c += stride) {
    int s = 0;
#pragma unroll
    for (int k = 1; k < kNWSeg; k++)
      if (c >= p.start4[k]) s = k;
    const float4 v = ((const float4*)p.src[s])[c - p.start4[s]];
    Pack4 q;
    q.b[0] = __float2bfloat16(v.x); q.b[1] = __float2bfloat16(v.y);
    q.b[2] = __float2bfloat16(v.z); q.b[3] = __float2bfloat16(v.w);
    *(short4*)(void*)(dst + (size_t)c * 4) = q.s;
  }
}

// ---------------- NT GEMM: C[M,N] = act(scale_m * (A[M,K] @ B[N,K]^T) + bias[N]) ----
// Prefetch double-buffered LDS (T3-minimal): STAGE(next) issued before compute of
// current tile; ONE __syncthreads per K-step (implicit vmcnt(0)+lgkmcnt(0) drains
// the prefetch AFTER the MFMAs ran under it). XCD-swizzled tile ids.
template <int BM, int BN, typename AT, typename BT, typename CT>
__global__ __launch_bounds__(256) void gemm_bt(const AT* __restrict__ A,
                                               const BT* __restrict__ B,
                                               CT* __restrict__ C,
                                               int M, int N, int K,
                                               const float* __restrict__ rowScale,
                                               const float* __restrict__ bias,
                                               int doRelu) {
  constexpr int BK = 32;
  __shared__ __align__(16) bf16 sA[2][BM * BK];
  __shared__ __align__(16) bf16 sB[2][BN * BK];
  const int t = threadIdx.x;
  const int lane = t & 63;
  const int wave = t >> 6;
  constexpr int WN = BN / 64;  // waves along N
  const int wm = wave / WN;
  const int wn = wave % WN;
  const int gx = gridDim.x;
  const int wgid = xcd_swz(blockIdx.y * gx + blockIdx.x, gx * gridDim.y);
  const int m0 = (wgid / gx) * BM;
  const int n0 = (wgid % gx) * BN;
  const int lane16 = lane & 15;
  const int quad = lane >> 4;

  auto stageA = [&](int k0, bf16* dst) {
#pragma unroll
    for (int it = 0; it < BM / 64; ++it) {
      int c = t + 256 * it;
      int row = c >> 2;
      int col = (c & 3) * 8;
      int gr = m0 + row;
      if (gr > M - 1) gr = M - 1;  // clamp: safe re-read, stores are guarded
      if constexpr (std::is_same_v<AT, bf16>) {
        async_cp16(A + (size_t)gr * K + k0 + col, dst + c * 8);
      } else {
        const float* src = A + (size_t)gr * K + k0 + col;
        float4 fa = *(const float4*)src;
        float4 fb = *(const float4*)(src + 4);
        Pack8 p;
        p.b[0] = __float2bfloat16(fa.x); p.b[1] = __float2bfloat16(fa.y);
        p.b[2] = __float2bfloat16(fa.z); p.b[3] = __float2bfloat16(fa.w);
        p.b[4] = __float2bfloat16(fb.x); p.b[5] = __float2bfloat16(fb.y);
        p.b[6] = __float2bfloat16(fb.z); p.b[7] = __float2bfloat16(fb.w);
        *(short8*)(void*)(dst + c * 8) = p.s;
      }
    }
  };
  auto stageB = [&](int k0, bf16* dst) {
#pragma unroll
    for (int it = 0; it < BN / 64; ++it) {
      int c = t + 256 * it;
      int row = c >> 2;
      int col = (c & 3) * 8;
      int gr = n0 + row;
      if (gr > N - 1) gr = N - 1;
      if constexpr (std::is_same_v<BT, bf16>) {
        async_cp16(B + (size_t)gr * K + k0 + col, dst + c * 8);
      } else {
        const float* src = B + (size_t)gr * K + k0 + col;
        float4 fa = *(const float4*)src;
        float4 fb = *(const float4*)(src + 4);
        Pack8 p;
        p.b[0] = __float2bfloat16(fa.x); p.b[1] = __float2bfloat16(fa.y);
        p.b[2] = __float2bfloat16(fa.z); p.b[3] = __float2bfloat16(fa.w);
        p.b[4] = __float2bfloat16(fb.x); p.b[5] = __float2bfloat16(fb.y);
        p.b[6] = __float2bfloat16(fb.z); p.b[7] = __float2bfloat16(fb.w);
        *(short8*)(void*)(dst + c * 8) = p.s;
      }
    }
  };

  floatx4 acc[4][4];
#pragma unroll
  for (int i = 0; i < 4; i++)
#pragma unroll
    for (int j = 0; j < 4; j++) acc[i][j] = (floatx4)0.0f;

  stageA(0, sA[0]);
  stageB(0, sB[0]);
  __syncthreads();
  int cur = 0;
  for (int k0 = 0; k0 < K; k0 += BK) {
    const int nxt = cur ^ 1;
    if (k0 + BK < K) {  // issue next-tile loads; they fly under this tile's MFMAs
      stageA(k0 + BK, sA[nxt]);
      stageB(k0 + BK, sB[nxt]);
    }
    short8 afr[4], bfr[4];
#pragma unroll
    for (int i = 0; i < 4; i++)
      afr[i] = *(const short8*)(const void*)&sA[cur][(wm * 64 + i * 16 + lane16) * BK + quad * 8];
#pragma unroll
    for (int j = 0; j < 4; j++)
      bfr[j] = *(const short8*)(const void*)&sB[cur][(wn * 64 + j * 16 + lane16) * BK + quad * 8];
#pragma unroll
    for (int i = 0; i < 4; i++)
#pragma unroll
      for (int j = 0; j < 4; j++)
        acc[i][j] = __builtin_amdgcn_mfma_f32_16x16x32_bf16(afr[i], bfr[j], acc[i][j], 0, 0, 0);
    __syncthreads();  // vmcnt(0)+lgkmcnt(0)+barrier: nxt ready, cur free
    cur = nxt;
  }

  // epilogue
#pragma unroll
  for (int i = 0; i < 4; i++) {
#pragma unroll
    for (int j = 0; j < 4; j++) {
      const int col = n0 + wn * 64 + j * 16 + lane16;
      const float bv = bias ? bias[col] : 0.f;
#pragma unroll
      for (int r = 0; r < 4; r++) {
        const int row = m0 + wm * 64 + i * 16 + quad * 4 + r;
        if (row < M) {
          float v = acc[i][j][r];
          if (rowScale) v *= rowScale[row];
          v += bv;
          if (doRelu) v = v > 0.f ? v : 0.f;
          if constexpr (std::is_same_v<CT, bf16>)
            C[(size_t)row * N + col] = __float2bfloat16(v);
          else
            C[(size_t)row * N + col] = v;
        }
      }
    }
  }
}

// ------- wide-tile NT GEMM: BM=128, BN=256, 512 threads (8 waves = 2Mx4N) -------
// bf16-only sources; prefetch double-buffered (48 KB LDS -> 3 blocks/CU).
template <typename CT>
__global__ __launch_bounds__(512) void gemm_bt2(const bf16* __restrict__ A,
                                                const bf16* __restrict__ B,
                                                CT* __restrict__ C,
                                                int M, int N, int K,
                                                const float* __restrict__ rowScale,
                                                const float* __restrict__ bias,
                                                int doRelu) {
  constexpr int BM = 128, BN = 256, BK = 32;
  __shared__ __align__(16) bf16 sA[2][BM * BK];  // 2 x 8 KB
  __shared__ __align__(16) bf16 sB[2][BN * BK];  // 2 x 16 KB
  const int t = threadIdx.x;
  const int lane = t & 63;
  const int wave = t >> 6;   // 0..7
  const int wm = wave >> 2;  // 0..1 along M
  const int wn = wave & 3;   // 0..3 along N
  const int gx = gridDim.x;
  const int wgid = xcd_swz(blockIdx.y * gx + blockIdx.x, gx * gridDim.y);
  const int m0 = (wgid / gx) * BM;
  const int n0 = (wgid % gx) * BN;
  const int lane16 = lane & 15;
  const int quad = lane >> 4;

  auto stage = [&](int k0, bf16* dA, bf16* dB) {
    {  // A tile: 128 rows x 32 bf16 = 512 chunks, 1 per thread
      const int c = t;
      const int row = c >> 2;
      const int col = (c & 3) * 8;
      int gr = m0 + row;
      if (gr > M - 1) gr = M - 1;
      async_cp16(A + (size_t)gr * K + k0 + col, dA + c * 8);
    }
#pragma unroll
    for (int it = 0; it < 2; ++it) {  // B tile: 256 rows x 32 = 1024 chunks
      const int c = t + 512 * it;
      const int row = c >> 2;
      const int col = (c & 3) * 8;
      int gr = n0 + row;
      if (gr > N - 1) gr = N - 1;
      async_cp16(B + (size_t)gr * K + k0 + col, dB + c * 8);
    }
  };

  floatx4 acc[4][4];
#pragma unroll
  for (int i = 0; i < 4; i++)
#pragma unroll
    for (int j = 0; j < 4; j++) acc[i][j] = (floatx4)0.0f;

  stage(0, sA[0], sB[0]);
  __syncthreads();
  int cur = 0;
  for (int k0 = 0; k0 < K; k0 += BK) {
    const int nxt = cur ^ 1;
    if (k0 + BK < K) stage(k0 + BK, sA[nxt], sB[nxt]);

    short8 afr[4], bfr[4];
#pragma unroll
    for (int i = 0; i < 4; i++)
      afr[i] = *(const short8*)(const void*)&sA[cur][(wm * 64 + i * 16 + lane16) * BK + quad * 8];
#pragma unroll
    for (int j = 0; j < 4; j++)
      bfr[j] = *(const short8*)(const void*)&sB[cur][(wn * 64 + j * 16 + lane16) * BK + quad * 8];
#pragma unroll
    for (int i = 0; i < 4; i++)
#pragma unroll
      for (int j = 0; j < 4; j++)
        acc[i][j] = __builtin_amdgcn_mfma_f32_16x16x32_bf16(afr[i], bfr[j], acc[i][j], 0, 0, 0);
    __syncthreads();
    cur = nxt;
  }

#pragma unroll
  for (int i = 0; i < 4; i++) {
#pragma unroll
    for (int j = 0; j < 4; j++) {
      const int col = n0 + wn * 64 + j * 16 + lane16;
      const float bv = bias ? bias[col] : 0.f;
#pragma unroll
      for (int r = 0; r < 4; r++) {
        const int row = m0 + wm * 64 + i * 16 + quad * 4 + r;
        if (row < M) {
          float v = acc[i][j][r];
          if (rowScale) v *= rowScale[row];
          v += bv;
          if (doRelu) v = v > 0.f ? v : 0.f;
          if constexpr (std::is_same_v<CT, bf16>)
            C[(size_t)row * N + col] = __float2bfloat16(v);
          else
            C[(size_t)row * N + col] = v;
        }
      }
    }
  }
}

// ---- l2norm + LayerNorm per (item,modal) row: 16 lanes/row, 4-stage butterfly ----
// Xn[row=item*4+m][64] bf16. Rows read from the 4 modality tables.
__global__ __launch_bounds__(256) void norm_ln(const bf16* __restrict__ c_emb,
                                               const bf16* __restrict__ t_emb,
                                               const bf16* __restrict__ cf_emb,
                                               const float* __restrict__ id_emb,
                                               bf16* __restrict__ Xn, int nItem) {
  const int gid = blockIdx.x * 256 + threadIdx.x;
  const int row = gid >> 4;
  const int d4 = gid & 15;
  if (row >= nItem * 4) return;
  const int item = row >> 2;
  const int m = row & 3;

  float x[4];
  if (m == 3) {
    const float4 f = *(const float4*)(id_emb + (size_t)item * 64 + d4 * 4);
    x[0] = f.x; x[1] = f.y; x[2] = f.z; x[3] = f.w;
  } else {
    const bf16* src = (m == 0) ? c_emb : (m == 1 ? t_emb : cf_emb);
    Pack4 p;
    p.s = *(const short4*)(const void*)(src + (size_t)item * 64 + d4 * 4);
    x[0] = bf2f(p.b[0]); x[1] = bf2f(p.b[1]); x[2] = bf2f(p.b[2]); x[3] = bf2f(p.b[3]);
  }

  float sm = x[0] + x[1] + x[2] + x[3];
  float ss = x[0] * x[0] + x[1] * x[1] + x[2] * x[2] + x[3] * x[3];
#pragma unroll
  for (int off = 1; off < 16; off <<= 1) {
    sm += __shfl_xor(sm, off, 64);
    ss += __shfl_xor(ss, off, 64);
  }
  const float inv = 1.0f / fmaxf(sqrtf(ss), 1e-12f);
  const float mu = sm * inv * (1.0f / 64.0f);
  const float ex2 = ss * inv * inv * (1.0f / 64.0f);
  const float var = ex2 - mu * mu;
  const float rs = rsqrtf(var + 1e-5f);

  Pack4 o;
#pragma unroll
  for (int c = 0; c < 4; c++) o.b[c] = __float2bfloat16((x[c] * inv - mu) * rs);
  *(short4*)(void*)(Xn + (size_t)row * 64 + d4 * 4) = o.s;
}

// ---- tiny attention: 4 items/wave, 16 lanes/item (lane = sub*16 + d4) ----------
// QK bf16 [nItem*4, 128] (cols 0-63 = Q, 64-127 = K); V fp32 [nItem*4, 64].
// out fp32 [nItem, 64]. Scores via 4-stage butterfly within 16 lanes.
__global__ __launch_bounds__(256) void attn4(const bf16* __restrict__ QK,
                                             const float* __restrict__ V,
                                             float* __restrict__ out, int nGroup) {
  const int t = threadIdx.x;
  const int wave = t >> 6;
  const int lane = t & 63;
  const int sub = lane >> 4;
  const int d4 = lane & 15;
  const int group = blockIdx.x * 4 + wave;
  if (group >= nGroup) return;
  const int item = group * 4 + sub;
  const size_t rb = (size_t)item * 4;

  float4 q4[4], k4[4], v4[4];
#pragma unroll
  for (int m = 0; m < 4; m++) {
    Pack4 pq, pk;
    pq.s = *(const short4*)(const void*)(QK + (rb + m) * 128 + d4 * 4);
    pk.s = *(const short4*)(const void*)(QK + (rb + m) * 128 + 64 + d4 * 4);
    q4[m] = float4{bf2f(pq.b[0]), bf2f(pq.b[1]), bf2f(pq.b[2]), bf2f(pq.b[3])};
    k4[m] = float4{bf2f(pk.b[0]), bf2f(pk.b[1]), bf2f(pk.b[2]), bf2f(pk.b[3])};
    v4[m] = *(const float4*)(V + (rb + m) * 64 + d4 * 4);
  }

  // per-lane partial dot over its 4 d's, then 4-stage butterfly within 16 lanes
  float p[16];
#pragma unroll
  for (int m = 0; m < 4; m++)
#pragma unroll
    for (int n = 0; n < 4; n++)
      p[m * 4 + n] = q4[m].x * k4[n].x + q4[m].y * k4[n].y +
                     q4[m].z * k4[n].z + q4[m].w * k4[n].w;
#pragma unroll
  for (int off = 1; off < 16; off <<= 1)
#pragma unroll
    for (int i = 0; i < 16; i++) p[i] += __shfl_xor(p[i], off, 64);

  float abar[4] = {0, 0, 0, 0};
#pragma unroll
  for (int m = 0; m < 4; m++) {
    const float s0 = p[m * 4 + 0] * 0.125f, s1 = p[m * 4 + 1] * 0.125f;
    const float s2 = p[m * 4 + 2] * 0.125f, s3 = p[m * 4 + 3] * 0.125f;
    const float mx = fmaxf(fmaxf(s0, s1), fmaxf(s2, s3));
    const float e0 = expf(s0 - mx), e1 = expf(s1 - mx);
    const float e2 = expf(s2 - mx), e3 = expf(s3 - mx);
    const float inv = 1.0f / (e0 + e1 + e2 + e3);
    abar[0] += e0 * inv;
    abar[1] += e1 * inv;
    abar[2] += e2 * inv;
    abar[3] += e3 * inv;
  }

  float4 o;
  o.x = 0.25f * (abar[0] * v4[0].x + abar[1] * v4[1].x + abar[2] * v4[2].x + abar[3] * v4[3].x);
  o.y = 0.25f * (abar[0] * v4[0].y + abar[1] * v4[1].y + abar[2] * v4[2].y + abar[3] * v4[3].y);
  o.z = 0.25f * (abar[0] * v4[0].z + abar[1] * v4[1].z + abar[2] * v4[2].z + abar[3] * v4[3].z);
  o.w = 0.25f * (abar[0] * v4[0].w + abar[1] * v4[1].w + abar[2] * v4[2].w + abar[3] * v4[3].w);
  *(float4*)(out + (size_t)item * 64 + d4 * 4) = o;
}

// ---- per-token/per-item fusion (FALLBACK path only) ----------------------------
__global__ __launch_bounds__(256, 4) void fuse_attn2(const int* __restrict__ seq,
                                                     const bf16* __restrict__ c_emb,
                                                     const bf16* __restrict__ t_emb,
                                                     const bf16* __restrict__ cf_emb,
                                                     const float* __restrict__ id_emb,
                                                     const float* __restrict__ wq,
                                                     const float* __restrict__ wk,
                                                     const float* __restrict__ wv,
                                                     float* __restrict__ out, int n_tok) {
  __shared__ __align__(16) float4 swc[3072];  // 48 KB: [mat][d4][j]
  __shared__ float sxn[4][4][64];             // 4 KB: [wave][m][d]
  const int t = threadIdx.x;
  const int lane = t & 63;
  const int wave = t >> 6;

  for (int c = t; c < 3072; c += 256) {
    const int mat = c >> 10, rem = c & 1023, d4 = rem >> 6, j = rem & 63;
    const float* W = (mat == 0) ? wq : (mat == 1 ? wk : wv);
    swc[c] = *(const float4*)(W + j * 64 + d4 * 4);
  }
  __syncthreads();

  const int gw = blockIdx.x * 4 + wave;
  const int gstride = gridDim.x * 4;
  for (int token = gw; token < n_tok; token += gstride) {
    int idx = seq ? seq[token] : token;
    if (idx >= kNumItem || idx < 0) idx = 0;

    float x[4];
    x[0] = bf2f(c_emb[(size_t)idx * 64 + lane]);
    x[1] = bf2f(t_emb[(size_t)idx * 64 + lane]);
    x[2] = bf2f(cf_emb[(size_t)idx * 64 + lane]);
    x[3] = id_emb[(size_t)idx * 64 + lane];

#pragma unroll
    for (int m = 0; m < 4; m++) {
      float sm = x[m], ss = x[m] * x[m];
#pragma unroll
      for (int off = 32; off > 0; off >>= 1) {
        sm += __shfl_xor(sm, off, 64);
        ss += __shfl_xor(ss, off, 64);
      }
      const float inv = 1.0f / fmaxf(sqrtf(ss), 1e-12f);
      const float xh = x[m] * inv;
      const float mu = sm * inv * (1.0f / 64.0f);
      const float ex2 = ss * inv * inv * (1.0f / 64.0f);
      const float var = ex2 - mu * mu;
      const float xn = (xh - mu) * rsqrtf(var + 1e-5f);
      x[m] = xn;
      sxn[wave][m][lane] = xn;
    }

    float q[4] = {0, 0, 0, 0}, kk[4] = {0, 0, 0, 0}, v[4] = {0, 0, 0, 0};
#pragma unroll
    for (int d4 = 0; d4 < 16; d4++) {
      const float4 a = swc[d4 * 64 + lane];
      const float4 b = swc[1024 + d4 * 64 + lane];
      const float4 g = swc[2048 + d4 * 64 + lane];
#pragma unroll
      for (int m = 0; m < 4; m++) {
        const float4 xn4 = *(const float4*)&sxn[wave][m][d4 * 4];
        q[m] += xn4.x * a.x + xn4.y * a.y + xn4.z * a.z + xn4.w * a.w;
        kk[m] += xn4.x * b.x + xn4.y * b.y + xn4.z * b.z + xn4.w * b.w;
        v[m] += xn4.x * g.x + xn4.y * g.y + xn4.z * g.z + xn4.w * g.w;
      }
    }

    float p[16];
#pragma unroll
    for (int m = 0; m < 4; m++)
#pragma unroll
      for (int n = 0; n < 4; n++) p[m * 4 + n] = q[m] * kk[n];
#pragma unroll
    for (int off = 1; off < 64; off <<= 1)
#pragma unroll
      for (int i = 0; i < 16; i++) p[i] += __shfl_xor(p[i], off, 64);

    float abar[4] = {0, 0, 0, 0};
#pragma unroll
    for (int m = 0; m < 4; m++) {
      float s0 = p[m * 4 + 0] * 0.125f, s1 = p[m * 4 + 1] * 0.125f;
      float s2 = p[m * 4 + 2] * 0.125f, s3 = p[m * 4 + 3] * 0.125f;
      float mx = fmaxf(fmaxf(s0, s1), fmaxf(s2, s3));
      float e0 = expf(s0 - mx), e1 = expf(s1 - mx), e2 = expf(s2 - mx), e3 = expf(s3 - mx);
      float inv = 1.0f / (e0 + e1 + e2 + e3);
      abar[0] += e0 * inv;
      abar[1] += e1 * inv;
      abar[2] += e2 * inv;
      abar[3] += e3 * inv;
    }
    const float o =
        0.25f * (abar[0] * v[0] + abar[1] * v[1] + abar[2] * v[2] + abar[3] * v[3]);
    out[(size_t)token * 64 + lane] = o;
  }
}

// ---- row gather: out[token] = fused[clamp(seq[token])]; 16 lanes x float4/row ----
__global__ __launch_bounds__(256) void gather_out(const int* __restrict__ seq,
                                                  const float* __restrict__ fused,
                                                  float* __restrict__ out, int n_tok) {
  const int gid = blockIdx.x * 256 + threadIdx.x;
  if (gid >= n_tok * 16) return;
  const int token = gid >> 4;
  const int c4 = gid & 15;
  int idx = seq[token];
  if (idx >= kNumItem || idx < 0) idx = 0;
  ((float4*)out)[(size_t)token * 16 + c4] = ((const float4*)fused)[(size_t)idx * 16 + c4];
}

extern "C" void kernel_launch(void* const* d_in, const int* in_sizes, int n_in,
                              void* d_out, int out_size, void* d_ws, size_t ws_size,
                              hipStream_t stream) {
  const int* seq = (const int*)d_in[0];
  const float* content = (const float*)d_in[1];
  const float* text = (const float*)d_in[2];
  const float* cf_feat = (const float*)d_in[3];
  const float* item_emb = (const float*)d_in[4];
  const float* c_w1 = (const float*)d_in[5];
  const float* c_b1 = (const float*)d_in[6];
  const float* c_w2 = (const float*)d_in[7];
  const float* c_b2 = (const float*)d_in[8];
  const float* c_w3 = (const float*)d_in[9];
  const float* c_b3 = (const float*)d_in[10];
  const float* t_w1 = (const float*)d_in[11];
  const float* t_b1 = (const float*)d_in[12];
  const float* t_w2 = (const float*)d_in[13];
  const float* t_b2 = (const float*)d_in[14];
  const float* t_w3 = (const float*)d_in[15];
  const float* t_b3 = (const float*)d_in[16];
  const float* cf_w = (const float*)d_in[17];
  const float* cf_b = (const float*)d_in[18];
  const float* wq = (const float*)d_in[19];
  const float* wk = (const float*)d_in[20];
  const float* wv = (const float*)d_in[21];
  float* out = (float*)d_out;

  const int M = kNumItem;         // 50000
  const int n_tok = in_sizes[0];  // 51200

  // ---- workspace carve-up (ws_size-tiered) ----
  char* w = (char*)d_ws;
  size_t off = 0;
  auto alloc = [&](size_t bytes) -> void* {
    void* p = w + off;
    off += (bytes + 255) & ~(size_t)255;
    return p;
  };
  float* invn_c = (float*)alloc((size_t)M * 4);
  float* invn_t = (float*)alloc((size_t)M * 4);
  bf16* c_emb = (bf16*)alloc((size_t)M * 64 * 2);
  bf16* t_emb = (bf16*)alloc((size_t)M * 64 * 2);
  bf16* cf_emb = (bf16*)alloc((size_t)M * 64 * 2);
  bf16* H1 = (bf16*)alloc((size_t)M * 1024 * 2);  // reused by text chain, then QK
  bf16* H2 = (bf16*)alloc((size_t)M * 256 * 2);

  // bf16 weight pack: c_w1,c_w2,c_w3,t_w1,t_w2,t_w3,cf_w,wq,wk,wv concatenated
  // (wq,wk adjacent -> one [128,64] B matrix for the fused QK GEMM)
  const int nw[kNWSeg] = {1024 * 1024, 256 * 1024, 64 * 256, 768 * 768, 256 * 768,
                          64 * 256,    64 * 64,    64 * 64,  64 * 64,   64 * 64};
  int wofs[kNWSeg + 1];
  wofs[0] = 0;
  for (int i = 0; i < kNWSeg; i++) wofs[i + 1] = wofs[i] + nw[i];
  bf16* Wb = (bf16*)alloc((size_t)wofs[kNWSeg] * 2);
  const bool useWb = (off <= ws_size);
  bf16* Ab = (bf16*)alloc((size_t)M * 1024 * 2);  // bf16 copy of content/text; then Xn|V
  const bool useAb = useWb && (off <= ws_size);
  // dense fused-embedding table: out[token] = fusedTab[seq[token]]
  float* fusedTab = (float*)alloc((size_t)M * 64 * 4);
  const bool useFused = (off <= ws_size);

  // aliases for the attention pipeline (regions free by the time they're used):
  const int R = M * 4;                                 // 200000 (item,modal) rows
  bf16* Xn = (bf16*)Ab;                                // 25.6 MB
  float* Vbuf = (float*)((char*)Ab + (size_t)R * 64 * 2);   // 51.2 MB (in Ab)
  bf16* QKbuf = (bf16*)H1;                             // R x 128 bf16 = 51.2 MB

  if (useWb) {
    WPack p;
    const float* srcs[kNWSeg] = {c_w1, c_w2, c_w3, t_w1, t_w2, t_w3, cf_w, wq, wk, wv};
    for (int i = 0; i < kNWSeg; i++) {
      p.src[i] = srcs[i];
      p.start4[i] = wofs[i] / 4;
    }
    p.total4 = wofs[kNWSeg] / 4;
    cvt_many<<<dim3(2048), dim3(256), 0, stream>>>(p, Wb);
  }

  if (useAb) {
    // ---- fat path: bf16 A + bf16 B everywhere big; wide tiles on big GEMMs ----
    cvt_rows_norm<<<dim3((M + 3) / 4), dim3(256), 0, stream>>>(content, Ab, invn_c, M, 1024);
    gemm_bt2<bf16><<<dim3(1024 / 256, (M + 127) / 128), dim3(512), 0, stream>>>(
        Ab, Wb + wofs[0], H1, M, 1024, 1024, invn_c, c_b1, 1);
    gemm_bt2<bf16><<<dim3(1, (M + 127) / 128), dim3(512), 0, stream>>>(
        H1, Wb + wofs[1], H2, M, 256, 1024, nullptr, c_b2, 1);
    gemm_bt<256, 64, bf16, bf16, bf16>
        <<<dim3(1, (M + 255) / 256), dim3(256), 0, stream>>>(
            H2, Wb + wofs[2], c_emb, M, 64, 256, nullptr, c_b3, 0);

    cvt_rows_norm<<<dim3((M + 3) / 4), dim3(256), 0, stream>>>(text, Ab, invn_t, M, 768);
    gemm_bt2<bf16><<<dim3(768 / 256, (M + 127) / 128), dim3(512), 0, stream>>>(
        Ab, Wb + wofs[3], H1, M, 768, 768, invn_t, t_b1, 1);
    gemm_bt2<bf16><<<dim3(1, (M + 127) / 128), dim3(512), 0, stream>>>(
        H1, Wb + wofs[4], H2, M, 256, 768, nullptr, t_b2, 1);
    gemm_bt<256, 64, bf16, bf16, bf16>
        <<<dim3(1, (M + 255) / 256), dim3(256), 0, stream>>>(
            H2, Wb + wofs[5], t_emb, M, 64, 256, nullptr, t_b3, 0);

    gemm_bt<256, 64, float, bf16, bf16>
        <<<dim3(1, (M + 255) / 256), dim3(256), 0, stream>>>(
            cf_feat, Wb + wofs[6], cf_emb, M, 64, 64, nullptr, cf_b, 0);

    // ---- attention pipeline: norm+LN -> QK (bf16) + V (fp32) GEMMs -> attn ----
    // H1 (QK), Ab (Xn|V), H2 all free at this point.
    norm_ln<<<dim3((R * 16 + 255) / 256), dim3(256), 0, stream>>>(
        c_emb, t_emb, cf_emb, item_emb, Xn, M);
    gemm_bt<256, 64, bf16, bf16, bf16>
        <<<dim3(2, (R + 255) / 256), dim3(256), 0, stream>>>(
            Xn, Wb + wofs[7], QKbuf, R, 128, 64, nullptr, nullptr, 0);
    gemm_bt<256, 64, bf16, bf16, float>
        <<<dim3(1, (R + 255) / 256), dim3(256), 0, stream>>>(
            Xn, Wb + wofs[9], Vbuf, R, 64, 64, nullptr, nullptr, 0);
    const int nGroup = (M + 3) / 4;  // 12500
    attn4<<<dim3((nGroup + 3) / 4), dim3(256), 0, stream>>>(
        QKbuf, Vbuf, fusedTab, nGroup);
    gather_out<<<dim3((n_tok * 16 + 255) / 256), dim3(256), 0, stream>>>(
        seq, fusedTab, out, n_tok);
  } else if (useWb) {
    // ---- slim path: fp32 A (packed in-kernel) + bf16 B ----
    row_invnorm<<<dim3((M + 3) / 4), dim3(256), 0, stream>>>(content, invn_c, M, 1024);
    row_invnorm<<<dim3((M + 3) / 4), dim3(256), 0, stream>>>(text, invn_t, M, 768);
    gemm_bt<128, 128, float, bf16, bf16>
        <<<dim3(1024 / 128, (M + 127) / 128), dim3(256), 0, stream>>>(
            content, Wb + wofs[0], H1, M, 1024, 1024, invn_c, c_b1, 1);
    gemm_bt<128, 128, bf16, bf16, bf16>
        <<<dim3(256 / 128, (M + 127) / 128), dim3(256), 0, stream>>>(
            H1, Wb + wofs[1], H2, M, 256, 1024, nullptr, c_b2, 1);
    gemm_bt<256, 64, bf16, bf16, bf16>
        <<<dim3(1, (M + 255) / 256), dim3(256), 0, stream>>>(
            H2, Wb + wofs[2], c_emb, M, 64, 256, nullptr, c_b3, 0);
    gemm_bt<128, 128, float, bf16, bf16>
        <<<dim3(768 / 128, (M + 127) / 128), dim3(256), 0, stream>>>(
            text, Wb + wofs[3], H1, M, 768, 768, invn_t, t_b1, 1);
    gemm_bt<128, 128, bf16, bf16, bf16>
        <<<dim3(256 / 128, (M + 127) / 128), dim3(256), 0, stream>>>(
            H1, Wb + wofs[4], H2, M, 256, 768, nullptr, t_b2, 1);
    gemm_bt<256, 64, bf16, bf16, bf16>
        <<<dim3(1, (M + 255) / 256), dim3(256), 0, stream>>>(
            H2, Wb + wofs[5], t_emb, M, 64, 256, nullptr, t_b3, 0);
    gemm_bt<256, 64, float, bf16, bf16>
        <<<dim3(1, (M + 255) / 256), dim3(256), 0, stream>>>(
            cf_feat, Wb + wofs[6], cf_emb, M, 64, 64, nullptr, cf_b, 0);
    if (useFused) {
      fuse_attn2<<<dim3(768), dim3(256), 0, stream>>>(
          nullptr, c_emb, t_emb, cf_emb, item_emb, wq, wk, wv, fusedTab, M);
      gather_out<<<dim3((n_tok * 16 + 255) / 256), dim3(256), 0, stream>>>(
          seq, fusedTab, out, n_tok);
    } else {
      fuse_attn2<<<dim3(768), dim3(256), 0, stream>>>(
          seq, c_emb, t_emb, cf_emb, item_emb, wq, wk, wv, out, n_tok);
    }
  } else {
    // ---- minimal path: fp32 A and B ----
    row_invnorm<<<dim3((M + 3) / 4), dim3(256), 0, stream>>>(content, invn_c, M, 1024);
    row_invnorm<<<dim3((M + 3) / 4), dim3(256), 0, stream>>>(text, invn_t, M, 768);
    gemm_bt<128, 128, float, float, bf16>
        <<<dim3(1024 / 128, (M + 127) / 128), dim3(256), 0, stream>>>(
            content, c_w1, H1, M, 1024, 1024, invn_c, c_b1, 1);
    gemm_bt<128, 128, bf16, float, bf16>
        <<<dim3(256 / 128, (M + 127) / 128), dim3(256), 0, stream>>>(
            H1, c_w2, H2, M, 256, 1024, nullptr, c_b2, 1);
    gemm_bt<256, 64, bf16, float, bf16>
        <<<dim3(1, (M + 255) / 256), dim3(256), 0, stream>>>(
            H2, c_w3, c_emb, M, 64, 256, nullptr, c_b3, 0);
    gemm_bt<128, 128, float, float, bf16>
        <<<dim3(768 / 128, (M + 127) / 128), dim3(256), 0, stream>>>(
            text, t_w1, H1, M, 768, 768, invn_t, t_b1, 1);
    gemm_bt<128, 128, bf16, float, bf16>
        <<<dim3(256 / 128, (M + 127) / 128), dim3(256), 0, stream>>>(
            H1, t_w2, H2, M, 256, 768, nullptr, t_b2, 1);
    gemm_bt<256, 64, bf16, float, bf16>
        <<<dim3(1, (M + 255) / 256), dim3(256), 0, stream>>>(
            H2, t_w3, t_emb, M, 64, 256, nullptr, t_b3, 0);
    gemm_bt<256, 64, float, float, bf16>
        <<<dim3(1, (M + 255) / 256), dim3(256), 0, stream>>>(
            cf_feat, cf_w, cf_emb, M, 64, 64, nullptr, cf_b, 0);
    fuse_attn2<<<dim3(768), dim3(256), 0, stream>>>(
        seq, c_emb, t_emb, cf_emb, item_emb, wq, wk, wv, out, n_tok);
  }
}

// Round 5
// 987.632 us; speedup vs baseline: 1.4365x; 1.0115x over previous
//
#include <hip/hip_runtime.h>
#include <hip/hip_bf16.h>
#include <type_traits>

typedef __hip_bfloat16 bf16;
typedef __attribute__((ext_vector_type(8))) short short8;
typedef __attribute__((ext_vector_type(4))) float floatx4;

static constexpr int kNumItem = 50000;

__device__ __forceinline__ float bf2f(const bf16 x) { return __bfloat162float(x); }

union alignas(16) Pack8 {
  bf16 b[8];
  short8 s;
};
union alignas(8) Pack4 {
  bf16 b[4];
  short4 s;
};

__device__ __forceinline__ void async_cp16(const void* g, void* l) {
  __builtin_amdgcn_global_load_lds((const __attribute__((address_space(1))) void*)g,
                                   (__attribute__((address_space(3))) void*)l, 16, 0, 0);
}

// counted vmcnt wait (T4): literal immediates via if constexpr dispatch.
template <int N>
__device__ __forceinline__ void wait_vm() {
  static_assert(N >= 0 && N <= 8, "unsupported vmcnt");
  if constexpr (N == 0) asm volatile("s_waitcnt vmcnt(0)" ::: "memory");
  else if constexpr (N == 1) asm volatile("s_waitcnt vmcnt(1)" ::: "memory");
  else if constexpr (N == 2) asm volatile("s_waitcnt vmcnt(2)" ::: "memory");
  else if constexpr (N == 3) asm volatile("s_waitcnt vmcnt(3)" ::: "memory");
  else if constexpr (N == 4) asm volatile("s_waitcnt vmcnt(4)" ::: "memory");
  else if constexpr (N == 5) asm volatile("s_waitcnt vmcnt(5)" ::: "memory");
  else if constexpr (N == 6) asm volatile("s_waitcnt vmcnt(6)" ::: "memory");
  else if constexpr (N == 7) asm volatile("s_waitcnt vmcnt(7)" ::: "memory");
  else asm volatile("s_waitcnt vmcnt(8)" ::: "memory");
}
__device__ __forceinline__ void wait_lgkm0() {
  asm volatile("s_waitcnt lgkmcnt(0)" ::: "memory");
}

// bijective XCD-chunk remap (m204): consecutive remapped ids stay on one XCD.
__device__ __forceinline__ int xcd_swz(int orig, int nwg) {
  const int nx = 8;
  const int q = nwg / nx, r = nwg % nx;
  const int xcd = orig % nx, loc = orig / nx;
  return (xcd < r ? xcd * (q + 1) : r * (q + 1) + (xcd - r) * q) + loc;
}

// ---------------- per-row 1/max(||x||,1e-12), fp32 input (slim path) ------------
__global__ __launch_bounds__(256) void row_invnorm(const float* __restrict__ X,
                                                   float* __restrict__ out,
                                                   int M, int K) {
  const int lane = threadIdx.x & 63;
  const int wave = threadIdx.x >> 6;
  const int row = blockIdx.x * 4 + wave;
  if (row >= M) return;
  const float* xr = X + (size_t)row * K;
  float s = 0.f;
  for (int c = lane * 8; c < K; c += 64 * 8) {
    float4 a = *(const float4*)(xr + c);
    float4 b = *(const float4*)(xr + c + 4);
    s += a.x * a.x + a.y * a.y + a.z * a.z + a.w * a.w;
    s += b.x * b.x + b.y * b.y + b.z * b.z + b.w * b.w;
  }
#pragma unroll
  for (int off = 32; off > 0; off >>= 1) s += __shfl_xor(s, off, 64);
  if (lane == 0) out[row] = 1.0f / fmaxf(sqrtf(s), 1e-12f);
}

// ------------- fused: fp32 row -> bf16 row copy + 1/||row|| (fat path) ----------
__global__ __launch_bounds__(256) void cvt_rows_norm(const float* __restrict__ X,
                                                     bf16* __restrict__ Xb,
                                                     float* __restrict__ out,
                                                     int M, int K) {
  const int lane = threadIdx.x & 63;
  const int wave = threadIdx.x >> 6;
  const int row = blockIdx.x * 4 + wave;
  if (row >= M) return;
  const float* xr = X + (size_t)row * K;
  bf16* dr = Xb + (size_t)row * K;
  float s = 0.f;
  for (int c = lane * 8; c < K; c += 64 * 8) {
    float4 a = *(const float4*)(xr + c);
    float4 b = *(const float4*)(xr + c + 4);
    s += a.x * a.x + a.y * a.y + a.z * a.z + a.w * a.w;
    s += b.x * b.x + b.y * b.y + b.z * b.z + b.w * b.w;
    Pack8 p;
    p.b[0] = __float2bfloat16(a.x); p.b[1] = __float2bfloat16(a.y);
    p.b[2] = __float2bfloat16(a.z); p.b[3] = __float2bfloat16(a.w);
    p.b[4] = __float2bfloat16(b.x); p.b[5] = __float2bfloat16(b.y);
    p.b[6] = __float2bfloat16(b.z); p.b[7] = __float2bfloat16(b.w);
    *(short8*)(void*)(dr + c) = p.s;
  }
#pragma unroll
  for (int off = 32; off > 0; off >>= 1) s += __shfl_xor(s, off, 64);
  if (lane == 0) out[row] = 1.0f / fmaxf(sqrtf(s), 1e-12f);
}

// ---------------- pack 10 fp32 weight matrices -> one contiguous bf16 region ----
static constexpr int kNWSeg = 10;
struct WPack {
  const float* src[kNWSeg];
  int start4[kNWSeg];  // chunk (float4) start offset of each segment in the concat
  int total4;
};
__global__ __launch_bounds__(256) void cvt_many(WPack p, bf16* __restrict__ dst) {
  int c = blockIdx.x * 256 + threadIdx.x;
  const int stride = gridDim.x * 256;
  for (; c < p.total4; c += stride) {
    int s = 0;
#pragma unroll
    for (int k = 1; k < kNWSeg; k++)
      if (c >= p.start4[k]) s = k;
    const float4 v = ((const float4*)p.src[s])[c - p.start4[s]];
    Pack4 q;
    q.b[0] = __float2bfloat16(v.x); q.b[1] = __float2bfloat16(v.y);
    q.b[2] = __float2bfloat16(v.z); q.b[3] = __float2bfloat16(v.w);
    *(short4*)(void*)(dst + (size_t)c * 4) = q.s;
  }
}

// ---------------- NT GEMM: C[M,N] = act(scale_m * (A[M,K] @ B[N,K]^T) + bias[N]) ----
// bf16xbf16: counted-vmcnt pipeline (T4) — never vmcnt(0) in steady state.
// Per K-step: wait vmcnt(LPT) -> barrier -> ds_read+MFMA -> lgkmcnt(0) -> barrier
// -> stage tile t+2 into the buffer just freed. fp32 sources: __syncthreads dbuf.
template <int BM, int BN, typename AT, typename BT, typename CT>
__global__ __launch_bounds__(256) void gemm_bt(const AT* __restrict__ A,
                                               const BT* __restrict__ B,
                                               CT* __restrict__ C,
                                               int M, int N, int K,
                                               const float* __restrict__ rowScale,
                                               const float* __restrict__ bias,
                                               int doRelu) {
  constexpr int BK = 32;
  __shared__ __align__(16) bf16 sA[2][BM * BK];
  __shared__ __align__(16) bf16 sB[2][BN * BK];
  const int t = threadIdx.x;
  const int lane = t & 63;
  const int wave = t >> 6;
  constexpr int WN = BN / 64;  // waves along N
  const int wm = wave / WN;
  const int wn = wave % WN;
  const int gx = gridDim.x;
  const int wgid = xcd_swz(blockIdx.y * gx + blockIdx.x, gx * gridDim.y);
  const int m0 = (wgid / gx) * BM;
  const int n0 = (wgid % gx) * BN;
  const int lane16 = lane & 15;
  const int quad = lane >> 4;

  auto stageA = [&](int k0, bf16* dst) {
#pragma unroll
    for (int it = 0; it < BM / 64; ++it) {
      int c = t + 256 * it;
      int row = c >> 2;
      int col = (c & 3) * 8;
      int gr = m0 + row;
      if (gr > M - 1) gr = M - 1;  // clamp: safe re-read, stores are guarded
      if constexpr (std::is_same_v<AT, bf16>) {
        async_cp16(A + (size_t)gr * K + k0 + col, dst + c * 8);
      } else {
        const float* src = A + (size_t)gr * K + k0 + col;
        float4 fa = *(const float4*)src;
        float4 fb = *(const float4*)(src + 4);
        Pack8 p;
        p.b[0] = __float2bfloat16(fa.x); p.b[1] = __float2bfloat16(fa.y);
        p.b[2] = __float2bfloat16(fa.z); p.b[3] = __float2bfloat16(fa.w);
        p.b[4] = __float2bfloat16(fb.x); p.b[5] = __float2bfloat16(fb.y);
        p.b[6] = __float2bfloat16(fb.z); p.b[7] = __float2bfloat16(fb.w);
        *(short8*)(void*)(dst + c * 8) = p.s;
      }
    }
  };
  auto stageB = [&](int k0, bf16* dst) {
#pragma unroll
    for (int it = 0; it < BN / 64; ++it) {
      int c = t + 256 * it;
      int row = c >> 2;
      int col = (c & 3) * 8;
      int gr = n0 + row;
      if (gr > N - 1) gr = N - 1;
      if constexpr (std::is_same_v<BT, bf16>) {
        async_cp16(B + (size_t)gr * K + k0 + col, dst + c * 8);
      } else {
        const float* src = B + (size_t)gr * K + k0 + col;
        float4 fa = *(const float4*)src;
        float4 fb = *(const float4*)(src + 4);
        Pack8 p;
        p.b[0] = __float2bfloat16(fa.x); p.b[1] = __float2bfloat16(fa.y);
        p.b[2] = __float2bfloat16(fa.z); p.b[3] = __float2bfloat16(fa.w);
        p.b[4] = __float2bfloat16(fb.x); p.b[5] = __float2bfloat16(fb.y);
        p.b[6] = __float2bfloat16(fb.z); p.b[7] = __float2bfloat16(fb.w);
        *(short8*)(void*)(dst + c * 8) = p.s;
      }
    }
  };

  floatx4 acc[4][4];
#pragma unroll
  for (int i = 0; i < 4; i++)
#pragma unroll
    for (int j = 0; j < 4; j++) acc[i][j] = (floatx4)0.0f;

  if constexpr (std::is_same_v<AT, bf16> && std::is_same_v<BT, bf16>) {
    // ---- counted-vmcnt pipeline ----
    constexpr int LPT = BM / 64 + BN / 64;  // loads/thread per tile
    const int nt = K / BK;
    stageA(0, sA[0]);
    stageB(0, sB[0]);
    if (nt > 1) {
      stageA(BK, sA[1]);
      stageB(BK, sB[1]);
    }
    for (int tt = 0; tt < nt; ++tt) {
      const int cur = tt & 1;
      if (tt + 1 < nt) wait_vm<LPT>();  // next tile's loads stay in flight
      else wait_vm<0>();
      __builtin_amdgcn_sched_barrier(0);
      __builtin_amdgcn_s_barrier();

      short8 afr[4], bfr[4];
#pragma unroll
      for (int i = 0; i < 4; i++)
        afr[i] = *(const short8*)(const void*)&sA[cur][(wm * 64 + i * 16 + lane16) * BK + quad * 8];
#pragma unroll
      for (int j = 0; j < 4; j++)
        bfr[j] = *(const short8*)(const void*)&sB[cur][(wn * 64 + j * 16 + lane16) * BK + quad * 8];
#pragma unroll
      for (int i = 0; i < 4; i++)
#pragma unroll
        for (int j = 0; j < 4; j++)
          acc[i][j] = __builtin_amdgcn_mfma_f32_16x16x32_bf16(afr[i], bfr[j], acc[i][j], 0, 0, 0);

      wait_lgkm0();  // all ds_reads retired before anyone overwrites this buffer
      __builtin_amdgcn_sched_barrier(0);
      __builtin_amdgcn_s_barrier();
      if (tt + 2 < nt) {
        stageA((tt + 2) * BK, sA[cur]);
        stageB((tt + 2) * BK, sB[cur]);
      }
    }
  } else {
    // ---- fp32-source fallback: __syncthreads double-buffer ----
    stageA(0, sA[0]);
    stageB(0, sB[0]);
    __syncthreads();
    int cur = 0;
    for (int k0 = 0; k0 < K; k0 += BK) {
      const int nxt = cur ^ 1;
      if (k0 + BK < K) {
        stageA(k0 + BK, sA[nxt]);
        stageB(k0 + BK, sB[nxt]);
      }
      short8 afr[4], bfr[4];
#pragma unroll
      for (int i = 0; i < 4; i++)
        afr[i] = *(const short8*)(const void*)&sA[cur][(wm * 64 + i * 16 + lane16) * BK + quad * 8];
#pragma unroll
      for (int j = 0; j < 4; j++)
        bfr[j] = *(const short8*)(const void*)&sB[cur][(wn * 64 + j * 16 + lane16) * BK + quad * 8];
#pragma unroll
      for (int i = 0; i < 4; i++)
#pragma unroll
        for (int j = 0; j < 4; j++)
          acc[i][j] = __builtin_amdgcn_mfma_f32_16x16x32_bf16(afr[i], bfr[j], acc[i][j], 0, 0, 0);
      __syncthreads();
      cur = nxt;
    }
  }

  // epilogue
#pragma unroll
  for (int i = 0; i < 4; i++) {
#pragma unroll
    for (int j = 0; j < 4; j++) {
      const int col = n0 + wn * 64 + j * 16 + lane16;
      const float bv = bias ? bias[col] : 0.f;
#pragma unroll
      for (int r = 0; r < 4; r++) {
        const int row = m0 + wm * 64 + i * 16 + quad * 4 + r;
        if (row < M) {
          float v = acc[i][j][r];
          if (rowScale) v *= rowScale[row];
          v += bv;
          if (doRelu) v = v > 0.f ? v : 0.f;
          if constexpr (std::is_same_v<CT, bf16>)
            C[(size_t)row * N + col] = __float2bfloat16(v);
          else
            C[(size_t)row * N + col] = v;
        }
      }
    }
  }
}

// ------- wide-tile NT GEMM: BM=128, BN=256, 512 threads (8 waves = 2Mx4N) -------
// bf16-only sources; counted-vmcnt pipeline (T4), 48 KB LDS -> 3 blocks/CU.
template <typename CT>
__global__ __launch_bounds__(512) void gemm_bt2(const bf16* __restrict__ A,
                                                const bf16* __restrict__ B,
                                                CT* __restrict__ C,
                                                int M, int N, int K,
                                                const float* __restrict__ rowScale,
                                                const float* __restrict__ bias,
                                                int doRelu) {
  constexpr int BM = 128, BN = 256, BK = 32;
  __shared__ __align__(16) bf16 sA[2][BM * BK];  // 2 x 8 KB
  __shared__ __align__(16) bf16 sB[2][BN * BK];  // 2 x 16 KB
  const int t = threadIdx.x;
  const int lane = t & 63;
  const int wave = t >> 6;   // 0..7
  const int wm = wave >> 2;  // 0..1 along M
  const int wn = wave & 3;   // 0..3 along N
  const int gx = gridDim.x;
  const int wgid = xcd_swz(blockIdx.y * gx + blockIdx.x, gx * gridDim.y);
  const int m0 = (wgid / gx) * BM;
  const int n0 = (wgid % gx) * BN;
  const int lane16 = lane & 15;
  const int quad = lane >> 4;

  auto stage = [&](int k0, bf16* dA, bf16* dB) {
    {  // A tile: 128 rows x 32 bf16 = 512 chunks, 1 per thread
      const int c = t;
      const int row = c >> 2;
      const int col = (c & 3) * 8;
      int gr = m0 + row;
      if (gr > M - 1) gr = M - 1;
      async_cp16(A + (size_t)gr * K + k0 + col, dA + c * 8);
    }
#pragma unroll
    for (int it = 0; it < 2; ++it) {  // B tile: 256 rows x 32 = 1024 chunks
      const int c = t + 512 * it;
      const int row = c >> 2;
      const int col = (c & 3) * 8;
      int gr = n0 + row;
      if (gr > N - 1) gr = N - 1;
      async_cp16(B + (size_t)gr * K + k0 + col, dB + c * 8);
    }
  };

  floatx4 acc[4][4];
#pragma unroll
  for (int i = 0; i < 4; i++)
#pragma unroll
    for (int j = 0; j < 4; j++) acc[i][j] = (floatx4)0.0f;

  const int nt = K / BK;
  stage(0, sA[0], sB[0]);
  if (nt > 1) stage(BK, sA[1], sB[1]);
  for (int tt = 0; tt < nt; ++tt) {
    const int cur = tt & 1;
    if (tt + 1 < nt) wait_vm<3>();  // 3 loads/thread for the next tile in flight
    else wait_vm<0>();
    __builtin_amdgcn_sched_barrier(0);
    __builtin_amdgcn_s_barrier();

    short8 afr[4], bfr[4];
#pragma unroll
    for (int i = 0; i < 4; i++)
      afr[i] = *(const short8*)(const void*)&sA[cur][(wm * 64 + i * 16 + lane16) * BK + quad * 8];
#pragma unroll
    for (int j = 0; j < 4; j++)
      bfr[j] = *(const short8*)(const void*)&sB[cur][(wn * 64 + j * 16 + lane16) * BK + quad * 8];
#pragma unroll
    for (int i = 0; i < 4; i++)
#pragma unroll
      for (int j = 0; j < 4; j++)
        acc[i][j] = __builtin_amdgcn_mfma_f32_16x16x32_bf16(afr[i], bfr[j], acc[i][j], 0, 0, 0);

    wait_lgkm0();
    __builtin_amdgcn_sched_barrier(0);
    __builtin_amdgcn_s_barrier();
    if (tt + 2 < nt) stage((tt + 2) * BK, sA[cur], sB[cur]);
  }

#pragma unroll
  for (int i = 0; i < 4; i++) {
#pragma unroll
    for (int j = 0; j < 4; j++) {
      const int col = n0 + wn * 64 + j * 16 + lane16;
      const float bv = bias ? bias[col] : 0.f;
#pragma unroll
      for (int r = 0; r < 4; r++) {
        const int row = m0 + wm * 64 + i * 16 + quad * 4 + r;
        if (row < M) {
          float v = acc[i][j][r];
          if (rowScale) v *= rowScale[row];
          v += bv;
          if (doRelu) v = v > 0.f ? v : 0.f;
          if constexpr (std::is_same_v<CT, bf16>)
            C[(size_t)row * N + col] = __float2bfloat16(v);
          else
            C[(size_t)row * N + col] = v;
        }
      }
    }
  }
}

// ---- l2norm + LayerNorm per (item,modal) row: 16 lanes/row, 4-stage butterfly ----
// Xn[row=item*4+m][64] bf16. Rows read from the 4 modality tables.
__global__ __launch_bounds__(256) void norm_ln(const bf16* __restrict__ c_emb,
                                               const bf16* __restrict__ t_emb,
                                               const bf16* __restrict__ cf_emb,
                                               const float* __restrict__ id_emb,
                                               bf16* __restrict__ Xn, int nItem) {
  const int gid = blockIdx.x * 256 + threadIdx.x;
  const int row = gid >> 4;
  const int d4 = gid & 15;
  if (row >= nItem * 4) return;
  const int item = row >> 2;
  const int m = row & 3;

  float x[4];
  if (m == 3) {
    const float4 f = *(const float4*)(id_emb + (size_t)item * 64 + d4 * 4);
    x[0] = f.x; x[1] = f.y; x[2] = f.z; x[3] = f.w;
  } else {
    const bf16* src = (m == 0) ? c_emb : (m == 1 ? t_emb : cf_emb);
    Pack4 p;
    p.s = *(const short4*)(const void*)(src + (size_t)item * 64 + d4 * 4);
    x[0] = bf2f(p.b[0]); x[1] = bf2f(p.b[1]); x[2] = bf2f(p.b[2]); x[3] = bf2f(p.b[3]);
  }

  float sm = x[0] + x[1] + x[2] + x[3];
  float ss = x[0] * x[0] + x[1] * x[1] + x[2] * x[2] + x[3] * x[3];
#pragma unroll
  for (int off = 1; off < 16; off <<= 1) {
    sm += __shfl_xor(sm, off, 64);
    ss += __shfl_xor(ss, off, 64);
  }
  const float inv = 1.0f / fmaxf(sqrtf(ss), 1e-12f);
  const float mu = sm * inv * (1.0f / 64.0f);
  const float ex2 = ss * inv * inv * (1.0f / 64.0f);
  const float var = ex2 - mu * mu;
  const float rs = rsqrtf(var + 1e-5f);

  Pack4 o;
#pragma unroll
  for (int c = 0; c < 4; c++) o.b[c] = __float2bfloat16((x[c] * inv - mu) * rs);
  *(short4*)(void*)(Xn + (size_t)row * 64 + d4 * 4) = o.s;
}

// ---- tiny attention: 4 items/wave, 16 lanes/item (lane = sub*16 + d4) ----------
// QK bf16 [nItem*4, 128] (cols 0-63 = Q, 64-127 = K); V fp32 [nItem*4, 64].
// out fp32 [nItem, 64]. Scores via 4-stage butterfly within 16 lanes.
__global__ __launch_bounds__(256) void attn4(const bf16* __restrict__ QK,
                                             const float* __restrict__ V,
                                             float* __restrict__ out, int nGroup) {
  const int t = threadIdx.x;
  const int wave = t >> 6;
  const int lane = t & 63;
  const int sub = lane >> 4;
  const int d4 = lane & 15;
  const int group = blockIdx.x * 4 + wave;
  if (group >= nGroup) return;
  const int item = group * 4 + sub;
  const size_t rb = (size_t)item * 4;

  float4 q4[4], k4[4], v4[4];
#pragma unroll
  for (int m = 0; m < 4; m++) {
    Pack4 pq, pk;
    pq.s = *(const short4*)(const void*)(QK + (rb + m) * 128 + d4 * 4);
    pk.s = *(const short4*)(const void*)(QK + (rb + m) * 128 + 64 + d4 * 4);
    q4[m] = float4{bf2f(pq.b[0]), bf2f(pq.b[1]), bf2f(pq.b[2]), bf2f(pq.b[3])};
    k4[m] = float4{bf2f(pk.b[0]), bf2f(pk.b[1]), bf2f(pk.b[2]), bf2f(pk.b[3])};
    v4[m] = *(const float4*)(V + (rb + m) * 64 + d4 * 4);
  }

  // per-lane partial dot over its 4 d's, then 4-stage butterfly within 16 lanes
  float p[16];
#pragma unroll
  for (int m = 0; m < 4; m++)
#pragma unroll
    for (int n = 0; n < 4; n++)
      p[m * 4 + n] = q4[m].x * k4[n].x + q4[m].y * k4[n].y +
                     q4[m].z * k4[n].z + q4[m].w * k4[n].w;
#pragma unroll
  for (int off = 1; off < 16; off <<= 1)
#pragma unroll
    for (int i = 0; i < 16; i++) p[i] += __shfl_xor(p[i], off, 64);

  float abar[4] = {0, 0, 0, 0};
#pragma unroll
  for (int m = 0; m < 4; m++) {
    const float s0 = p[m * 4 + 0] * 0.125f, s1 = p[m * 4 + 1] * 0.125f;
    const float s2 = p[m * 4 + 2] * 0.125f, s3 = p[m * 4 + 3] * 0.125f;
    const float mx = fmaxf(fmaxf(s0, s1), fmaxf(s2, s3));
    const float e0 = expf(s0 - mx), e1 = expf(s1 - mx);
    const float e2 = expf(s2 - mx), e3 = expf(s3 - mx);
    const float inv = 1.0f / (e0 + e1 + e2 + e3);
    abar[0] += e0 * inv;
    abar[1] += e1 * inv;
    abar[2] += e2 * inv;
    abar[3] += e3 * inv;
  }

  float4 o;
  o.x = 0.25f * (abar[0] * v4[0].x + abar[1] * v4[1].x + abar[2] * v4[2].x + abar[3] * v4[3].x);
  o.y = 0.25f * (abar[0] * v4[0].y + abar[1] * v4[1].y + abar[2] * v4[2].y + abar[3] * v4[3].y);
  o.z = 0.25f * (abar[0] * v4[0].z + abar[1] * v4[1].z + abar[2] * v4[2].z + abar[3] * v4[3].z);
  o.w = 0.25f * (abar[0] * v4[0].w + abar[1] * v4[1].w + abar[2] * v4[2].w + abar[3] * v4[3].w);
  *(float4*)(out + (size_t)item * 64 + d4 * 4) = o;
}

// ---- per-token/per-item fusion (FALLBACK path only) ----------------------------
__global__ __launch_bounds__(256, 4) void fuse_attn2(const int* __restrict__ seq,
                                                     const bf16* __restrict__ c_emb,
                                                     const bf16* __restrict__ t_emb,
                                                     const bf16* __restrict__ cf_emb,
                                                     const float* __restrict__ id_emb,
                                                     const float* __restrict__ wq,
                                                     const float* __restrict__ wk,
                                                     const float* __restrict__ wv,
                                                     float* __restrict__ out, int n_tok) {
  __shared__ __align__(16) float4 swc[3072];  // 48 KB: [mat][d4][j]
  __shared__ float sxn[4][4][64];             // 4 KB: [wave][m][d]
  const int t = threadIdx.x;
  const int lane = t & 63;
  const int wave = t >> 6;

  for (int c = t; c < 3072; c += 256) {
    const int mat = c >> 10, rem = c & 1023, d4 = rem >> 6, j = rem & 63;
    const float* W = (mat == 0) ? wq : (mat == 1 ? wk : wv);
    swc[c] = *(const float4*)(W + j * 64 + d4 * 4);
  }
  __syncthreads();

  const int gw = blockIdx.x * 4 + wave;
  const int gstride = gridDim.x * 4;
  for (int token = gw; token < n_tok; token += gstride) {
    int idx = seq ? seq[token] : token;
    if (idx >= kNumItem || idx < 0) idx = 0;

    float x[4];
    x[0] = bf2f(c_emb[(size_t)idx * 64 + lane]);
    x[1] = bf2f(t_emb[(size_t)idx * 64 + lane]);
    x[2] = bf2f(cf_emb[(size_t)idx * 64 + lane]);
    x[3] = id_emb[(size_t)idx * 64 + lane];

#pragma unroll
    for (int m = 0; m < 4; m++) {
      float sm = x[m], ss = x[m] * x[m];
#pragma unroll
      for (int off = 32; off > 0; off >>= 1) {
        sm += __shfl_xor(sm, off, 64);
        ss += __shfl_xor(ss, off, 64);
      }
      const float inv = 1.0f / fmaxf(sqrtf(ss), 1e-12f);
      const float xh = x[m] * inv;
      const float mu = sm * inv * (1.0f / 64.0f);
      const float ex2 = ss * inv * inv * (1.0f / 64.0f);
      const float var = ex2 - mu * mu;
      const float xn = (xh - mu) * rsqrtf(var + 1e-5f);
      x[m] = xn;
      sxn[wave][m][lane] = xn;
    }

    float q[4] = {0, 0, 0, 0}, kk[4] = {0, 0, 0, 0}, v[4] = {0, 0, 0, 0};
#pragma unroll
    for (int d4 = 0; d4 < 16; d4++) {
      const float4 a = swc[d4 * 64 + lane];
      const float4 b = swc[1024 + d4 * 64 + lane];
      const float4 g = swc[2048 + d4 * 64 + lane];
#pragma unroll
      for (int m = 0; m < 4; m++) {
        const float4 xn4 = *(const float4*)&sxn[wave][m][d4 * 4];
        q[m] += xn4.x * a.x + xn4.y * a.y + xn4.z * a.z + xn4.w * a.w;
        kk[m] += xn4.x * b.x + xn4.y * b.y + xn4.z * b.z + xn4.w * b.w;
        v[m] += xn4.x * g.x + xn4.y * g.y + xn4.z * g.z + xn4.w * g.w;
      }
    }

    float p[16];
#pragma unroll
    for (int m = 0; m < 4; m++)
#pragma unroll
      for (int n = 0; n < 4; n++) p[m * 4 + n] = q[m] * kk[n];
#pragma unroll
    for (int off = 1; off < 64; off <<= 1)
#pragma unroll
      for (int i = 0; i < 16; i++) p[i] += __shfl_xor(p[i], off, 64);

    float abar[4] = {0, 0, 0, 0};
#pragma unroll
    for (int m = 0; m < 4; m++) {
      float s0 = p[m * 4 + 0] * 0.125f, s1 = p[m * 4 + 1] * 0.125f;
      float s2 = p[m * 4 + 2] * 0.125f, s3 = p[m * 4 + 3] * 0.125f;
      float mx = fmaxf(fmaxf(s0, s1), fmaxf(s2, s3));
      float e0 = expf(s0 - mx), e1 = expf(s1 - mx), e2 = expf(s2 - mx), e3 = expf(s3 - mx);
      float inv = 1.0f / (e0 + e1 + e2 + e3);
      abar[0] += e0 * inv;
      abar[1] += e1 * inv;
      abar[2] += e2 * inv;
      abar[3] += e3 * inv;
    }
    const float o =
        0.25f * (abar[0] * v[0] + abar[1] * v[1] + abar[2] * v[2] + abar[3] * v[3]);
    out[(size_t)token * 64 + lane] = o;
  }
}

// ---- row gather: out[token] = fused[clamp(seq[token])]; 16 lanes x float4/row ----
__global__ __launch_bounds__(256) void gather_out(const int* __restrict__ seq,
                                                  const float* __restrict__ fused,
                                                  float* __restrict__ out, int n_tok) {
  const int gid = blockIdx.x * 256 + threadIdx.x;
  if (gid >= n_tok * 16) return;
  const int token = gid >> 4;
  const int c4 = gid & 15;
  int idx = seq[token];
  if (idx >= kNumItem || idx < 0) idx = 0;
  ((float4*)out)[(size_t)token * 16 + c4] = ((const float4*)fused)[(size_t)idx * 16 + c4];
}

extern "C" void kernel_launch(void* const* d_in, const int* in_sizes, int n_in,
                              void* d_out, int out_size, void* d_ws, size_t ws_size,
                              hipStream_t stream) {
  const int* seq = (const int*)d_in[0];
  const float* content = (const float*)d_in[1];
  const float* text = (const float*)d_in[2];
  const float* cf_feat = (const float*)d_in[3];
  const float* item_emb = (const float*)d_in[4];
  const float* c_w1 = (const float*)d_in[5];
  const float* c_b1 = (const float*)d_in[6];
  const float* c_w2 = (const float*)d_in[7];
  const float* c_b2 = (const float*)d_in[8];
  const float* c_w3 = (const float*)d_in[9];
  const float* c_b3 = (const float*)d_in[10];
  const float* t_w1 = (const float*)d_in[11];
  const float* t_b1 = (const float*)d_in[12];
  const float* t_w2 = (const float*)d_in[13];
  const float* t_b2 = (const float*)d_in[14];
  const float* t_w3 = (const float*)d_in[15];
  const float* t_b3 = (const float*)d_in[16];
  const float* cf_w = (const float*)d_in[17];
  const float* cf_b = (const float*)d_in[18];
  const float* wq = (const float*)d_in[19];
  const float* wk = (const float*)d_in[20];
  const float* wv = (const float*)d_in[21];
  float* out = (float*)d_out;

  const int M = kNumItem;         // 50000
  const int n_tok = in_sizes[0];  // 51200

  // ---- workspace carve-up (ws_size-tiered) ----
  char* w = (char*)d_ws;
  size_t off = 0;
  auto alloc = [&](size_t bytes) -> void* {
    void* p = w + off;
    off += (bytes + 255) & ~(size_t)255;
    return p;
  };
  float* invn_c = (float*)alloc((size_t)M * 4);
  float* invn_t = (float*)alloc((size_t)M * 4);
  bf16* c_emb = (bf16*)alloc((size_t)M * 64 * 2);
  bf16* t_emb = (bf16*)alloc((size_t)M * 64 * 2);
  bf16* cf_emb = (bf16*)alloc((size_t)M * 64 * 2);
  bf16* H1 = (bf16*)alloc((size_t)M * 1024 * 2);  // reused by text chain, then QK
  bf16* H2 = (bf16*)alloc((size_t)M * 256 * 2);

  // bf16 weight pack: c_w1,c_w2,c_w3,t_w1,t_w2,t_w3,cf_w,wq,wk,wv concatenated
  // (wq,wk adjacent -> one [128,64] B matrix for the fused QK GEMM)
  const int nw[kNWSeg] = {1024 * 1024, 256 * 1024, 64 * 256, 768 * 768, 256 * 768,
                          64 * 256,    64 * 64,    64 * 64,  64 * 64,   64 * 64};
  int wofs[kNWSeg + 1];
  wofs[0] = 0;
  for (int i = 0; i < kNWSeg; i++) wofs[i + 1] = wofs[i] + nw[i];
  bf16* Wb = (bf16*)alloc((size_t)wofs[kNWSeg] * 2);
  const bool useWb = (off <= ws_size);
  bf16* Ab = (bf16*)alloc((size_t)M * 1024 * 2);  // bf16 copy of content/text; then Xn|V
  const bool useAb = useWb && (off <= ws_size);
  // dense fused-embedding table: out[token] = fusedTab[seq[token]]
  float* fusedTab = (float*)alloc((size_t)M * 64 * 4);
  const bool useFused = (off <= ws_size);

  // aliases for the attention pipeline (regions free by the time they're used):
  const int R = M * 4;                                 // 200000 (item,modal) rows
  bf16* Xn = (bf16*)Ab;                                // 25.6 MB
  float* Vbuf = (float*)((char*)Ab + (size_t)R * 64 * 2);   // 51.2 MB (in Ab)
  bf16* QKbuf = (bf16*)H1;                             // R x 128 bf16 = 51.2 MB

  if (useWb) {
    WPack p;
    const float* srcs[kNWSeg] = {c_w1, c_w2, c_w3, t_w1, t_w2, t_w3, cf_w, wq, wk, wv};
    for (int i = 0; i < kNWSeg; i++) {
      p.src[i] = srcs[i];
      p.start4[i] = wofs[i] / 4;
    }
    p.total4 = wofs[kNWSeg] / 4;
    cvt_many<<<dim3(2048), dim3(256), 0, stream>>>(p, Wb);
  }

  if (useAb) {
    // ---- fat path: bf16 A + bf16 B everywhere big; wide tiles on big GEMMs ----
    cvt_rows_norm<<<dim3((M + 3) / 4), dim3(256), 0, stream>>>(content, Ab, invn_c, M, 1024);
    gemm_bt2<bf16><<<dim3(1024 / 256, (M + 127) / 128), dim3(512), 0, stream>>>(
        Ab, Wb + wofs[0], H1, M, 1024, 1024, invn_c, c_b1, 1);
    gemm_bt2<bf16><<<dim3(1, (M + 127) / 128), dim3(512), 0, stream>>>(
        H1, Wb + wofs[1], H2, M, 256, 1024, nullptr, c_b2, 1);
    gemm_bt<256, 64, bf16, bf16, bf16>
        <<<dim3(1, (M + 255) / 256), dim3(256), 0, stream>>>(
            H2, Wb + wofs[2], c_emb, M, 64, 256, nullptr, c_b3, 0);

    cvt_rows_norm<<<dim3((M + 3) / 4), dim3(256), 0, stream>>>(text, Ab, invn_t, M, 768);
    gemm_bt2<bf16><<<dim3(768 / 256, (M + 127) / 128), dim3(512), 0, stream>>>(
        Ab, Wb + wofs[3], H1, M, 768, 768, invn_t, t_b1, 1);
    gemm_bt2<bf16><<<dim3(1, (M + 127) / 128), dim3(512), 0, stream>>>(
        H1, Wb + wofs[4], H2, M, 256, 768, nullptr, t_b2, 1);
    gemm_bt<256, 64, bf16, bf16, bf16>
        <<<dim3(1, (M + 255) / 256), dim3(256), 0, stream>>>(
            H2, Wb + wofs[5], t_emb, M, 64, 256, nullptr, t_b3, 0);

    gemm_bt<256, 64, float, bf16, bf16>
        <<<dim3(1, (M + 255) / 256), dim3(256), 0, stream>>>(
            cf_feat, Wb + wofs[6], cf_emb, M, 64, 64, nullptr, cf_b, 0);

    // ---- attention pipeline: norm+LN -> QK (bf16) + V (fp32) GEMMs -> attn ----
    // H1 (QK), Ab (Xn|V), H2 all free at this point.
    norm_ln<<<dim3((R * 16 + 255) / 256), dim3(256), 0, stream>>>(
        c_emb, t_emb, cf_emb, item_emb, Xn, M);
    gemm_bt<256, 64, bf16, bf16, bf16>
        <<<dim3(2, (R + 255) / 256), dim3(256), 0, stream>>>(
            Xn, Wb + wofs[7], QKbuf, R, 128, 64, nullptr, nullptr, 0);
    gemm_bt<256, 64, bf16, bf16, float>
        <<<dim3(1, (R + 255) / 256), dim3(256), 0, stream>>>(
            Xn, Wb + wofs[9], Vbuf, R, 64, 64, nullptr, nullptr, 0);
    const int nGroup = (M + 3) / 4;  // 12500
    attn4<<<dim3((nGroup + 3) / 4), dim3(256), 0, stream>>>(
        QKbuf, Vbuf, fusedTab, nGroup);
    gather_out<<<dim3((n_tok * 16 + 255) / 256), dim3(256), 0, stream>>>(
        seq, fusedTab, out, n_tok);
  } else if (useWb) {
    // ---- slim path: fp32 A (packed in-kernel) + bf16 B ----
    row_invnorm<<<dim3((M + 3) / 4), dim3(256), 0, stream>>>(content, invn_c, M, 1024);
    row_invnorm<<<dim3((M + 3) / 4), dim3(256), 0, stream>>>(text, invn_t, M, 768);
    gemm_bt<128, 128, float, bf16, bf16>
        <<<dim3(1024 / 128, (M + 127) / 128), dim3(256), 0, stream>>>(
            content, Wb + wofs[0], H1, M, 1024, 1024, invn_c, c_b1, 1);
    gemm_bt<128, 128, bf16, bf16, bf16>
        <<<dim3(256 / 128, (M + 127) / 128), dim3(256), 0, stream>>>(
            H1, Wb + wofs[1], H2, M, 256, 1024, nullptr, c_b2, 1);
    gemm_bt<256, 64, bf16, bf16, bf16>
        <<<dim3(1, (M + 255) / 256), dim3(256), 0, stream>>>(
            H2, Wb + wofs[2], c_emb, M, 64, 256, nullptr, c_b3, 0);
    gemm_bt<128, 128, float, bf16, bf16>
        <<<dim3(768 / 128, (M + 127) / 128), dim3(256), 0, stream>>>(
            text, Wb + wofs[3], H1, M, 768, 768, invn_t, t_b1, 1);
    gemm_bt<128, 128, bf16, bf16, bf16>
        <<<dim3(256 / 128, (M + 127) / 128), dim3(256), 0, stream>>>(
            H1, Wb + wofs[4], H2, M, 256, 768, nullptr, t_b2, 1);
    gemm_bt<256, 64, bf16, bf16, bf16>
        <<<dim3(1, (M + 255) / 256), dim3(256), 0, stream>>>(
            H2, Wb + wofs[5], t_emb, M, 64, 256, nullptr, t_b3, 0);
    gemm_bt<256, 64, float, bf16, bf16>
        <<<dim3(1, (M + 255) / 256), dim3(256), 0, stream>>>(
            cf_feat, Wb + wofs[6], cf_emb, M, 64, 64, nullptr, cf_b, 0);
    if (useFused) {
      fuse_attn2<<<dim3(768), dim3(256), 0, stream>>>(
          nullptr, c_emb, t_emb, cf_emb, item_emb, wq, wk, wv, fusedTab, M);
      gather_out<<<dim3((n_tok * 16 + 255) / 256), dim3(256), 0, stream>>>(
          seq, fusedTab, out, n_tok);
    } else {
      fuse_attn2<<<dim3(768), dim3(256), 0, stream>>>(
          seq, c_emb, t_emb, cf_emb, item_emb, wq, wk, wv, out, n_tok);
    }
  } else {
    // ---- minimal path: fp32 A and B ----
    row_invnorm<<<dim3((M + 3) / 4), dim3(256), 0, stream>>>(content, invn_c, M, 1024);
    row_invnorm<<<dim3((M + 3) / 4), dim3(256), 0, stream>>>(text, invn_t, M, 768);
    gemm_bt<128, 128, float, float, bf16>
        <<<dim3(1024 / 128, (M + 127) / 128), dim3(256), 0, stream>>>(
            content, c_w1, H1, M, 1024, 1024, invn_c, c_b1, 1);
    gemm_bt<128, 128, bf16, float, bf16>
        <<<dim3(256 / 128, (M + 127) / 128), dim3(256), 0, stream>>>(
            H1, c_w2, H2, M, 256, 1024, nullptr, c_b2, 1);
    gemm_bt<256, 64, bf16, float, bf16>
        <<<dim3(1, (M + 255) / 256), dim3(256), 0, stream>>>(
            H2, c_w3, c_emb, M, 64, 256, nullptr, c_b3, 0);
    gemm_bt<128, 128, float, float, bf16>
        <<<dim3(768 / 128, (M + 127) / 128), dim3(256), 0, stream>>>(
            text, t_w1, H1, M, 768, 768, invn_t, t_b1, 1);
    gemm_bt<128, 128, bf16, float, bf16>
        <<<dim3(256 / 128, (M + 127) / 128), dim3(256), 0, stream>>>(
            H1, t_w2, H2, M, 256, 768, nullptr, t_b2, 1);
    gemm_bt<256, 64, bf16, float, bf16>
        <<<dim3(1, (M + 255) / 256), dim3(256), 0, stream>>>(
            H2, t_w3, t_emb, M, 64, 256, nullptr, t_b3, 0);
    gemm_bt<256, 64, float, float, bf16>
        <<<dim3(1, (M + 255) / 256), dim3(256), 0, stream>>>(
            cf_feat, cf_w, cf_emb, M, 64, 64, nullptr, cf_b, 0);
    fuse_attn2<<<dim3(768), dim3(256), 0, stream>>>(
        seq, c_emb, t_emb, cf_emb, item_emb, wq, wk, wv, out, n_tok);
  }
}

// Round 6
// 982.120 us; speedup vs baseline: 1.4446x; 1.0056x over previous
//
#include <hip/hip_runtime.h>
#include <hip/hip_bf16.h>
#include <type_traits>

typedef __hip_bfloat16 bf16;
typedef __attribute__((ext_vector_type(8))) short short8;
typedef __attribute__((ext_vector_type(4))) float floatx4;

static constexpr int kNumItem = 50000;

__device__ __forceinline__ float bf2f(const bf16 x) { return __bfloat162float(x); }

union alignas(16) Pack8 {
  bf16 b[8];
  short8 s;
};
union alignas(8) Pack4 {
  bf16 b[4];
  short4 s;
};

__device__ __forceinline__ void async_cp16(const void* g, void* l) {
  __builtin_amdgcn_global_load_lds((const __attribute__((address_space(1))) void*)g,
                                   (__attribute__((address_space(3))) void*)l, 16, 0, 0);
}

// counted vmcnt wait (T4): literal immediates via if constexpr dispatch.
template <int N>
__device__ __forceinline__ void wait_vm() {
  static_assert(N >= 0 && N <= 8, "unsupported vmcnt");
  if constexpr (N == 0) asm volatile("s_waitcnt vmcnt(0)" ::: "memory");
  else if constexpr (N == 1) asm volatile("s_waitcnt vmcnt(1)" ::: "memory");
  else if constexpr (N == 2) asm volatile("s_waitcnt vmcnt(2)" ::: "memory");
  else if constexpr (N == 3) asm volatile("s_waitcnt vmcnt(3)" ::: "memory");
  else if constexpr (N == 4) asm volatile("s_waitcnt vmcnt(4)" ::: "memory");
  else if constexpr (N == 5) asm volatile("s_waitcnt vmcnt(5)" ::: "memory");
  else if constexpr (N == 6) asm volatile("s_waitcnt vmcnt(6)" ::: "memory");
  else if constexpr (N == 7) asm volatile("s_waitcnt vmcnt(7)" ::: "memory");
  else asm volatile("s_waitcnt vmcnt(8)" ::: "memory");
}
__device__ __forceinline__ void wait_lgkm0() {
  asm volatile("s_waitcnt lgkmcnt(0)" ::: "memory");
}

// bijective XCD-chunk remap (m204): consecutive remapped ids stay on one XCD.
__device__ __forceinline__ int xcd_swz(int orig, int nwg) {
  const int nx = 8;
  const int q = nwg / nx, r = nwg % nx;
  const int xcd = orig % nx, loc = orig / nx;
  return (xcd < r ? xcd * (q + 1) : r * (q + 1) + (xcd - r) * q) + loc;
}

// LDS chunk swizzle (T2 adapted for 64B rows): slot' = slot ^ ((row>>1)&3).
// Applied to the global SOURCE column at stage time (LDS dest stays linear for
// global_load_lds) and to the ds_read chunk index. Involution within each row.
__device__ __forceinline__ int swz_col(int c) {
  return ((c & 3) ^ ((c >> 3) & 3)) * 8;  // c>>3 == (row=c>>2)>>1
}

// ---------------- per-row 1/max(||x||,1e-12), fp32 input (slim path) ------------
__global__ __launch_bounds__(256) void row_invnorm(const float* __restrict__ X,
                                                   float* __restrict__ out,
                                                   int M, int K) {
  const int lane = threadIdx.x & 63;
  const int wave = threadIdx.x >> 6;
  const int row = blockIdx.x * 4 + wave;
  if (row >= M) return;
  const float* xr = X + (size_t)row * K;
  float s = 0.f;
  for (int c = lane * 8; c < K; c += 64 * 8) {
    float4 a = *(const float4*)(xr + c);
    float4 b = *(const float4*)(xr + c + 4);
    s += a.x * a.x + a.y * a.y + a.z * a.z + a.w * a.w;
    s += b.x * b.x + b.y * b.y + b.z * b.z + b.w * b.w;
  }
#pragma unroll
  for (int off = 32; off > 0; off >>= 1) s += __shfl_xor(s, off, 64);
  if (lane == 0) out[row] = 1.0f / fmaxf(sqrtf(s), 1e-12f);
}

// ------------- fused: fp32 row -> bf16 row copy + 1/||row|| (fat path) ----------
__global__ __launch_bounds__(256) void cvt_rows_norm(const float* __restrict__ X,
                                                     bf16* __restrict__ Xb,
                                                     float* __restrict__ out,
                                                     int M, int K) {
  const int lane = threadIdx.x & 63;
  const int wave = threadIdx.x >> 6;
  const int row = blockIdx.x * 4 + wave;
  if (row >= M) return;
  const float* xr = X + (size_t)row * K;
  bf16* dr = Xb + (size_t)row * K;
  float s = 0.f;
  for (int c = lane * 8; c < K; c += 64 * 8) {
    float4 a = *(const float4*)(xr + c);
    float4 b = *(const float4*)(xr + c + 4);
    s += a.x * a.x + a.y * a.y + a.z * a.z + a.w * a.w;
    s += b.x * b.x + b.y * b.y + b.z * b.z + b.w * b.w;
    Pack8 p;
    p.b[0] = __float2bfloat16(a.x); p.b[1] = __float2bfloat16(a.y);
    p.b[2] = __float2bfloat16(a.z); p.b[3] = __float2bfloat16(a.w);
    p.b[4] = __float2bfloat16(b.x); p.b[5] = __float2bfloat16(b.y);
    p.b[6] = __float2bfloat16(b.z); p.b[7] = __float2bfloat16(b.w);
    *(short8*)(void*)(dr + c) = p.s;
  }
#pragma unroll
  for (int off = 32; off > 0; off >>= 1) s += __shfl_xor(s, off, 64);
  if (lane == 0) out[row] = 1.0f / fmaxf(sqrtf(s), 1e-12f);
}

// ---------------- pack 10 fp32 weight matrices -> one contiguous bf16 region ----
static constexpr int kNWSeg = 10;
struct WPack {
  const float* src[kNWSeg];
  int start4[kNWSeg];  // chunk (float4) start offset of each segment in the concat
  int total4;
};
__global__ __launch_bounds__(256) void cvt_many(WPack p, bf16* __restrict__ dst) {
  int c = blockIdx.x * 256 + threadIdx.x;
  const int stride = gridDim.x * 256;
  for (; c < p.total4; c += stride) {
    int s = 0;
#pragma unroll
    for (int k = 1; k < kNWSeg; k++)
      if (c >= p.start4[k]) s = k;
    const float4 v = ((const float4*)p.src[s])[c - p.start4[s]];
    Pack4 q;
    q.b[0] = __float2bfloat16(v.x); q.b[1] = __float2bfloat16(v.y);
    q.b[2] = __float2bfloat16(v.z); q.b[3] = __float2bfloat16(v.w);
    *(short4*)(void*)(dst + (size_t)c * 4) = q.s;
  }
}

// ---------------- NT GEMM: C[M,N] = act(scale_m * (A[M,K] @ B[N,K]^T) + bias[N]) ----
// bf16xbf16: counted-vmcnt pipeline (T4) + LDS chunk swizzle (T2): source column
// pre-swizzled so the swizzled ds_read is conflict-free (4-way -> 1-way per
// 8-lane service group). fp32 sources: __syncthreads dbuf, same swizzle.
template <int BM, int BN, typename AT, typename BT, typename CT>
__global__ __launch_bounds__(256) void gemm_bt(const AT* __restrict__ A,
                                               const BT* __restrict__ B,
                                               CT* __restrict__ C,
                                               int M, int N, int K,
                                               const float* __restrict__ rowScale,
                                               const float* __restrict__ bias,
                                               int doRelu) {
  constexpr int BK = 32;
  __shared__ __align__(16) bf16 sA[2][BM * BK];
  __shared__ __align__(16) bf16 sB[2][BN * BK];
  const int t = threadIdx.x;
  const int lane = t & 63;
  const int wave = t >> 6;
  constexpr int WN = BN / 64;  // waves along N
  const int wm = wave / WN;
  const int wn = wave % WN;
  const int gx = gridDim.x;
  const int wgid = xcd_swz(blockIdx.y * gx + blockIdx.x, gx * gridDim.y);
  const int m0 = (wgid / gx) * BM;
  const int n0 = (wgid % gx) * BN;
  const int lane16 = lane & 15;
  const int quad = lane >> 4;
  const int rsw = (lane16 >> 1) & 3;  // read-side swizzle (row bits 1-2 = lane16 bits 1-2)

  auto stageA = [&](int k0, bf16* dst) {
#pragma unroll
    for (int it = 0; it < BM / 64; ++it) {
      int c = t + 256 * it;
      int row = c >> 2;
      int col = swz_col(c);
      int gr = m0 + row;
      if (gr > M - 1) gr = M - 1;  // clamp: safe re-read, stores are guarded
      if constexpr (std::is_same_v<AT, bf16>) {
        async_cp16(A + (size_t)gr * K + k0 + col, dst + c * 8);
      } else {
        const float* src = A + (size_t)gr * K + k0 + col;
        float4 fa = *(const float4*)src;
        float4 fb = *(const float4*)(src + 4);
        Pack8 p;
        p.b[0] = __float2bfloat16(fa.x); p.b[1] = __float2bfloat16(fa.y);
        p.b[2] = __float2bfloat16(fa.z); p.b[3] = __float2bfloat16(fa.w);
        p.b[4] = __float2bfloat16(fb.x); p.b[5] = __float2bfloat16(fb.y);
        p.b[6] = __float2bfloat16(fb.z); p.b[7] = __float2bfloat16(fb.w);
        *(short8*)(void*)(dst + c * 8) = p.s;
      }
    }
  };
  auto stageB = [&](int k0, bf16* dst) {
#pragma unroll
    for (int it = 0; it < BN / 64; ++it) {
      int c = t + 256 * it;
      int row = c >> 2;
      int col = swz_col(c);
      int gr = n0 + row;
      if (gr > N - 1) gr = N - 1;
      if constexpr (std::is_same_v<BT, bf16>) {
        async_cp16(B + (size_t)gr * K + k0 + col, dst + c * 8);
      } else {
        const float* src = B + (size_t)gr * K + k0 + col;
        float4 fa = *(const float4*)src;
        float4 fb = *(const float4*)(src + 4);
        Pack8 p;
        p.b[0] = __float2bfloat16(fa.x); p.b[1] = __float2bfloat16(fa.y);
        p.b[2] = __float2bfloat16(fa.z); p.b[3] = __float2bfloat16(fa.w);
        p.b[4] = __float2bfloat16(fb.x); p.b[5] = __float2bfloat16(fb.y);
        p.b[6] = __float2bfloat16(fb.z); p.b[7] = __float2bfloat16(fb.w);
        *(short8*)(void*)(dst + c * 8) = p.s;
      }
    }
  };

  floatx4 acc[4][4];
#pragma unroll
  for (int i = 0; i < 4; i++)
#pragma unroll
    for (int j = 0; j < 4; j++) acc[i][j] = (floatx4)0.0f;

  if constexpr (std::is_same_v<AT, bf16> && std::is_same_v<BT, bf16>) {
    // ---- counted-vmcnt pipeline ----
    constexpr int LPT = BM / 64 + BN / 64;  // loads/thread per tile
    const int nt = K / BK;
    stageA(0, sA[0]);
    stageB(0, sB[0]);
    if (nt > 1) {
      stageA(BK, sA[1]);
      stageB(BK, sB[1]);
    }
    for (int tt = 0; tt < nt; ++tt) {
      const int cur = tt & 1;
      if (tt + 1 < nt) wait_vm<LPT>();  // next tile's loads stay in flight
      else wait_vm<0>();
      __builtin_amdgcn_sched_barrier(0);
      __builtin_amdgcn_s_barrier();

      short8 afr[4], bfr[4];
#pragma unroll
      for (int i = 0; i < 4; i++)
        afr[i] = *(const short8*)(const void*)
            &sA[cur][(wm * 64 + i * 16 + lane16) * BK + (quad ^ rsw) * 8];
#pragma unroll
      for (int j = 0; j < 4; j++)
        bfr[j] = *(const short8*)(const void*)
            &sB[cur][(wn * 64 + j * 16 + lane16) * BK + (quad ^ rsw) * 8];
#pragma unroll
      for (int i = 0; i < 4; i++)
#pragma unroll
        for (int j = 0; j < 4; j++)
          acc[i][j] = __builtin_amdgcn_mfma_f32_16x16x32_bf16(afr[i], bfr[j], acc[i][j], 0, 0, 0);

      wait_lgkm0();  // all ds_reads retired before anyone overwrites this buffer
      __builtin_amdgcn_sched_barrier(0);
      __builtin_amdgcn_s_barrier();
      if (tt + 2 < nt) {
        stageA((tt + 2) * BK, sA[cur]);
        stageB((tt + 2) * BK, sB[cur]);
      }
    }
  } else {
    // ---- fp32-source fallback: __syncthreads double-buffer ----
    stageA(0, sA[0]);
    stageB(0, sB[0]);
    __syncthreads();
    int cur = 0;
    for (int k0 = 0; k0 < K; k0 += BK) {
      const int nxt = cur ^ 1;
      if (k0 + BK < K) {
        stageA(k0 + BK, sA[nxt]);
        stageB(k0 + BK, sB[nxt]);
      }
      short8 afr[4], bfr[4];
#pragma unroll
      for (int i = 0; i < 4; i++)
        afr[i] = *(const short8*)(const void*)
            &sA[cur][(wm * 64 + i * 16 + lane16) * BK + (quad ^ rsw) * 8];
#pragma unroll
      for (int j = 0; j < 4; j++)
        bfr[j] = *(const short8*)(const void*)
            &sB[cur][(wn * 64 + j * 16 + lane16) * BK + (quad ^ rsw) * 8];
#pragma unroll
      for (int i = 0; i < 4; i++)
#pragma unroll
        for (int j = 0; j < 4; j++)
          acc[i][j] = __builtin_amdgcn_mfma_f32_16x16x32_bf16(afr[i], bfr[j], acc[i][j], 0, 0, 0);
      __syncthreads();
      cur = nxt;
    }
  }

  // epilogue
#pragma unroll
  for (int i = 0; i < 4; i++) {
#pragma unroll
    for (int j = 0; j < 4; j++) {
      const int col = n0 + wn * 64 + j * 16 + lane16;
      const float bv = bias ? bias[col] : 0.f;
#pragma unroll
      for (int r = 0; r < 4; r++) {
        const int row = m0 + wm * 64 + i * 16 + quad * 4 + r;
        if (row < M) {
          float v = acc[i][j][r];
          if (rowScale) v *= rowScale[row];
          v += bv;
          if (doRelu) v = v > 0.f ? v : 0.f;
          if constexpr (std::is_same_v<CT, bf16>)
            C[(size_t)row * N + col] = __float2bfloat16(v);
          else
            C[(size_t)row * N + col] = v;
        }
      }
    }
  }
}

// ------- wide-tile NT GEMM: BM=128, BN=256, 512 threads (8 waves = 2Mx4N) -------
// bf16-only; counted-vmcnt pipeline (T4) + LDS chunk swizzle (T2).
template <typename CT>
__global__ __launch_bounds__(512) void gemm_bt2(const bf16* __restrict__ A,
                                                const bf16* __restrict__ B,
                                                CT* __restrict__ C,
                                                int M, int N, int K,
                                                const float* __restrict__ rowScale,
                                                const float* __restrict__ bias,
                                                int doRelu) {
  constexpr int BM = 128, BN = 256, BK = 32;
  __shared__ __align__(16) bf16 sA[2][BM * BK];  // 2 x 8 KB
  __shared__ __align__(16) bf16 sB[2][BN * BK];  // 2 x 16 KB
  const int t = threadIdx.x;
  const int lane = t & 63;
  const int wave = t >> 6;   // 0..7
  const int wm = wave >> 2;  // 0..1 along M
  const int wn = wave & 3;   // 0..3 along N
  const int gx = gridDim.x;
  const int wgid = xcd_swz(blockIdx.y * gx + blockIdx.x, gx * gridDim.y);
  const int m0 = (wgid / gx) * BM;
  const int n0 = (wgid % gx) * BN;
  const int lane16 = lane & 15;
  const int quad = lane >> 4;
  const int rsw = (lane16 >> 1) & 3;

  auto stage = [&](int k0, bf16* dA, bf16* dB) {
    {  // A tile: 128 rows x 32 bf16 = 512 chunks, 1 per thread
      const int c = t;
      const int row = c >> 2;
      const int col = swz_col(c);
      int gr = m0 + row;
      if (gr > M - 1) gr = M - 1;
      async_cp16(A + (size_t)gr * K + k0 + col, dA + c * 8);
    }
#pragma unroll
    for (int it = 0; it < 2; ++it) {  // B tile: 256 rows x 32 = 1024 chunks
      const int c = t + 512 * it;
      const int row = c >> 2;
      const int col = swz_col(c);
      int gr = n0 + row;
      if (gr > N - 1) gr = N - 1;
      async_cp16(B + (size_t)gr * K + k0 + col, dB + c * 8);
    }
  };

  floatx4 acc[4][4];
#pragma unroll
  for (int i = 0; i < 4; i++)
#pragma unroll
    for (int j = 0; j < 4; j++) acc[i][j] = (floatx4)0.0f;

  const int nt = K / BK;
  stage(0, sA[0], sB[0]);
  if (nt > 1) stage(BK, sA[1], sB[1]);
  for (int tt = 0; tt < nt; ++tt) {
    const int cur = tt & 1;
    if (tt + 1 < nt) wait_vm<3>();  // 3 loads/thread for the next tile in flight
    else wait_vm<0>();
    __builtin_amdgcn_sched_barrier(0);
    __builtin_amdgcn_s_barrier();

    short8 afr[4], bfr[4];
#pragma unroll
    for (int i = 0; i < 4; i++)
      afr[i] = *(const short8*)(const void*)
          &sA[cur][(wm * 64 + i * 16 + lane16) * BK + (quad ^ rsw) * 8];
#pragma unroll
    for (int j = 0; j < 4; j++)
      bfr[j] = *(const short8*)(const void*)
          &sB[cur][(wn * 64 + j * 16 + lane16) * BK + (quad ^ rsw) * 8];
#pragma unroll
    for (int i = 0; i < 4; i++)
#pragma unroll
      for (int j = 0; j < 4; j++)
        acc[i][j] = __builtin_amdgcn_mfma_f32_16x16x32_bf16(afr[i], bfr[j], acc[i][j], 0, 0, 0);

    wait_lgkm0();
    __builtin_amdgcn_sched_barrier(0);
    __builtin_amdgcn_s_barrier();
    if (tt + 2 < nt) stage((tt + 2) * BK, sA[cur], sB[cur]);
  }

#pragma unroll
  for (int i = 0; i < 4; i++) {
#pragma unroll
    for (int j = 0; j < 4; j++) {
      const int col = n0 + wn * 64 + j * 16 + lane16;
      const float bv = bias ? bias[col] : 0.f;
#pragma unroll
      for (int r = 0; r < 4; r++) {
        const int row = m0 + wm * 64 + i * 16 + quad * 4 + r;
        if (row < M) {
          float v = acc[i][j][r];
          if (rowScale) v *= rowScale[row];
          v += bv;
          if (doRelu) v = v > 0.f ? v : 0.f;
          if constexpr (std::is_same_v<CT, bf16>)
            C[(size_t)row * N + col] = __float2bfloat16(v);
          else
            C[(size_t)row * N + col] = v;
        }
      }
    }
  }
}

// ---- l2norm + LayerNorm per (item,modal) row: 16 lanes/row, 4-stage butterfly ----
// Xn[row=item*4+m][64] bf16. Rows read from the 4 modality tables.
__global__ __launch_bounds__(256) void norm_ln(const bf16* __restrict__ c_emb,
                                               const bf16* __restrict__ t_emb,
                                               const bf16* __restrict__ cf_emb,
                                               const float* __restrict__ id_emb,
                                               bf16* __restrict__ Xn, int nItem) {
  const int gid = blockIdx.x * 256 + threadIdx.x;
  const int row = gid >> 4;
  const int d4 = gid & 15;
  if (row >= nItem * 4) return;
  const int item = row >> 2;
  const int m = row & 3;

  float x[4];
  if (m == 3) {
    const float4 f = *(const float4*)(id_emb + (size_t)item * 64 + d4 * 4);
    x[0] = f.x; x[1] = f.y; x[2] = f.z; x[3] = f.w;
  } else {
    const bf16* src = (m == 0) ? c_emb : (m == 1 ? t_emb : cf_emb);
    Pack4 p;
    p.s = *(const short4*)(const void*)(src + (size_t)item * 64 + d4 * 4);
    x[0] = bf2f(p.b[0]); x[1] = bf2f(p.b[1]); x[2] = bf2f(p.b[2]); x[3] = bf2f(p.b[3]);
  }

  float sm = x[0] + x[1] + x[2] + x[3];
  float ss = x[0] * x[0] + x[1] * x[1] + x[2] * x[2] + x[3] * x[3];
#pragma unroll
  for (int off = 1; off < 16; off <<= 1) {
    sm += __shfl_xor(sm, off, 64);
    ss += __shfl_xor(ss, off, 64);
  }
  const float inv = 1.0f / fmaxf(sqrtf(ss), 1e-12f);
  const float mu = sm * inv * (1.0f / 64.0f);
  const float ex2 = ss * inv * inv * (1.0f / 64.0f);
  const float var = ex2 - mu * mu;
  const float rs = rsqrtf(var + 1e-5f);

  Pack4 o;
#pragma unroll
  for (int c = 0; c < 4; c++) o.b[c] = __float2bfloat16((x[c] * inv - mu) * rs);
  *(short4*)(void*)(Xn + (size_t)row * 64 + d4 * 4) = o.s;
}

// ---- tiny attention: 4 items/wave, 16 lanes/item (lane = sub*16 + d4) ----------
// QK bf16 [nItem*4, 128] (cols 0-63 = Q, 64-127 = K); V fp32 [nItem*4, 64].
// out fp32 [nItem, 64]. Scores via 4-stage butterfly within 16 lanes.
__global__ __launch_bounds__(256) void attn4(const bf16* __restrict__ QK,
                                             const float* __restrict__ V,
                                             float* __restrict__ out, int nGroup) {
  const int t = threadIdx.x;
  const int wave = t >> 6;
  const int lane = t & 63;
  const int sub = lane >> 4;
  const int d4 = lane & 15;
  const int group = blockIdx.x * 4 + wave;
  if (group >= nGroup) return;
  const int item = group * 4 + sub;
  const size_t rb = (size_t)item * 4;

  float4 q4[4], k4[4], v4[4];
#pragma unroll
  for (int m = 0; m < 4; m++) {
    Pack4 pq, pk;
    pq.s = *(const short4*)(const void*)(QK + (rb + m) * 128 + d4 * 4);
    pk.s = *(const short4*)(const void*)(QK + (rb + m) * 128 + 64 + d4 * 4);
    q4[m] = float4{bf2f(pq.b[0]), bf2f(pq.b[1]), bf2f(pq.b[2]), bf2f(pq.b[3])};
    k4[m] = float4{bf2f(pk.b[0]), bf2f(pk.b[1]), bf2f(pk.b[2]), bf2f(pk.b[3])};
    v4[m] = *(const float4*)(V + (rb + m) * 64 + d4 * 4);
  }

  // per-lane partial dot over its 4 d's, then 4-stage butterfly within 16 lanes
  float p[16];
#pragma unroll
  for (int m = 0; m < 4; m++)
#pragma unroll
    for (int n = 0; n < 4; n++)
      p[m * 4 + n] = q4[m].x * k4[n].x + q4[m].y * k4[n].y +
                     q4[m].z * k4[n].z + q4[m].w * k4[n].w;
#pragma unroll
  for (int off = 1; off < 16; off <<= 1)
#pragma unroll
    for (int i = 0; i < 16; i++) p[i] += __shfl_xor(p[i], off, 64);

  float abar[4] = {0, 0, 0, 0};
#pragma unroll
  for (int m = 0; m < 4; m++) {
    const float s0 = p[m * 4 + 0] * 0.125f, s1 = p[m * 4 + 1] * 0.125f;
    const float s2 = p[m * 4 + 2] * 0.125f, s3 = p[m * 4 + 3] * 0.125f;
    const float mx = fmaxf(fmaxf(s0, s1), fmaxf(s2, s3));
    const float e0 = expf(s0 - mx), e1 = expf(s1 - mx);
    const float e2 = expf(s2 - mx), e3 = expf(s3 - mx);
    const float inv = 1.0f / (e0 + e1 + e2 + e3);
    abar[0] += e0 * inv;
    abar[1] += e1 * inv;
    abar[2] += e2 * inv;
    abar[3] += e3 * inv;
  }

  float4 o;
  o.x = 0.25f * (abar[0] * v4[0].x + abar[1] * v4[1].x + abar[2] * v4[2].x + abar[3] * v4[3].x);
  o.y = 0.25f * (abar[0] * v4[0].y + abar[1] * v4[1].y + abar[2] * v4[2].y + abar[3] * v4[3].y);
  o.z = 0.25f * (abar[0] * v4[0].z + abar[1] * v4[1].z + abar[2] * v4[2].z + abar[3] * v4[3].z);
  o.w = 0.25f * (abar[0] * v4[0].w + abar[1] * v4[1].w + abar[2] * v4[2].w + abar[3] * v4[3].w);
  *(float4*)(out + (size_t)item * 64 + d4 * 4) = o;
}

// ---- per-token/per-item fusion (FALLBACK path only) ----------------------------
__global__ __launch_bounds__(256, 4) void fuse_attn2(const int* __restrict__ seq,
                                                     const bf16* __restrict__ c_emb,
                                                     const bf16* __restrict__ t_emb,
                                                     const bf16* __restrict__ cf_emb,
                                                     const float* __restrict__ id_emb,
                                                     const float* __restrict__ wq,
                                                     const float* __restrict__ wk,
                                                     const float* __restrict__ wv,
                                                     float* __restrict__ out, int n_tok) {
  __shared__ __align__(16) float4 swc[3072];  // 48 KB: [mat][d4][j]
  __shared__ float sxn[4][4][64];             // 4 KB: [wave][m][d]
  const int t = threadIdx.x;
  const int lane = t & 63;
  const int wave = t >> 6;

  for (int c = t; c < 3072; c += 256) {
    const int mat = c >> 10, rem = c & 1023, d4 = rem >> 6, j = rem & 63;
    const float* W = (mat == 0) ? wq : (mat == 1 ? wk : wv);
    swc[c] = *(const float4*)(W + j * 64 + d4 * 4);
  }
  __syncthreads();

  const int gw = blockIdx.x * 4 + wave;
  const int gstride = gridDim.x * 4;
  for (int token = gw; token < n_tok; token += gstride) {
    int idx = seq ? seq[token] : token;
    if (idx >= kNumItem || idx < 0) idx = 0;

    float x[4];
    x[0] = bf2f(c_emb[(size_t)idx * 64 + lane]);
    x[1] = bf2f(t_emb[(size_t)idx * 64 + lane]);
    x[2] = bf2f(cf_emb[(size_t)idx * 64 + lane]);
    x[3] = id_emb[(size_t)idx * 64 + lane];

#pragma unroll
    for (int m = 0; m < 4; m++) {
      float sm = x[m], ss = x[m] * x[m];
#pragma unroll
      for (int off = 32; off > 0; off >>= 1) {
        sm += __shfl_xor(sm, off, 64);
        ss += __shfl_xor(ss, off, 64);
      }
      const float inv = 1.0f / fmaxf(sqrtf(ss), 1e-12f);
      const float xh = x[m] * inv;
      const float mu = sm * inv * (1.0f / 64.0f);
      const float ex2 = ss * inv * inv * (1.0f / 64.0f);
      const float var = ex2 - mu * mu;
      const float xn = (xh - mu) * rsqrtf(var + 1e-5f);
      x[m] = xn;
      sxn[wave][m][lane] = xn;
    }

    float q[4] = {0, 0, 0, 0}, kk[4] = {0, 0, 0, 0}, v[4] = {0, 0, 0, 0};
#pragma unroll
    for (int d4 = 0; d4 < 16; d4++) {
      const float4 a = swc[d4 * 64 + lane];
      const float4 b = swc[1024 + d4 * 64 + lane];
      const float4 g = swc[2048 + d4 * 64 + lane];
#pragma unroll
      for (int m = 0; m < 4; m++) {
        const float4 xn4 = *(const float4*)&sxn[wave][m][d4 * 4];
        q[m] += xn4.x * a.x + xn4.y * a.y + xn4.z * a.z + xn4.w * a.w;
        kk[m] += xn4.x * b.x + xn4.y * b.y + xn4.z * b.z + xn4.w * b.w;
        v[m] += xn4.x * g.x + xn4.y * g.y + xn4.z * g.z + xn4.w * g.w;
      }
    }

    float p[16];
#pragma unroll
    for (int m = 0; m < 4; m++)
#pragma unroll
      for (int n = 0; n < 4; n++) p[m * 4 + n] = q[m] * kk[n];
#pragma unroll
    for (int off = 1; off < 64; off <<= 1)
#pragma unroll
      for (int i = 0; i < 16; i++) p[i] += __shfl_xor(p[i], off, 64);

    float abar[4] = {0, 0, 0, 0};
#pragma unroll
    for (int m = 0; m < 4; m++) {
      float s0 = p[m * 4 + 0] * 0.125f, s1 = p[m * 4 + 1] * 0.125f;
      float s2 = p[m * 4 + 2] * 0.125f, s3 = p[m * 4 + 3] * 0.125f;
      float mx = fmaxf(fmaxf(s0, s1), fmaxf(s2, s3));
      float e0 = expf(s0 - mx), e1 = expf(s1 - mx), e2 = expf(s2 - mx), e3 = expf(s3 - mx);
      float inv = 1.0f / (e0 + e1 + e2 + e3);
      abar[0] += e0 * inv;
      abar[1] += e1 * inv;
      abar[2] += e2 * inv;
      abar[3] += e3 * inv;
    }
    const float o =
        0.25f * (abar[0] * v[0] + abar[1] * v[1] + abar[2] * v[2] + abar[3] * v[3]);
    out[(size_t)token * 64 + lane] = o;
  }
}

// ---- row gather: out[token] = fused[clamp(seq[token])]; 16 lanes x float4/row ----
__global__ __launch_bounds__(256) void gather_out(const int* __restrict__ seq,
                                                  const float* __restrict__ fused,
                                                  float* __restrict__ out, int n_tok) {
  const int gid = blockIdx.x * 256 + threadIdx.x;
  if (gid >= n_tok * 16) return;
  const int token = gid >> 4;
  const int c4 = gid & 15;
  int idx = seq[token];
  if (idx >= kNumItem || idx < 0) idx = 0;
  ((float4*)out)[(size_t)token * 16 + c4] = ((const float4*)fused)[(size_t)idx * 16 + c4];
}

extern "C" void kernel_launch(void* const* d_in, const int* in_sizes, int n_in,
                              void* d_out, int out_size, void* d_ws, size_t ws_size,
                              hipStream_t stream) {
  const int* seq = (const int*)d_in[0];
  const float* content = (const float*)d_in[1];
  const float* text = (const float*)d_in[2];
  const float* cf_feat = (const float*)d_in[3];
  const float* item_emb = (const float*)d_in[4];
  const float* c_w1 = (const float*)d_in[5];
  const float* c_b1 = (const float*)d_in[6];
  const float* c_w2 = (const float*)d_in[7];
  const float* c_b2 = (const float*)d_in[8];
  const float* c_w3 = (const float*)d_in[9];
  const float* c_b3 = (const float*)d_in[10];
  const float* t_w1 = (const float*)d_in[11];
  const float* t_b1 = (const float*)d_in[12];
  const float* t_w2 = (const float*)d_in[13];
  const float* t_b2 = (const float*)d_in[14];
  const float* t_w3 = (const float*)d_in[15];
  const float* t_b3 = (const float*)d_in[16];
  const float* cf_w = (const float*)d_in[17];
  const float* cf_b = (const float*)d_in[18];
  const float* wq = (const float*)d_in[19];
  const float* wk = (const float*)d_in[20];
  const float* wv = (const float*)d_in[21];
  float* out = (float*)d_out;

  const int M = kNumItem;         // 50000
  const int n_tok = in_sizes[0];  // 51200

  // ---- workspace carve-up (ws_size-tiered) ----
  char* w = (char*)d_ws;
  size_t off = 0;
  auto alloc = [&](size_t bytes) -> void* {
    void* p = w + off;
    off += (bytes + 255) & ~(size_t)255;
    return p;
  };
  float* invn_c = (float*)alloc((size_t)M * 4);
  float* invn_t = (float*)alloc((size_t)M * 4);
  bf16* c_emb = (bf16*)alloc((size_t)M * 64 * 2);
  bf16* t_emb = (bf16*)alloc((size_t)M * 64 * 2);
  bf16* cf_emb = (bf16*)alloc((size_t)M * 64 * 2);
  bf16* H1 = (bf16*)alloc((size_t)M * 1024 * 2);  // reused by text chain, then QK
  bf16* H2 = (bf16*)alloc((size_t)M * 256 * 2);

  // bf16 weight pack: c_w1,c_w2,c_w3,t_w1,t_w2,t_w3,cf_w,wq,wk,wv concatenated
  // (wq,wk adjacent -> one [128,64] B matrix for the fused QK GEMM)
  const int nw[kNWSeg] = {1024 * 1024, 256 * 1024, 64 * 256, 768 * 768, 256 * 768,
                          64 * 256,    64 * 64,    64 * 64,  64 * 64,   64 * 64};
  int wofs[kNWSeg + 1];
  wofs[0] = 0;
  for (int i = 0; i < kNWSeg; i++) wofs[i + 1] = wofs[i] + nw[i];
  bf16* Wb = (bf16*)alloc((size_t)wofs[kNWSeg] * 2);
  const bool useWb = (off <= ws_size);
  bf16* Ab = (bf16*)alloc((size_t)M * 1024 * 2);  // bf16 copy of content/text; then Xn|V
  const bool useAb = useWb && (off <= ws_size);
  // dense fused-embedding table: out[token] = fusedTab[seq[token]]
  float* fusedTab = (float*)alloc((size_t)M * 64 * 4);
  const bool useFused = (off <= ws_size);

  // aliases for the attention pipeline (regions free by the time they're used):
  const int R = M * 4;                                 // 200000 (item,modal) rows
  bf16* Xn = (bf16*)Ab;                                // 25.6 MB
  float* Vbuf = (float*)((char*)Ab + (size_t)R * 64 * 2);   // 51.2 MB (in Ab)
  bf16* QKbuf = (bf16*)H1;                             // R x 128 bf16 = 51.2 MB

  if (useWb) {
    WPack p;
    const float* srcs[kNWSeg] = {c_w1, c_w2, c_w3, t_w1, t_w2, t_w3, cf_w, wq, wk, wv};
    for (int i = 0; i < kNWSeg; i++) {
      p.src[i] = srcs[i];
      p.start4[i] = wofs[i] / 4;
    }
    p.total4 = wofs[kNWSeg] / 4;
    cvt_many<<<dim3(2048), dim3(256), 0, stream>>>(p, Wb);
  }

  if (useAb) {
    // ---- fat path: bf16 A + bf16 B everywhere big; wide tiles on big GEMMs ----
    cvt_rows_norm<<<dim3((M + 3) / 4), dim3(256), 0, stream>>>(content, Ab, invn_c, M, 1024);
    gemm_bt2<bf16><<<dim3(1024 / 256, (M + 127) / 128), dim3(512), 0, stream>>>(
        Ab, Wb + wofs[0], H1, M, 1024, 1024, invn_c, c_b1, 1);
    gemm_bt2<bf16><<<dim3(1, (M + 127) / 128), dim3(512), 0, stream>>>(
        H1, Wb + wofs[1], H2, M, 256, 1024, nullptr, c_b2, 1);
    gemm_bt<256, 64, bf16, bf16, bf16>
        <<<dim3(1, (M + 255) / 256), dim3(256), 0, stream>>>(
            H2, Wb + wofs[2], c_emb, M, 64, 256, nullptr, c_b3, 0);

    cvt_rows_norm<<<dim3((M + 3) / 4), dim3(256), 0, stream>>>(text, Ab, invn_t, M, 768);
    gemm_bt2<bf16><<<dim3(768 / 256, (M + 127) / 128), dim3(512), 0, stream>>>(
        Ab, Wb + wofs[3], H1, M, 768, 768, invn_t, t_b1, 1);
    gemm_bt2<bf16><<<dim3(1, (M + 127) / 128), dim3(512), 0, stream>>>(
        H1, Wb + wofs[4], H2, M, 256, 768, nullptr, t_b2, 1);
    gemm_bt<256, 64, bf16, bf16, bf16>
        <<<dim3(1, (M + 255) / 256), dim3(256), 0, stream>>>(
            H2, Wb + wofs[5], t_emb, M, 64, 256, nullptr, t_b3, 0);

    gemm_bt<256, 64, float, bf16, bf16>
        <<<dim3(1, (M + 255) / 256), dim3(256), 0, stream>>>(
            cf_feat, Wb + wofs[6], cf_emb, M, 64, 64, nullptr, cf_b, 0);

    // ---- attention pipeline: norm+LN -> QK (bf16) + V (fp32) GEMMs -> attn ----
    // H1 (QK), Ab (Xn|V), H2 all free at this point.
    norm_ln<<<dim3((R * 16 + 255) / 256), dim3(256), 0, stream>>>(
        c_emb, t_emb, cf_emb, item_emb, Xn, M);
    gemm_bt<256, 64, bf16, bf16, bf16>
        <<<dim3(2, (R + 255) / 256), dim3(256), 0, stream>>>(
            Xn, Wb + wofs[7], QKbuf, R, 128, 64, nullptr, nullptr, 0);
    gemm_bt<256, 64, bf16, bf16, float>
        <<<dim3(1, (R + 255) / 256), dim3(256), 0, stream>>>(
            Xn, Wb + wofs[9], Vbuf, R, 64, 64, nullptr, nullptr, 0);
    const int nGroup = (M + 3) / 4;  // 12500
    attn4<<<dim3((nGroup + 3) / 4), dim3(256), 0, stream>>>(
        QKbuf, Vbuf, fusedTab, nGroup);
    gather_out<<<dim3((n_tok * 16 + 255) / 256), dim3(256), 0, stream>>>(
        seq, fusedTab, out, n_tok);
  } else if (useWb) {
    // ---- slim path: fp32 A (packed in-kernel) + bf16 B ----
    row_invnorm<<<dim3((M + 3) / 4), dim3(256), 0, stream>>>(content, invn_c, M, 1024);
    row_invnorm<<<dim3((M + 3) / 4), dim3(256), 0, stream>>>(text, invn_t, M, 768);
    gemm_bt<128, 128, float, bf16, bf16>
        <<<dim3(1024 / 128, (M + 127) / 128), dim3(256), 0, stream>>>(
            content, Wb + wofs[0], H1, M, 1024, 1024, invn_c, c_b1, 1);
    gemm_bt<128, 128, bf16, bf16, bf16>
        <<<dim3(256 / 128, (M + 127) / 128), dim3(256), 0, stream>>>(
            H1, Wb + wofs[1], H2, M, 256, 1024, nullptr, c_b2, 1);
    gemm_bt<256, 64, bf16, bf16, bf16>
        <<<dim3(1, (M + 255) / 256), dim3(256), 0, stream>>>(
            H2, Wb + wofs[2], c_emb, M, 64, 256, nullptr, c_b3, 0);
    gemm_bt<128, 128, float, bf16, bf16>
        <<<dim3(768 / 128, (M + 127) / 128), dim3(256), 0, stream>>>(
            text, Wb + wofs[3], H1, M, 768, 768, invn_t, t_b1, 1);
    gemm_bt<128, 128, bf16, bf16, bf16>
        <<<dim3(256 / 128, (M + 127) / 128), dim3(256), 0, stream>>>(
            H1, Wb + wofs[4], H2, M, 256, 768, nullptr, t_b2, 1);
    gemm_bt<256, 64, bf16, bf16, bf16>
        <<<dim3(1, (M + 255) / 256), dim3(256), 0, stream>>>(
            H2, Wb + wofs[5], t_emb, M, 64, 256, nullptr, t_b3, 0);
    gemm_bt<256, 64, float, bf16, bf16>
        <<<dim3(1, (M + 255) / 256), dim3(256), 0, stream>>>(
            cf_feat, Wb + wofs[6], cf_emb, M, 64, 64, nullptr, cf_b, 0);
    if (useFused) {
      fuse_attn2<<<dim3(768), dim3(256), 0, stream>>>(
          nullptr, c_emb, t_emb, cf_emb, item_emb, wq, wk, wv, fusedTab, M);
      gather_out<<<dim3((n_tok * 16 + 255) / 256), dim3(256), 0, stream>>>(
          seq, fusedTab, out, n_tok);
    } else {
      fuse_attn2<<<dim3(768), dim3(256), 0, stream>>>(
          seq, c_emb, t_emb, cf_emb, item_emb, wq, wk, wv, out, n_tok);
    }
  } else {
    // ---- minimal path: fp32 A and B ----
    row_invnorm<<<dim3((M + 3) / 4), dim3(256), 0, stream>>>(content, invn_c, M, 1024);
    row_invnorm<<<dim3((M + 3) / 4), dim3(256), 0, stream>>>(text, invn_t, M, 768);
    gemm_bt<128, 128, float, float, bf16>
        <<<dim3(1024 / 128, (M + 127) / 128), dim3(256), 0, stream>>>(
            content, c_w1, H1, M, 1024, 1024, invn_c, c_b1, 1);
    gemm_bt<128, 128, bf16, float, bf16>
        <<<dim3(256 / 128, (M + 127) / 128), dim3(256), 0, stream>>>(
            H1, c_w2, H2, M, 256, 1024, nullptr, c_b2, 1);
    gemm_bt<256, 64, bf16, float, bf16>
        <<<dim3(1, (M + 255) / 256), dim3(256), 0, stream>>>(
            H2, c_w3, c_emb, M, 64, 256, nullptr, c_b3, 0);
    gemm_bt<128, 128, float, float, bf16>
        <<<dim3(768 / 128, (M + 127) / 128), dim3(256), 0, stream>>>(
            text, t_w1, H1, M, 768, 768, invn_t, t_b1, 1);
    gemm_bt<128, 128, bf16, float, bf16>
        <<<dim3(256 / 128, (M + 127) / 128), dim3(256), 0, stream>>>(
            H1, t_w2, H2, M, 256, 768, nullptr, t_b2, 1);
    gemm_bt<256, 64, bf16, float, bf16>
        <<<dim3(1, (M + 255) / 256), dim3(256), 0, stream>>>(
            H2, t_w3, t_emb, M, 64, 256, nullptr, t_b3, 0);
    gemm_bt<256, 64, float, float, bf16>
        <<<dim3(1, (M + 255) / 256), dim3(256), 0, stream>>>(
            cf_feat, cf_w, cf_emb, M, 64, 64, nullptr, cf_b, 0);
    fuse_attn2<<<dim3(768), dim3(256), 0, stream>>>(
        seq, c_emb, t_emb, cf_emb, item_emb, wq, wk, wv, out, n_tok);
  }
}